// Round 6
// baseline (4239.803 us; speedup 1.0000x reference)
//
#include <hip/hip_runtime.h>
#include <math.h>

#define B 8
#define S 128
#define D 512
#define M 4
#define BS 1024
#define BSD 524288          // B*S*D
#define DEPTH 16
#define THRESH 0.9999f
#define EPS 1e-6f
#define SCALE 0.04419417382415922f   // D^-0.5

typedef float floatx4 __attribute__((ext_vector_type(4)));
typedef short s8v __attribute__((ext_vector_type(8)));
typedef unsigned short us4 __attribute__((ext_vector_type(4)));

__device__ __forceinline__ unsigned short f2bf(float f) {
  unsigned int u = __float_as_uint(f);
  u += 0x7FFFu + ((u >> 16) & 1u);          // round-to-nearest-even
  return (unsigned short)(u >> 16);
}
__device__ __forceinline__ float bf2f(unsigned short h) {
  return __uint_as_float((unsigned int)h << 16);
}

// async global->LDS, 16B per lane, linear LDS dest (wave-uniform base + lane*16)
__device__ __forceinline__ void gll16(const void* g, void* l) {
  __builtin_amdgcn_global_load_lds(
      (const __attribute__((address_space(1))) unsigned int*)g,
      (__attribute__((address_space(3))) unsigned int*)l, 16, 0, 0);
}

// ---------------- workspace layout (float-slot offsets) ----------------
#define OFF_ZR   0
#define OFF_ZI   (1*BSD)
#define OFF_AR   (2*BSD)
#define OFF_AI   (3*BSD)
#define OFF_OR   (4*BSD)            // [M][B][S][D] fp32 = 4*BSD
#define OFF_OI   (8*BSD)
#define OFF_FEAT (12*BSD)           // 65536
#define OFF_GWP  (12*BSD + 65536)   // 8192
#define OFF_H0   (12*BSD + 73728)
#define OFF_H1   (12*BSD + 77824)
#define OFF_CUM  (12*BSD + 81920)   // 8
#define OFF_W    (12*BSD + 81928)   // 32
#define OFF_WT   (12*BSD + 81960)   // 8
#define OFF_CUM2 (12*BSD + 81968)   // 8
// bf16 annex (slots)
#define OFF_XH   (12*BSD + 90112)           // xcat hi [1024][1024] = 1 BSD
#define OFF_XL   (OFF_XH + 1*BSD)
#define OFF_WH   (OFF_XH + 2*BSD)           // 24 planes [512][512] hi = 6 BSD
#define OFF_WL   (OFF_XH + 8*BSD)
#define OFF_QCH  (OFF_XH + 14*BSD)          // Qcat hi [M][1024][1024] = 4 BSD
#define OFF_QCL  (OFF_XH + 18*BSD)
#define OFF_KCH  (OFF_XH + 22*BSD)
#define OFF_KCL  (OFF_XH + 26*BSD)
#define OFF_VTH  (OFF_XH + 30*BSD)          // Vt hi [2ri][M][512][1024] = 4 BSD
#define OFF_VTL  (OFF_XH + 34*BSD)
#define OFF_PH   (OFF_XH + 38*BSD)          // P hi [32][128][128] = 262144 slots
#define OFF_PL   (OFF_PH + 262144)
// end ~= 107.3 MB (R6/R8 proven)

// ---------------- init: fp32 carry + bf16 hi/lo Xcat + zero FEAT/GWP/CUMs ----------------
__global__ __launch_bounds__(256) void k_init(const float* __restrict__ xr,
                                              const float* __restrict__ xi,
                                              float* __restrict__ ws) {
  unsigned short* xh = (unsigned short*)(ws + OFF_XH);
  unsigned short* xl = (unsigned short*)(ws + OFF_XL);
  int i4 = blockIdx.x * 256 + threadIdx.x;      // BSD/4
  float4 a = ((const float4*)xr)[i4];
  float4 b = ((const float4*)xi)[i4];
  ((float4*)(ws + OFF_ZR))[i4] = a;
  ((float4*)(ws + OFF_ZI))[i4] = b;
  float4 z = {0.f, 0.f, 0.f, 0.f};
  ((float4*)(ws + OFF_AR))[i4] = z;
  ((float4*)(ws + OFF_AI))[i4] = z;
  int row = i4 >> 7;
  int d4 = (i4 & 127) * 4;
  float av[4] = {a.x, a.y, a.z, a.w}, bv[4] = {b.x, b.y, b.z, b.w};
  us4 hh, hl;
#pragma unroll
  for (int j = 0; j < 4; ++j) {
    unsigned short h = f2bf(av[j]); hh[j] = h; hl[j] = f2bf(av[j] - bf2f(h));
  }
  *(us4*)(xh + (size_t)row * 1024 + d4) = hh;
  *(us4*)(xl + (size_t)row * 1024 + d4) = hl;
#pragma unroll
  for (int j = 0; j < 4; ++j) {
    unsigned short h = f2bf(bv[j]); hh[j] = h; hl[j] = f2bf(bv[j] - bf2f(h));
  }
  *(us4*)(xh + (size_t)row * 1024 + 512 + d4) = hh;
  *(us4*)(xl + (size_t)row * 1024 + 512 + d4) = hl;
  if (i4 < (B * D) / 4) {
    ((float4*)(ws + OFF_H0))[i4] = z;
    ((float4*)(ws + OFF_H1))[i4] = z;
  }
  if (i4 < 16384) ((float4*)(ws + OFF_FEAT))[i4] = z;
  if (i4 < 2048)  ((float4*)(ws + OFF_GWP))[i4] = z;
  if (i4 < B) { ws[OFF_CUM + i4] = 0.f; ws[OFF_CUM2 + i4] = 0.f; }
}

// ---------------- weight prep (R6, proven) ----------------
__global__ __launch_bounds__(256) void k_wprep(const float* __restrict__ Wqr,
                                               const float* __restrict__ Wqi,
                                               const float* __restrict__ Wkr,
                                               const float* __restrict__ Wki,
                                               const float* __restrict__ Wvr,
                                               const float* __restrict__ Wvi,
                                               float* __restrict__ ws) {
  __shared__ float lt[64][65];
  unsigned short* wh = (unsigned short*)(ws + OFF_WH);
  unsigned short* wl = (unsigned short*)(ws + OFF_WL);
  int z = blockIdx.z, m = z / 6, idx = z % 6;
  const float* Wsrc;
  switch (idx) {
    case 0:  Wsrc = Wqr; break;
    case 1:  Wsrc = Wqi; break;
    case 2:  Wsrc = Wkr; break;
    case 3:  Wsrc = Wki; break;
    case 4:  Wsrc = Wvr; break;
    default: Wsrc = Wvi; break;
  }
  Wsrc += (size_t)m * D * D;
  int k0 = blockIdx.x * 64, n0 = blockIdx.y * 64;
  int tx = threadIdx.x & 63, ty = threadIdx.x >> 6;
#pragma unroll
  for (int i = 0; i < 16; ++i) {
    int kl = ty + i * 4;
    lt[kl][tx] = Wsrc[(size_t)(k0 + kl) * D + n0 + tx];
  }
  __syncthreads();
  unsigned short* whp = wh + (size_t)z * 262144;
  unsigned short* wlp = wl + (size_t)z * 262144;
#pragma unroll
  for (int i = 0; i < 16; ++i) {
    int nl = ty + i * 4;
    float v = lt[tx][nl];
    unsigned short h = f2bf(v);
    whp[(size_t)(n0 + nl) * 512 + k0 + tx] = h;
    wlp[(size_t)(n0 + nl) * 512 + k0 + tx] = f2bf(v - bf2f(h));
  }
}

// ---------------- gwp (pre-loop only) ----------------
__global__ __launch_bounds__(256) void k_gwp(const float* __restrict__ zr,
                                             const float* __restrict__ zi,
                                             float* __restrict__ gwp) {
  int idx = blockIdx.x * 256 + threadIdx.x;
  int b = idx >> 10;
  int f = idx & 1023;
  const float* src = (f < D) ? (zr + b * S * D + f) : (zi + b * S * D + (f - D));
  float s = 0.f;
#pragma unroll 8
  for (int ss = 0; ss < S; ++ss) s += src[ss * D];
  gwp[idx] = s * (1.0f / S);
}

// ---------------- k_qkgru: Q/K GEMMs (z<16) + GRU (z in {16,17}) (R17) ----------------
// grid (4, 8, 18). QK: z = m*4 + w6, w6 in [0,4), 512 blocks = exactly 2 CU-rounds;
// GRU blocks (64) ride in the second round. R13-proven bodies.
__global__ __launch_bounds__(256) void k_qkgru(float* __restrict__ ws,
                                               const float* __restrict__ gwp,
                                               const float* __restrict__ hold,
                                               float* __restrict__ hnew,
                                               const float* __restrict__ Wih,
                                               const float* __restrict__ Whh,
                                               const float* __restrict__ bih,
                                               const float* __restrict__ bhh) {
  __shared__ __align__(16) unsigned short Ah[128 * 32], Al[128 * 32];
  __shared__ __align__(16) unsigned short Bh[128 * 32], Bl[128 * 32];
  int t = threadIdx.x;
  if (blockIdx.z >= 16) {
    // ---- GRU path (R7-proven body; LDS overlaid) ----
    float* xbuf = (float*)Ah;                 // 1024 floats
    float* hbuf = (float*)Al;                 // 512 floats
    float (*red)[64][4] = (float (*)[64][4])Bh;
    int gid = (blockIdx.z - 16) * 32 + blockIdx.y * 4 + blockIdx.x;
    int b = gid >> 3;
    int c0 = (gid & 7) * 64;
    int td = t & 63, ks = t >> 6;
    for (int f = t; f < 1024; f += 256) xbuf[f] = gwp[b * 1024 + f];
    for (int d2 = t; d2 < 512; d2 += 256) hbuf[d2] = hold[b * 512 + d2];
    __syncthreads();
    float accR = 0.f, accZ = 0.f, accXn = 0.f, accHn = 0.f;
    int kbeg = ks * 384, kend = kbeg + 384;
#pragma unroll 4
    for (int kk = kbeg; kk < kend; ++kk) {
      bool ih = kk < 1024;
      float x = ih ? xbuf[kk] : hbuf[kk - 1024];
      const float* base = ih ? (Wih + (size_t)kk * 1536) : (Whh + (size_t)(kk - 1024) * 1536);
      float wr = base[c0 + td];
      float wz = base[512 + c0 + td];
      float wn = base[1024 + c0 + td];
      accR += x * wr;
      accZ += x * wz;
      if (ih) accXn += x * wn; else accHn += x * wn;
    }
    red[ks][td][0] = accR;
    red[ks][td][1] = accZ;
    red[ks][td][2] = accXn;
    red[ks][td][3] = accHn;
    __syncthreads();
    if (t < 64) {
      int c = c0 + t;
      float r_ = 0.f, z_ = 0.f, xn = 0.f, hn = 0.f;
#pragma unroll
      for (int s = 0; s < 4; ++s) {
        r_ += red[s][t][0]; z_ += red[s][t][1]; xn += red[s][t][2]; hn += red[s][t][3];
      }
      r_ += bih[c] + bhh[c];
      z_ += bih[512 + c] + bhh[512 + c];
      xn += bih[1024 + c];
      hn += bhh[1024 + c];
      float r = 1.f / (1.f + expf(-r_));
      float z = 1.f / (1.f + expf(-z_));
      float n = tanhf(xn + r * hn);
      hnew[b * 512 + c] = (1.f - z) * n + z * hbuf[c];
    }
    return;
  }
  // ---- QK GEMM path ----
  const unsigned short* xh = (const unsigned short*)(ws + OFF_XH);
  const unsigned short* xl = (const unsigned short*)(ws + OFF_XL);
  const unsigned short* wh = (const unsigned short*)(ws + OFF_WH);
  const unsigned short* wl = (const unsigned short*)(ws + OFF_WL);
  int z = blockIdx.z, m = z >> 2, w6 = z & 3;
  int pair = (w6 >> 1) * 2;
  int p1 = m * 6 + pair + (w6 & 1);
  int p2 = m * 6 + pair + ((w6 & 1) ^ 1);
  bool neg2 = ((w6 & 1) == 0);               // real-output GEMMs negate second K-half
  const unsigned short* PH1 = wh + (size_t)p1 * 262144;
  const unsigned short* PL1 = wl + (size_t)p1 * 262144;
  const unsigned short* PH2 = wh + (size_t)p2 * 262144;
  const unsigned short* PL2 = wl + (size_t)p2 * 262144;

  int row0 = blockIdx.y * 128;    // X rows
  int col0 = blockIdx.x * 128;    // W cols
  int lane = t & 63, w = t >> 6;
  int wr = w >> 1, wc = w & 1;
  int q = lane >> 4, r = lane & 15;
  int srow = t >> 2;
  int skoff = (t & 3) * 8;
  size_t wrow1 = (size_t)(col0 + srow) * 512 + skoff;
  size_t wrow2 = (size_t)(col0 + 64 + srow) * 512 + skoff;
  size_t xrow1 = (size_t)(row0 + srow) * 1024 + skoff;
  size_t xrow2 = (size_t)(row0 + 64 + srow) * 1024 + skoff;
  const s8v sgn = {(short)0x8000, (short)0x8000, (short)0x8000, (short)0x8000,
                   (short)0x8000, (short)0x8000, (short)0x8000, (short)0x8000};

  floatx4 acc[4][4];
#pragma unroll
  for (int i = 0; i < 4; ++i)
#pragma unroll
    for (int j = 0; j < 4; ++j) acc[i][j] = (floatx4){0.f, 0.f, 0.f, 0.f};

  for (int k0 = 0; k0 < 1024; k0 += 32) {
    const unsigned short *WgH, *WgL;
    int kk = k0;
    bool xon = false;
    if (k0 < 512) { WgH = PH1; WgL = PL1; }
    else          { WgH = PH2; WgL = PL2; kk = k0 - 512; xon = neg2; }
    gll16(xh + xrow1 + k0, (char*)Ah + t * 16);
    gll16(xh + xrow2 + k0, (char*)Ah + 4096 + t * 16);
    gll16(xl + xrow1 + k0, (char*)Al + t * 16);
    gll16(xl + xrow2 + k0, (char*)Al + 4096 + t * 16);
    gll16(WgH + wrow1 + kk, (char*)Bh + t * 16);
    gll16(WgH + wrow2 + kk, (char*)Bh + 4096 + t * 16);
    gll16(WgL + wrow1 + kk, (char*)Bl + t * 16);
    gll16(WgL + wrow2 + kk, (char*)Bl + 4096 + t * 16);
    __syncthreads();
    s8v ah[4], al[4], bh[4], bl[4];
#pragma unroll
    for (int i = 0; i < 4; ++i) {
      int ro = (wr * 64 + i * 16 + r) * 32 + q * 8;
      ah[i] = *(const s8v*)((const short*)Ah + ro);
      al[i] = *(const s8v*)((const short*)Al + ro);
    }
#pragma unroll
    for (int j = 0; j < 4; ++j) {
      int ro = (wc * 64 + j * 16 + r) * 32 + q * 8;
      bh[j] = *(const s8v*)((const short*)Bh + ro);
      bl[j] = *(const s8v*)((const short*)Bl + ro);
    }
    if (xon) {
#pragma unroll
      for (int j = 0; j < 4; ++j) { bh[j] = bh[j] ^ sgn; bl[j] = bl[j] ^ sgn; }
    }
#pragma unroll
    for (int i = 0; i < 4; ++i)
#pragma unroll
      for (int j = 0; j < 4; ++j) {
        acc[i][j] = __builtin_amdgcn_mfma_f32_16x16x32_bf16(ah[i], bh[j], acc[i][j], 0, 0, 0);
        acc[i][j] = __builtin_amdgcn_mfma_f32_16x16x32_bf16(ah[i], bl[j], acc[i][j], 0, 0, 0);
        acc[i][j] = __builtin_amdgcn_mfma_f32_16x16x32_bf16(al[i], bh[j], acc[i][j], 0, 0, 0);
      }
    __syncthreads();
  }
  unsigned short *dh, *dl;
  if (w6 < 2) { dh = (unsigned short*)(ws + OFF_QCH); dl = (unsigned short*)(ws + OFF_QCL); }
  else        { dh = (unsigned short*)(ws + OFF_KCH); dl = (unsigned short*)(ws + OFF_KCL); }
  int half = (w6 & 1) * 512;
  size_t base = (size_t)m * 1024 * 1024;
#pragma unroll
  for (int i = 0; i < 4; ++i)
#pragma unroll
    for (int j = 0; j < 4; ++j) {
      int rowb = row0 + wr * 64 + i * 16 + q * 4;
      int colb = col0 + wc * 64 + j * 16 + r;
#pragma unroll
      for (int reg = 0; reg < 4; ++reg) {
        float v = acc[i][j][reg];
        unsigned short h = f2bf(v);
        size_t idx = base + (size_t)(rowb + reg) * 1024 + half + colb;
        dh[idx] = h;
        dl[idx] = f2bf(v - bf2f(h));
      }
    }
}

// ---------------- k_vattn: attention (blk<128, row-split 32 rows) + V GEMM (blk>=128) ----------------
// R17: attn first so it dispatches immediately (critical path to k_pv); V backfills.
// attn blk: mb = blk>>2, rq = blk&3 -> rows [rq*32, rq*32+32) of mb's 128. Softmax rows
// independent -> row split exact. V path identical to R16.
__global__ __launch_bounds__(256) void k_vattn(float* __restrict__ ws) {
  __shared__ __align__(16) unsigned short Ah[128 * 32], Al[128 * 32];
  __shared__ __align__(16) unsigned short Bh[128 * 32], Bl[128 * 32];
  __shared__ float rmax[32][4];
  __shared__ float rsum[32][4];
  int t = threadIdx.x;
  int blk = blockIdx.x;

  if (blk < 128) {
    // ---- attn path: 32 Q-rows x 128 K-cols ----
    const unsigned short* qch = (const unsigned short*)(ws + OFF_QCH);
    const unsigned short* qcl = (const unsigned short*)(ws + OFF_QCL);
    const unsigned short* kch = (const unsigned short*)(ws + OFF_KCH);
    const unsigned short* kcl = (const unsigned short*)(ws + OFF_KCL);
    unsigned short* ph = (unsigned short*)(ws + OFF_PH);
    unsigned short* pl = (unsigned short*)(ws + OFF_PL);
    int mb = blk >> 2, rq = blk & 3;
    int r0 = rq * 32;
    size_t gbase = (size_t)mb * 128 * 1024;
    int lane = t & 63, wc = t >> 6;
    int q = lane >> 4, r = lane & 15;
    int at = t & 127;                      // A-stage slot (32 rows x 4 chunks)
    size_t arow = gbase + (size_t)(r0 + (at >> 2)) * 1024 + (at & 3) * 8;
    int srow = t >> 2, skoff = (t & 3) * 8;
    size_t brow1 = gbase + (size_t)srow * 1024 + skoff;
    size_t brow2 = gbase + (size_t)(64 + srow) * 1024 + skoff;

    floatx4 acc[2][2];
#pragma unroll
    for (int i = 0; i < 2; ++i)
#pragma unroll
      for (int j = 0; j < 2; ++j) acc[i][j] = (floatx4){0.f, 0.f, 0.f, 0.f};

    for (int k0 = 0; k0 < 1024; k0 += 32) {
      // waves 0,1 stage A-hi; waves 2,3 stage A-lo (uniform branch per wave)
      if (t < 128) gll16(qch + arow + k0, (char*)Ah + at * 16);
      else         gll16(qcl + arow + k0, (char*)Al + at * 16);
      gll16(kch + brow1 + k0, (char*)Bh + t * 16);
      gll16(kch + brow2 + k0, (char*)Bh + 4096 + t * 16);
      gll16(kcl + brow1 + k0, (char*)Bl + t * 16);
      gll16(kcl + brow2 + k0, (char*)Bl + 4096 + t * 16);
      __syncthreads();
      s8v ah[2], al[2], bh[2], bl[2];
#pragma unroll
      for (int i = 0; i < 2; ++i) {
        int ro = (i * 16 + r) * 32 + q * 8;
        ah[i] = *(const s8v*)((const short*)Ah + ro);
        al[i] = *(const s8v*)((const short*)Al + ro);
      }
#pragma unroll
      for (int j = 0; j < 2; ++j) {
        int ro = (wc * 32 + j * 16 + r) * 32 + q * 8;
        bh[j] = *(const s8v*)((const short*)Bh + ro);
        bl[j] = *(const s8v*)((const short*)Bl + ro);
      }
#pragma unroll
      for (int i = 0; i < 2; ++i)
#pragma unroll
        for (int j = 0; j < 2; ++j) {
          acc[i][j] = __builtin_amdgcn_mfma_f32_16x16x32_bf16(ah[i], bh[j], acc[i][j], 0, 0, 0);
          acc[i][j] = __builtin_amdgcn_mfma_f32_16x16x32_bf16(ah[i], bl[j], acc[i][j], 0, 0, 0);
          acc[i][j] = __builtin_amdgcn_mfma_f32_16x16x32_bf16(al[i], bh[j], acc[i][j], 0, 0, 0);
        }
      __syncthreads();
    }
#pragma unroll
    for (int i = 0; i < 2; ++i)
#pragma unroll
      for (int j = 0; j < 2; ++j)
#pragma unroll
        for (int reg = 0; reg < 4; ++reg) acc[i][j][reg] *= SCALE;
#pragma unroll
    for (int i = 0; i < 2; ++i)
#pragma unroll
      for (int reg = 0; reg < 4; ++reg) {
        float mx = fmaxf(acc[i][0][reg], acc[i][1][reg]);
        for (int o = 1; o < 16; o <<= 1) mx = fmaxf(mx, __shfl_xor(mx, o));
        if (r == 0) rmax[i * 16 + q * 4 + reg][wc] = mx;
      }
    __syncthreads();
#pragma unroll
    for (int i = 0; i < 2; ++i)
#pragma unroll
      for (int reg = 0; reg < 4; ++reg) {
        int row = i * 16 + q * 4 + reg;
        float gmx = fmaxf(fmaxf(rmax[row][0], rmax[row][1]),
                          fmaxf(rmax[row][2], rmax[row][3]));
        float sm = 0.f;
#pragma unroll
        for (int j = 0; j < 2; ++j) {
          float e = __expf(acc[i][j][reg] - gmx);
          acc[i][j][reg] = e;
          sm += e;
        }
        for (int o = 1; o < 16; o <<= 1) sm += __shfl_xor(sm, o);
        if (r == 0) rsum[row][wc] = sm;
      }
    __syncthreads();
#pragma unroll
    for (int i = 0; i < 2; ++i)
#pragma unroll
      for (int reg = 0; reg < 4; ++reg) {
        int row = i * 16 + q * 4 + reg;
        float inv = 1.f / (rsum[row][0] + rsum[row][1] + rsum[row][2] + rsum[row][3]);
        size_t rb = (size_t)(mb * 128 + r0 + row) * 128;
#pragma unroll
        for (int j = 0; j < 2; ++j) {
          float p = acc[i][j][reg] * inv;
          unsigned short h = f2bf(p);
          size_t idx = rb + wc * 32 + j * 16 + r;
          ph[idx] = h;
          pl[idx] = f2bf(p - bf2f(h));
        }
      }
    return;
  }

  // ---- V GEMM path (R13-proven body, w6 in {4,5}) ----
  const unsigned short* xh = (const unsigned short*)(ws + OFF_XH);
  const unsigned short* xl = (const unsigned short*)(ws + OFF_XL);
  const unsigned short* wh = (const unsigned short*)(ws + OFF_WH);
  const unsigned short* wl = (const unsigned short*)(ws + OFF_WL);
  int vblk = blk - 128;
  int plane = vblk >> 5, m = plane >> 1, w6 = 4 + (plane & 1);
  int bx = (vblk & 31) >> 3, by = vblk & 7;
  int p1 = m * 6 + 4 + (w6 & 1);
  int p2 = m * 6 + 4 + ((w6 & 1) ^ 1);
  bool neg2 = ((w6 & 1) == 0);
  const unsigned short* PH1 = wh + (size_t)p1 * 262144;
  const unsigned short* PL1 = wl + (size_t)p1 * 262144;
  const unsigned short* PH2 = wh + (size_t)p2 * 262144;
  const unsigned short* PL2 = wl + (size_t)p2 * 262144;

  int row0 = bx * 128;     // W cols (Vt rows)
  int col0 = by * 128;     // X rows (Vt cols)
  int lane = t & 63, w = t >> 6;
  int wr = w >> 1, wc = w & 1;
  int q = lane >> 4, r = lane & 15;
  int srow = t >> 2;
  int skoff = (t & 3) * 8;
  size_t wrow1 = (size_t)(row0 + srow) * 512 + skoff;
  size_t wrow2 = (size_t)(row0 + 64 + srow) * 512 + skoff;
  size_t xrow1 = (size_t)(col0 + srow) * 1024 + skoff;
  size_t xrow2 = (size_t)(col0 + 64 + srow) * 1024 + skoff;
  const s8v sgn = {(short)0x8000, (short)0x8000, (short)0x8000, (short)0x8000,
                   (short)0x8000, (short)0x8000, (short)0x8000, (short)0x8000};

  floatx4 acc[4][4];
#pragma unroll
  for (int i = 0; i < 4; ++i)
#pragma unroll
    for (int j = 0; j < 4; ++j) acc[i][j] = (floatx4){0.f, 0.f, 0.f, 0.f};

  for (int k0 = 0; k0 < 1024; k0 += 32) {
    const unsigned short *WgH, *WgL;
    int kk = k0;
    bool xon = false;
    if (k0 < 512) { WgH = PH1; WgL = PL1; }
    else          { WgH = PH2; WgL = PL2; kk = k0 - 512; xon = neg2; }
    gll16(WgH + wrow1 + kk, (char*)Ah + t * 16);
    gll16(WgH + wrow2 + kk, (char*)Ah + 4096 + t * 16);
    gll16(WgL + wrow1 + kk, (char*)Al + t * 16);
    gll16(WgL + wrow2 + kk, (char*)Al + 4096 + t * 16);
    gll16(xh + xrow1 + k0, (char*)Bh + t * 16);
    gll16(xh + xrow2 + k0, (char*)Bh + 4096 + t * 16);
    gll16(xl + xrow1 + k0, (char*)Bl + t * 16);
    gll16(xl + xrow2 + k0, (char*)Bl + 4096 + t * 16);
    __syncthreads();
    s8v ah[4], al[4], bh[4], bl[4];
#pragma unroll
    for (int i = 0; i < 4; ++i) {
      int ro = (wr * 64 + i * 16 + r) * 32 + q * 8;
      ah[i] = *(const s8v*)((const short*)Ah + ro);
      al[i] = *(const s8v*)((const short*)Al + ro);
    }
#pragma unroll
    for (int j = 0; j < 4; ++j) {
      int ro = (wc * 64 + j * 16 + r) * 32 + q * 8;
      bh[j] = *(const s8v*)((const short*)Bh + ro);
      bl[j] = *(const s8v*)((const short*)Bl + ro);
    }
    if (xon) {                                 // sign-flip weight-side fragments (A side)
#pragma unroll
      for (int i = 0; i < 4; ++i) { ah[i] = ah[i] ^ sgn; al[i] = al[i] ^ sgn; }
    }
#pragma unroll
    for (int i = 0; i < 4; ++i)
#pragma unroll
      for (int j = 0; j < 4; ++j) {
        acc[i][j] = __builtin_amdgcn_mfma_f32_16x16x32_bf16(ah[i], bh[j], acc[i][j], 0, 0, 0);
        acc[i][j] = __builtin_amdgcn_mfma_f32_16x16x32_bf16(ah[i], bl[j], acc[i][j], 0, 0, 0);
        acc[i][j] = __builtin_amdgcn_mfma_f32_16x16x32_bf16(al[i], bh[j], acc[i][j], 0, 0, 0);
      }
    __syncthreads();
  }
  unsigned short* dh = (unsigned short*)(ws + OFF_VTH);
  unsigned short* dl = (unsigned short*)(ws + OFF_VTL);
  size_t base = (size_t)((w6 & 1) * 4 + m) * 512 * 1024;
#pragma unroll
  for (int i = 0; i < 4; ++i)
#pragma unroll
    for (int j = 0; j < 4; ++j) {
      int rowb = row0 + wr * 64 + i * 16 + q * 4;
      int colb = col0 + wc * 64 + j * 16 + r;
#pragma unroll
      for (int reg = 0; reg < 4; ++reg) {
        float v = acc[i][j][reg];
        unsigned short h = f2bf(v);
        size_t idx = base + (size_t)(rowb + reg) * 1024 + colb;
        dh[idx] = h;
        dl[idx] = f2bf(v - bf2f(h));
      }
    }
}

// ---------------- PV: O = P @ Vt^T (bf16x3 MFMA), fp32 out (R13 single-buffer) ----------------
__global__ __launch_bounds__(256) void k_pv(float* __restrict__ ws) {
  __shared__ __align__(16) unsigned short Ph_[128 * 32], Pl_[128 * 32];
  __shared__ __align__(16) unsigned short VrH[128 * 32], VrL[128 * 32];
  __shared__ __align__(16) unsigned short ViH[128 * 32], ViL[128 * 32];
  const unsigned short* ph = (const unsigned short*)(ws + OFF_PH);
  const unsigned short* pl = (const unsigned short*)(ws + OFF_PL);
  const unsigned short* vth = (const unsigned short*)(ws + OFF_VTH);
  const unsigned short* vtl = (const unsigned short*)(ws + OFF_VTL);
  int mb = blockIdx.y, m = mb >> 3, b = mb & 7;
  int col0 = blockIdx.x * 128;
  int t = threadIdx.x, lane = t & 63, w = t >> 6;
  int wr = w >> 1, wc = w & 1;
  int q = lane >> 4, r = lane & 15;
  int srow = t >> 2;
  int skoff = (t & 3) * 8;
  size_t prow1 = (size_t)(mb * 128 + srow) * 128 + skoff;
  size_t prow2 = (size_t)(mb * 128 + 64 + srow) * 128 + skoff;
  size_t vbr1 = ((size_t)(m * 512) + col0 + srow) * 1024 + b * 128 + skoff;
  size_t vbr2 = ((size_t)(m * 512) + col0 + 64 + srow) * 1024 + b * 128 + skoff;
  size_t vplane_i = (size_t)4 * 512 * 1024;

  floatx4 accR[4][4], accI[4][4];
#pragma unroll
  for (int i = 0; i < 4; ++i)
#pragma unroll
    for (int j = 0; j < 4; ++j) {
      accR[i][j] = (floatx4){0.f, 0.f, 0.f, 0.f};
      accI[i][j] = (floatx4){0.f, 0.f, 0.f, 0.f};
    }

  for (int k0 = 0; k0 < 128; k0 += 32) {
    gll16(ph + prow1 + k0, (char*)Ph_ + t * 16);
    gll16(ph + prow2 + k0, (char*)Ph_ + 4096 + t * 16);
    gll16(pl + prow1 + k0, (char*)Pl_ + t * 16);
    gll16(pl + prow2 + k0, (char*)Pl_ + 4096 + t * 16);
    gll16(vth + vbr1 + k0, (char*)VrH + t * 16);
    gll16(vth + vbr2 + k0, (char*)VrH + 4096 + t * 16);
    gll16(vtl + vbr1 + k0, (char*)VrL + t * 16);
    gll16(vtl + vbr2 + k0, (char*)VrL + 4096 + t * 16);
    gll16(vth + vplane_i + vbr1 + k0, (char*)ViH + t * 16);
    gll16(vth + vplane_i + vbr2 + k0, (char*)ViH + 4096 + t * 16);
    gll16(vtl + vplane_i + vbr1 + k0, (char*)ViL + t * 16);
    gll16(vtl + vplane_i + vbr2 + k0, (char*)ViL + 4096 + t * 16);
    __syncthreads();
    s8v ah[4], al[4];
#pragma unroll
    for (int i = 0; i < 4; ++i) {
      int ro = (wr * 64 + i * 16 + r) * 32 + q * 8;
      ah[i] = *(const s8v*)((const short*)Ph_ + ro);
      al[i] = *(const s8v*)((const short*)Pl_ + ro);
    }
#pragma unroll
    for (int j = 0; j < 4; ++j) {
      int ro = (wc * 64 + j * 16 + r) * 32 + q * 8;
      s8v vrh = *(const s8v*)((const short*)VrH + ro);
      s8v vrl = *(const s8v*)((const short*)VrL + ro);
      s8v vih = *(const s8v*)((const short*)ViH + ro);
      s8v vil = *(const s8v*)((const short*)ViL + ro);
#pragma unroll
      for (int i = 0; i < 4; ++i) {
        accR[i][j] = __builtin_amdgcn_mfma_f32_16x16x32_bf16(ah[i], vrh, accR[i][j], 0, 0, 0);
        accR[i][j] = __builtin_amdgcn_mfma_f32_16x16x32_bf16(ah[i], vrl, accR[i][j], 0, 0, 0);
        accR[i][j] = __builtin_amdgcn_mfma_f32_16x16x32_bf16(al[i], vrh, accR[i][j], 0, 0, 0);
        accI[i][j] = __builtin_amdgcn_mfma_f32_16x16x32_bf16(ah[i], vih, accI[i][j], 0, 0, 0);
        accI[i][j] = __builtin_amdgcn_mfma_f32_16x16x32_bf16(ah[i], vil, accI[i][j], 0, 0, 0);
        accI[i][j] = __builtin_amdgcn_mfma_f32_16x16x32_bf16(al[i], vih, accI[i][j], 0, 0, 0);
      }
    }
    __syncthreads();
  }
  float* orp = ws + OFF_OR + (size_t)mb * 128 * 512;
  float* oip = ws + OFF_OI + (size_t)mb * 128 * 512;
#pragma unroll
  for (int i = 0; i < 4; ++i)
#pragma unroll
    for (int j = 0; j < 4; ++j) {
      int rowb = wr * 64 + i * 16 + q * 4;
      int colb = col0 + wc * 64 + j * 16 + r;
#pragma unroll
      for (int reg = 0; reg < 4; ++reg) {
        orp[(size_t)(rowb + reg) * 512 + colb] = accR[i][j][reg];
        oip[(size_t)(rowb + reg) * 512 + colb] = accI[i][j][reg];
      }
    }
}

// ---------------- ModReLU + ComplexLayerNorm + feat partials (fused, R9/R11) ----------------
__global__ __launch_bounds__(256) void k_modlnfeat(float* __restrict__ ws,
                                                   const float* __restrict__ mod_bias,
                                                   const float* __restrict__ ln_scale,
                                                   const float* __restrict__ ln_shift) {
  int blk = blockIdx.x;
  int mb = blk >> 2, grp = blk & 3;
  int m = mb >> 3;
  int t = threadIdx.x, w = t >> 6, l = t & 63;
  int e0 = l * 8;
  float mb_[8], lsc[8], lsh[8];
  *(float4*)&mb_[0] = *(const float4*)(mod_bias + m * 512 + e0);
  *(float4*)&mb_[4] = *(const float4*)(mod_bias + m * 512 + e0 + 4);
  *(float4*)&lsc[0] = *(const float4*)(ln_scale + m * 512 + e0);
  *(float4*)&lsc[4] = *(const float4*)(ln_scale + m * 512 + e0 + 4);
  *(float4*)&lsh[0] = *(const float4*)(ln_shift + m * 512 + e0);
  *(float4*)&lsh[4] = *(const float4*)(ln_shift + m * 512 + e0 + 4);
  float featR[8] = {}, featI[8] = {};
  for (int it = 0; it < 8; ++it) {
    int s = grp * 32 + it * 4 + w;
    float* orp = ws + OFF_OR + ((size_t)mb * 128 + s) * 512 + e0;
    float* oip = ws + OFF_OI + ((size_t)mb * 128 + s) * 512 + e0;
    float orv[8], oiv[8], magv[8];
    *(float4*)&orv[0] = *(const float4*)orp;
    *(float4*)&orv[4] = *(const float4*)(orp + 4);
    *(float4*)&oiv[0] = *(const float4*)oip;
    *(float4*)&oiv[4] = *(const float4*)(oip + 4);
    float sum = 0.f, sumsq = 0.f;
#pragma unroll
    for (int j = 0; j < 8; ++j) {
      float o_r = orv[j], o_i = oiv[j];
      float mag = sqrtf(o_r * o_r + o_i * o_i) + EPS;
      float g = fmaxf(mag + mb_[j], 0.f) / mag;
      o_r *= g; o_i *= g;
      orv[j] = o_r; oiv[j] = o_i;
      float mag2 = sqrtf(o_r * o_r + o_i * o_i) + EPS;
      magv[j] = mag2;
      sum += mag2;
      sumsq += mag2 * mag2;
    }
    for (int o = 1; o < 64; o <<= 1) {
      sum += __shfl_xor(sum, o);
      sumsq += __shfl_xor(sumsq, o);
    }
    float mu = sum * (1.f / D);
    float var = (sumsq - (float)D * mu * mu) * (1.f / (D - 1));
    float inv = 1.f / sqrtf(var + EPS);
#pragma unroll
    for (int j = 0; j < 8; ++j) {
      float nm = (magv[j] - mu) * inv * lsc[j] + lsh[j];
      float hyp = magv[j] - EPS;
      float cp, sp;
      if (hyp > 0.f) { cp = orv[j] / hyp; sp = oiv[j] / hyp; }
      else           { cp = 1.f;          sp = 0.f; }
      orv[j] = nm * cp;
      oiv[j] = nm * sp;
      featR[j] += orv[j];
      featI[j] += oiv[j];
    }
    *(float4*)orp = *(float4*)&orv[0];
    *(float4*)(orp + 4) = *(float4*)&orv[4];
    *(float4*)oip = *(float4*)&oiv[0];
    *(float4*)(oip + 4) = *(float4*)&oiv[4];
  }
  float* fb = ws + OFF_FEAT + (size_t)mb * 1024;
#pragma unroll
  for (int j = 0; j < 8; ++j) {
    atomicAdd(fb + e0 + j, featR[j] * (1.0f / S));
    atomicAdd(fb + 512 + e0 + j, featI[j] * (1.0f / S));
  }
}

// ---------------- wsel (R1) + zero FEAT/GWP for next step (R9) ----------------
__global__ __launch_bounds__(256) void k_wsel(float* __restrict__ ws,
                                              const float* __restrict__ hnew,
                                              const float* __restrict__ bias_W,
                                              const float* __restrict__ bias_b,
                                              const float* __restrict__ w_sal) {
  __shared__ float mb_s[B][M];
  __shared__ float sal_s[M][B];
  int t = threadIdx.x;
  int p = t >> 3, l = t & 7;
  {
    int b = p >> 2, m = p & 3;
    float s = 0.f;
    for (int d2 = l; d2 < D; d2 += 8) s += hnew[b * D + d2] * bias_W[d2 * M + m];
    for (int o = 1; o < 8; o <<= 1) s += __shfl_xor(s, o);
    if (l == 0) mb_s[b][m] = s + bias_b[m];
  }
  {
    int m = p >> 3, b = p & 7;
    float s = 0.f;
    for (int f = l; f < 2 * D; f += 8) s += ws[OFF_FEAT + (m * B + b) * 2 * D + f] * w_sal[m * 2 * D + f];
    for (int o = 1; o < 8; o <<= 1) s += __shfl_xor(s, o);
    if (l == 0) sal_s[m][b] = s;
  }
  __syncthreads();
  if (t < B) {
    int b = t;
    float lg[M], mx = -1e30f;
#pragma unroll
    for (int m = 0; m < M; ++m) { lg[m] = sal_s[m][b] + mb_s[b][m]; mx = fmaxf(mx, lg[m]); }
    float sm = 0.f;
#pragma unroll
    for (int m = 0; m < M; ++m) { lg[m] = expf(lg[m] - mx); sm += lg[m]; }
    float inv = 1.f / sm;
#pragma unroll
    for (int m = 0; m < M; ++m) ws[OFF_W + m * B + b] = lg[m] * inv;
  }
  float4 z4 = {0.f, 0.f, 0.f, 0.f};
  for (int i = t; i < 16384; i += 256) ((float4*)(ws + OFF_FEAT))[i] = z4;
  for (int i = t; i < 2048; i += 256) ((float4*)(ws + OFF_GWP))[i] = z4;
}

// ---------------- bcast (fp32 Z + bf16 Xcat) + gwp partial accumulation (R9) ----------------
__global__ __launch_bounds__(256) void k_bcast(float* __restrict__ ws) {
  __shared__ float pr[1024];
  unsigned short* xh = (unsigned short*)(ws + OFF_XH);
  unsigned short* xl = (unsigned short*)(ws + OFF_XL);
  int t = threadIdx.x;
  int i4 = blockIdx.x * 256 + t;
  int b = i4 >> 14;
  int l = t & 127;
  float w0 = ws[OFF_W + 0 * B + b], w1 = ws[OFF_W + 1 * B + b];
  float w2 = ws[OFF_W + 2 * B + b], w3 = ws[OFF_W + 3 * B + b];
  const float4* mr = (const float4*)(ws + OFF_OR);
  const float4* mi = (const float4*)(ws + OFF_OI);
  const int MS = BSD / 4;
  int row = i4 >> 7;
  int d4 = (i4 & 127) * 4;
  float4 r0 = mr[i4], r1 = mr[i4 + MS], r2 = mr[i4 + 2 * MS], r3 = mr[i4 + 3 * MS];
  float gvR[4];
  gvR[0] = w0 * r0.x + w1 * r1.x + w2 * r2.x + w3 * r3.x;
  gvR[1] = w0 * r0.y + w1 * r1.y + w2 * r2.y + w3 * r3.y;
  gvR[2] = w0 * r0.z + w1 * r1.z + w2 * r2.z + w3 * r3.z;
  gvR[3] = w0 * r0.w + w1 * r1.w + w2 * r2.w + w3 * r3.w;
  ((float4*)(ws + OFF_ZR))[i4] = (float4){gvR[0], gvR[1], gvR[2], gvR[3]};
  us4 hh, hl;
#pragma unroll
  for (int j = 0; j < 4; ++j) {
    unsigned short h = f2bf(gvR[j]); hh[j] = h; hl[j] = f2bf(gvR[j] - bf2f(h));
  }
  *(us4*)(xh + (size_t)row * 1024 + d4) = hh;
  *(us4*)(xl + (size_t)row * 1024 + d4) = hl;
  float4 s0 = mi[i4], s1 = mi[i4 + MS], s2 = mi[i4 + 2 * MS], s3 = mi[i4 + 3 * MS];
  float gvI[4];
  gvI[0] = w0 * s0.x + w1 * s1.x + w2 * s2.x + w3 * s3.x;
  gvI[1] = w0 * s0.y + w1 * s1.y + w2 * s2.y + w3 * s3.y;
  gvI[2] = w0 * s0.z + w1 * s1.z + w2 * s2.z + w3 * s3.z;
  gvI[3] = w0 * s0.w + w1 * s1.w + w2 * s2.w + w3 * s3.w;
  ((float4*)(ws + OFF_ZI))[i4] = (float4){gvI[0], gvI[1], gvI[2], gvI[3]};
#pragma unroll
  for (int j = 0; j < 4; ++j) {
    unsigned short h = f2bf(gvI[j]); hh[j] = h; hl[j] = f2bf(gvI[j] - bf2f(h));
  }
  *(us4*)(xh + (size_t)row * 1024 + 512 + d4) = hh;
  *(us4*)(xl + (size_t)row * 1024 + 512 + d4) = hl;
  if (t < 128) {
#pragma unroll
    for (int j = 0; j < 4; ++j) { pr[l * 4 + j] = gvR[j]; pr[512 + l * 4 + j] = gvI[j]; }
  }
  __syncthreads();
  if (t >= 128) {
#pragma unroll
    for (int j = 0; j < 4; ++j) { pr[l * 4 + j] += gvR[j]; pr[512 + l * 4 + j] += gvI[j]; }
  }
  __syncthreads();
  for (int pp = t; pp < 1024; pp += 256)
    atomicAdd(ws + OFF_GWP + b * 1024 + pp, pr[pp] * (1.0f / S));
}

// ---------------- halt + ACT accumulate (fused; cum double-buffered) (R9) ----------------
__global__ __launch_bounds__(256) void k_acchalt(float* __restrict__ ws,
                                                 const float* __restrict__ w_halt,
                                                 const float* __restrict__ b_halt,
                                                 const float* __restrict__ cumr,
                                                 float* __restrict__ cumw) {
  __shared__ float sred[4];
  int t = threadIdx.x;
  int i4 = blockIdx.x * 256 + t;
  int b = i4 >> 14;
  float4 g = *(const float4*)(ws + OFF_GWP + b * 1024 + t * 4);
  float4 wv = *(const float4*)(w_halt + t * 4);
  float s = g.x * wv.x + g.y * wv.y + g.z * wv.z + g.w * wv.w;
  for (int o = 1; o < 64; o <<= 1) s += __shfl_xor(s, o);
  if ((t & 63) == 0) sred[t >> 6] = s;
  __syncthreads();
  float tot = sred[0] + sred[1] + sred[2] + sred[3];
  float p = 1.f / (1.f + expf(-(tot + b_halt[0])));
  float cum = cumr[b];
  float still = (cum < THRESH) ? 1.f : 0.f;
  bool nh = ((cum + p) >= THRESH) && (cum < THRESH);
  float wt = (nh ? (1.f - cum) : p) * still;
  if (((blockIdx.x & 63) == 0) && t == 0) cumw[b] = cum + wt;
  float4 z = ((const float4*)(ws + OFF_ZR))[i4];
  float4 a = ((float4*)(ws + OFF_AR))[i4];
  a.x += wt * z.x; a.y += wt * z.y; a.z += wt * z.z; a.w += wt * z.w;
  ((float4*)(ws + OFF_AR))[i4] = a;
  z = ((const float4*)(ws + OFF_ZI))[i4];
  a = ((float4*)(ws + OFF_AI))[i4];
  a.x += wt * z.x; a.y += wt * z.y; a.z += wt * z.z; a.w += wt * z.w;
  ((float4*)(ws + OFF_AI))[i4] = a;
}

// ---------------- output (R1) ----------------
__global__ __launch_bounds__(256) void k_out(const float* __restrict__ ws,
                                             float* __restrict__ out) {
  int i4 = blockIdx.x * 256 + threadIdx.x;
  ((float4*)out)[i4] = ((const float4*)(ws + OFF_AR))[i4];
  ((float4*)out)[i4 + BSD / 4] = ((const float4*)(ws + OFF_AI))[i4];
}

extern "C" void kernel_launch(void* const* d_in, const int* in_sizes, int n_in,
                              void* d_out, int out_size, void* d_ws, size_t ws_size,
                              hipStream_t stream) {
  (void)in_sizes; (void)n_in; (void)out_size; (void)ws_size;
  const float* x_real  = (const float*)d_in[0];
  const float* x_imag  = (const float*)d_in[1];
  const float* Wq_r    = (const float*)d_in[2];
  const float* Wq_i    = (const float*)d_in[3];
  const float* Wk_r    = (const float*)d_in[4];
  const float* Wk_i    = (const float*)d_in[5];
  const float* Wv_r    = (const float*)d_in[6];
  const float* Wv_i    = (const float*)d_in[7];
  const float* mod_bias = (const float*)d_in[8];
  const float* ln_scale = (const float*)d_in[9];
  const float* ln_shift = (const float*)d_in[10];
  const float* w_sal   = (const float*)d_in[11];
  const float* gru_Wih = (const float*)d_in[12];
  const float* gru_Whh = (const float*)d_in[13];
  const float* gru_bih = (const float*)d_in[14];
  const float* gru_bhh = (const float*)d_in[15];
  const float* bias_W  = (const float*)d_in[16];
  const float* bias_b  = (const float*)d_in[17];
  const float* w_halt  = (const float*)d_in[18];
  const float* b_halt  = (const float*)d_in[19];
  float* ws = (float*)d_ws;
  float* out = (float*)d_out;

  k_wprep<<<dim3(8, 8, 24), 256, 0, stream>>>(Wq_r, Wq_i, Wk_r, Wk_i, Wv_r, Wv_i, ws);
  k_init<<<512, 256, 0, stream>>>(x_real, x_imag, ws);
  k_gwp<<<32, 256, 0, stream>>>(ws + OFF_ZR, ws + OFF_ZI, ws + OFF_GWP);
  for (int step = 0; step < DEPTH; ++step) {
    const float* hold = ws + ((step & 1) ? OFF_H1 : OFF_H0);
    float* hnew = ws + ((step & 1) ? OFF_H0 : OFF_H1);
    const float* cumr = ws + ((step & 1) ? OFF_CUM2 : OFF_CUM);
    float* cumw = ws + ((step & 1) ? OFF_CUM : OFF_CUM2);
    k_qkgru<<<dim3(4, 8, 18), 256, 0, stream>>>(ws, ws + OFF_GWP, hold, hnew,
                                                gru_Wih, gru_Whh, gru_bih, gru_bhh);
    k_vattn<<<384, 256, 0, stream>>>(ws);
    k_pv<<<dim3(4, 32), 256, 0, stream>>>(ws);
    k_modlnfeat<<<128, 256, 0, stream>>>(ws, mod_bias, ln_scale, ln_shift);
    k_wsel<<<1, 256, 0, stream>>>(ws, hnew, bias_W, bias_b, w_sal);
    k_bcast<<<512, 256, 0, stream>>>(ws);
    k_acchalt<<<512, 256, 0, stream>>>(ws, w_halt, b_halt, cumr, cumw);
  }
  k_out<<<512, 256, 0, stream>>>(ws, out);
}

// Round 7
// 3729.251 us; speedup vs baseline: 1.1369x; 1.1369x over previous
//
#include <hip/hip_runtime.h>
#include <math.h>

#define B 8
#define S 128
#define D 512
#define M 4
#define BS 1024
#define BSD 524288          // B*S*D
#define DEPTH 16
#define THRESH 0.9999f
#define EPS 1e-6f
#define SCALE 0.04419417382415922f   // D^-0.5

typedef float floatx4 __attribute__((ext_vector_type(4)));
typedef short s8v __attribute__((ext_vector_type(8)));
typedef unsigned short us4 __attribute__((ext_vector_type(4)));

__device__ __forceinline__ unsigned short f2bf(float f) {
  unsigned int u = __float_as_uint(f);
  u += 0x7FFFu + ((u >> 16) & 1u);          // round-to-nearest-even
  return (unsigned short)(u >> 16);
}
__device__ __forceinline__ float bf2f(unsigned short h) {
  return __uint_as_float((unsigned int)h << 16);
}

// async global->LDS, 16B per lane, linear LDS dest (wave-uniform base + lane*16)
__device__ __forceinline__ void gll16(const void* g, void* l) {
  __builtin_amdgcn_global_load_lds(
      (const __attribute__((address_space(1))) unsigned int*)g,
      (__attribute__((address_space(3))) unsigned int*)l, 16, 0, 0);
}

// ---------------- workspace layout (float-slot offsets) ----------------
#define OFF_ZR   0
#define OFF_ZI   (1*BSD)
#define OFF_AR   (2*BSD)
#define OFF_AI   (3*BSD)
#define OFF_OR   (4*BSD)            // [M][B][S][D] fp32 = 4*BSD
#define OFF_OI   (8*BSD)
#define OFF_FEAT (12*BSD)           // 65536
#define OFF_GWP  (12*BSD + 65536)   // 8192
#define OFF_H0   (12*BSD + 73728)
#define OFF_H1   (12*BSD + 77824)
#define OFF_CUM  (12*BSD + 81920)   // 8
#define OFF_W    (12*BSD + 81928)   // 32
#define OFF_WT   (12*BSD + 81960)   // 8
#define OFF_CUM2 (12*BSD + 81968)   // 8
// bf16 annex (slots)
#define OFF_XH   (12*BSD + 90112)           // xcat hi [1024][1024] = 1 BSD
#define OFF_XL   (OFF_XH + 1*BSD)
#define OFF_WH   (OFF_XH + 2*BSD)           // 24 planes [512][512] hi = 6 BSD
#define OFF_WL   (OFF_XH + 8*BSD)
#define OFF_QCH  (OFF_XH + 14*BSD)          // Qcat hi [M][1024][1024] = 4 BSD
#define OFF_QCL  (OFF_XH + 18*BSD)
#define OFF_KCH  (OFF_XH + 22*BSD)
#define OFF_KCL  (OFF_XH + 26*BSD)
#define OFF_VTH  (OFF_XH + 30*BSD)          // Vt hi [2ri][M][512][1024] = 4 BSD
#define OFF_VTL  (OFF_XH + 34*BSD)
#define OFF_PH   (OFF_XH + 38*BSD)          // P hi [32][128][128] = 262144 slots
#define OFF_PL   (OFF_PH + 262144)
// end ~= 107.3 MB (R6/R8 proven)

// ---------------- init: fp32 carry + bf16 hi/lo Xcat + zero FEAT/GWP/CUMs ----------------
__global__ __launch_bounds__(256) void k_init(const float* __restrict__ xr,
                                              const float* __restrict__ xi,
                                              float* __restrict__ ws) {
  unsigned short* xh = (unsigned short*)(ws + OFF_XH);
  unsigned short* xl = (unsigned short*)(ws + OFF_XL);
  int i4 = blockIdx.x * 256 + threadIdx.x;      // BSD/4
  float4 a = ((const float4*)xr)[i4];
  float4 b = ((const float4*)xi)[i4];
  ((float4*)(ws + OFF_ZR))[i4] = a;
  ((float4*)(ws + OFF_ZI))[i4] = b;
  float4 z = {0.f, 0.f, 0.f, 0.f};
  ((float4*)(ws + OFF_AR))[i4] = z;
  ((float4*)(ws + OFF_AI))[i4] = z;
  int row = i4 >> 7;
  int d4 = (i4 & 127) * 4;
  float av[4] = {a.x, a.y, a.z, a.w}, bv[4] = {b.x, b.y, b.z, b.w};
  us4 hh, hl;
#pragma unroll
  for (int j = 0; j < 4; ++j) {
    unsigned short h = f2bf(av[j]); hh[j] = h; hl[j] = f2bf(av[j] - bf2f(h));
  }
  *(us4*)(xh + (size_t)row * 1024 + d4) = hh;
  *(us4*)(xl + (size_t)row * 1024 + d4) = hl;
#pragma unroll
  for (int j = 0; j < 4; ++j) {
    unsigned short h = f2bf(bv[j]); hh[j] = h; hl[j] = f2bf(bv[j] - bf2f(h));
  }
  *(us4*)(xh + (size_t)row * 1024 + 512 + d4) = hh;
  *(us4*)(xl + (size_t)row * 1024 + 512 + d4) = hl;
  if (i4 < (B * D) / 4) {
    ((float4*)(ws + OFF_H0))[i4] = z;
    ((float4*)(ws + OFF_H1))[i4] = z;
  }
  if (i4 < 16384) ((float4*)(ws + OFF_FEAT))[i4] = z;
  if (i4 < 2048)  ((float4*)(ws + OFF_GWP))[i4] = z;
  if (i4 < B) { ws[OFF_CUM + i4] = 0.f; ws[OFF_CUM2 + i4] = 0.f; }
}

// ---------------- weight prep (R6, proven) ----------------
__global__ __launch_bounds__(256) void k_wprep(const float* __restrict__ Wqr,
                                               const float* __restrict__ Wqi,
                                               const float* __restrict__ Wkr,
                                               const float* __restrict__ Wki,
                                               const float* __restrict__ Wvr,
                                               const float* __restrict__ Wvi,
                                               float* __restrict__ ws) {
  __shared__ float lt[64][65];
  unsigned short* wh = (unsigned short*)(ws + OFF_WH);
  unsigned short* wl = (unsigned short*)(ws + OFF_WL);
  int z = blockIdx.z, m = z / 6, idx = z % 6;
  const float* Wsrc;
  switch (idx) {
    case 0:  Wsrc = Wqr; break;
    case 1:  Wsrc = Wqi; break;
    case 2:  Wsrc = Wkr; break;
    case 3:  Wsrc = Wki; break;
    case 4:  Wsrc = Wvr; break;
    default: Wsrc = Wvi; break;
  }
  Wsrc += (size_t)m * D * D;
  int k0 = blockIdx.x * 64, n0 = blockIdx.y * 64;
  int tx = threadIdx.x & 63, ty = threadIdx.x >> 6;
#pragma unroll
  for (int i = 0; i < 16; ++i) {
    int kl = ty + i * 4;
    lt[kl][tx] = Wsrc[(size_t)(k0 + kl) * D + n0 + tx];
  }
  __syncthreads();
  unsigned short* whp = wh + (size_t)z * 262144;
  unsigned short* wlp = wl + (size_t)z * 262144;
#pragma unroll
  for (int i = 0; i < 16; ++i) {
    int nl = ty + i * 4;
    float v = lt[tx][nl];
    unsigned short h = f2bf(v);
    whp[(size_t)(n0 + nl) * 512 + k0 + tx] = h;
    wlp[(size_t)(n0 + nl) * 512 + k0 + tx] = f2bf(v - bf2f(h));
  }
}

// ---------------- gwp (pre-loop only) ----------------
__global__ __launch_bounds__(256) void k_gwp(const float* __restrict__ zr,
                                             const float* __restrict__ zi,
                                             float* __restrict__ gwp) {
  int idx = blockIdx.x * 256 + threadIdx.x;
  int b = idx >> 10;
  int f = idx & 1023;
  const float* src = (f < D) ? (zr + b * S * D + f) : (zi + b * S * D + (f - D));
  float s = 0.f;
#pragma unroll 8
  for (int ss = 0; ss < S; ++ss) s += src[ss * D];
  gwp[idx] = s * (1.0f / S);
}

// ---------------- k_qk: Q/K GEMMs only (R16-proven; 512 blocks = 2 CU-rounds) ----------------
__global__ __launch_bounds__(256) void k_qk(float* __restrict__ ws) {
  __shared__ __align__(16) unsigned short Ah[128 * 32], Al[128 * 32];
  __shared__ __align__(16) unsigned short Bh[128 * 32], Bl[128 * 32];
  int t = threadIdx.x;
  const unsigned short* xh = (const unsigned short*)(ws + OFF_XH);
  const unsigned short* xl = (const unsigned short*)(ws + OFF_XL);
  const unsigned short* wh = (const unsigned short*)(ws + OFF_WH);
  const unsigned short* wl = (const unsigned short*)(ws + OFF_WL);
  int z = blockIdx.z, m = z >> 2, w6 = z & 3;
  int pair = (w6 >> 1) * 2;
  int p1 = m * 6 + pair + (w6 & 1);
  int p2 = m * 6 + pair + ((w6 & 1) ^ 1);
  bool neg2 = ((w6 & 1) == 0);               // real-output GEMMs negate second K-half
  const unsigned short* PH1 = wh + (size_t)p1 * 262144;
  const unsigned short* PL1 = wl + (size_t)p1 * 262144;
  const unsigned short* PH2 = wh + (size_t)p2 * 262144;
  const unsigned short* PL2 = wl + (size_t)p2 * 262144;

  int row0 = blockIdx.y * 128;    // X rows
  int col0 = blockIdx.x * 128;    // W cols
  int lane = t & 63, w = t >> 6;
  int wr = w >> 1, wc = w & 1;
  int q = lane >> 4, r = lane & 15;
  int srow = t >> 2;
  int skoff = (t & 3) * 8;
  size_t wrow1 = (size_t)(col0 + srow) * 512 + skoff;
  size_t wrow2 = (size_t)(col0 + 64 + srow) * 512 + skoff;
  size_t xrow1 = (size_t)(row0 + srow) * 1024 + skoff;
  size_t xrow2 = (size_t)(row0 + 64 + srow) * 1024 + skoff;
  const s8v sgn = {(short)0x8000, (short)0x8000, (short)0x8000, (short)0x8000,
                   (short)0x8000, (short)0x8000, (short)0x8000, (short)0x8000};

  floatx4 acc[4][4];
#pragma unroll
  for (int i = 0; i < 4; ++i)
#pragma unroll
    for (int j = 0; j < 4; ++j) acc[i][j] = (floatx4){0.f, 0.f, 0.f, 0.f};

  for (int k0 = 0; k0 < 1024; k0 += 32) {
    const unsigned short *WgH, *WgL;
    int kk = k0;
    bool xon = false;
    if (k0 < 512) { WgH = PH1; WgL = PL1; }
    else          { WgH = PH2; WgL = PL2; kk = k0 - 512; xon = neg2; }
    gll16(xh + xrow1 + k0, (char*)Ah + t * 16);
    gll16(xh + xrow2 + k0, (char*)Ah + 4096 + t * 16);
    gll16(xl + xrow1 + k0, (char*)Al + t * 16);
    gll16(xl + xrow2 + k0, (char*)Al + 4096 + t * 16);
    gll16(WgH + wrow1 + kk, (char*)Bh + t * 16);
    gll16(WgH + wrow2 + kk, (char*)Bh + 4096 + t * 16);
    gll16(WgL + wrow1 + kk, (char*)Bl + t * 16);
    gll16(WgL + wrow2 + kk, (char*)Bl + 4096 + t * 16);
    __syncthreads();
    s8v ah[4], al[4], bh[4], bl[4];
#pragma unroll
    for (int i = 0; i < 4; ++i) {
      int ro = (wr * 64 + i * 16 + r) * 32 + q * 8;
      ah[i] = *(const s8v*)((const short*)Ah + ro);
      al[i] = *(const s8v*)((const short*)Al + ro);
    }
#pragma unroll
    for (int j = 0; j < 4; ++j) {
      int ro = (wc * 64 + j * 16 + r) * 32 + q * 8;
      bh[j] = *(const s8v*)((const short*)Bh + ro);
      bl[j] = *(const s8v*)((const short*)Bl + ro);
    }
    if (xon) {
#pragma unroll
      for (int j = 0; j < 4; ++j) { bh[j] = bh[j] ^ sgn; bl[j] = bl[j] ^ sgn; }
    }
#pragma unroll
    for (int i = 0; i < 4; ++i)
#pragma unroll
      for (int j = 0; j < 4; ++j) {
        acc[i][j] = __builtin_amdgcn_mfma_f32_16x16x32_bf16(ah[i], bh[j], acc[i][j], 0, 0, 0);
        acc[i][j] = __builtin_amdgcn_mfma_f32_16x16x32_bf16(ah[i], bl[j], acc[i][j], 0, 0, 0);
        acc[i][j] = __builtin_amdgcn_mfma_f32_16x16x32_bf16(al[i], bh[j], acc[i][j], 0, 0, 0);
      }
    __syncthreads();
  }
  unsigned short *dh, *dl;
  if (w6 < 2) { dh = (unsigned short*)(ws + OFF_QCH); dl = (unsigned short*)(ws + OFF_QCL); }
  else        { dh = (unsigned short*)(ws + OFF_KCH); dl = (unsigned short*)(ws + OFF_KCL); }
  int half = (w6 & 1) * 512;
  size_t base = (size_t)m * 1024 * 1024;
#pragma unroll
  for (int i = 0; i < 4; ++i)
#pragma unroll
    for (int j = 0; j < 4; ++j) {
      int rowb = row0 + wr * 64 + i * 16 + q * 4;
      int colb = col0 + wc * 64 + j * 16 + r;
#pragma unroll
      for (int reg = 0; reg < 4; ++reg) {
        float v = acc[i][j][reg];
        unsigned short h = f2bf(v);
        size_t idx = base + (size_t)(rowb + reg) * 1024 + half + colb;
        dh[idx] = h;
        dl[idx] = f2bf(v - bf2f(h));
      }
    }
}

// ---------------- k_vattn: attn (blk<128, 32-row split) + V GEMM (128..383) + GRU (384..447) ----------------
// R18: R16's co-residency (GRU+attn+V all dispatched at t~0, 448 blocks <= 2/CU) with
// R17's verified 32-row attn split. attn first (critical path to k_pv); V & GRU backfill.
__global__ __launch_bounds__(256) void k_vattn(float* __restrict__ ws,
                                               const float* __restrict__ gwp,
                                               const float* __restrict__ hold,
                                               float* __restrict__ hnew,
                                               const float* __restrict__ Wih,
                                               const float* __restrict__ Whh,
                                               const float* __restrict__ bih,
                                               const float* __restrict__ bhh) {
  __shared__ __align__(16) unsigned short Ah[128 * 32], Al[128 * 32];
  __shared__ __align__(16) unsigned short Bh[128 * 32], Bl[128 * 32];
  __shared__ float rmax[32][4];
  __shared__ float rsum[32][4];
  int t = threadIdx.x;
  int blk = blockIdx.x;

  if (blk >= 384) {
    // ---- GRU path (R7-proven body; LDS overlaid) ----
    float* xbuf = (float*)Ah;                 // 1024 floats
    float* hbuf = (float*)Al;                 // 512 floats
    float (*red)[64][4] = (float (*)[64][4])Bh;
    int gid = blk - 384;
    int b = gid >> 3;
    int c0 = (gid & 7) * 64;
    int td = t & 63, ks = t >> 6;
    for (int f = t; f < 1024; f += 256) xbuf[f] = gwp[b * 1024 + f];
    for (int d2 = t; d2 < 512; d2 += 256) hbuf[d2] = hold[b * 512 + d2];
    __syncthreads();
    float accR = 0.f, accZ = 0.f, accXn = 0.f, accHn = 0.f;
    int kbeg = ks * 384, kend = kbeg + 384;
#pragma unroll 4
    for (int kk = kbeg; kk < kend; ++kk) {
      bool ih = kk < 1024;
      float x = ih ? xbuf[kk] : hbuf[kk - 1024];
      const float* base = ih ? (Wih + (size_t)kk * 1536) : (Whh + (size_t)(kk - 1024) * 1536);
      float wr = base[c0 + td];
      float wz = base[512 + c0 + td];
      float wn = base[1024 + c0 + td];
      accR += x * wr;
      accZ += x * wz;
      if (ih) accXn += x * wn; else accHn += x * wn;
    }
    red[ks][td][0] = accR;
    red[ks][td][1] = accZ;
    red[ks][td][2] = accXn;
    red[ks][td][3] = accHn;
    __syncthreads();
    if (t < 64) {
      int c = c0 + t;
      float r_ = 0.f, z_ = 0.f, xn = 0.f, hn = 0.f;
#pragma unroll
      for (int s = 0; s < 4; ++s) {
        r_ += red[s][t][0]; z_ += red[s][t][1]; xn += red[s][t][2]; hn += red[s][t][3];
      }
      r_ += bih[c] + bhh[c];
      z_ += bih[512 + c] + bhh[512 + c];
      xn += bih[1024 + c];
      hn += bhh[1024 + c];
      float r = 1.f / (1.f + expf(-r_));
      float z = 1.f / (1.f + expf(-z_));
      float n = tanhf(xn + r * hn);
      hnew[b * 512 + c] = (1.f - z) * n + z * hbuf[c];
    }
    return;
  }

  if (blk < 128) {
    // ---- attn path: 32 Q-rows x 128 K-cols (R17-verified body) ----
    const unsigned short* qch = (const unsigned short*)(ws + OFF_QCH);
    const unsigned short* qcl = (const unsigned short*)(ws + OFF_QCL);
    const unsigned short* kch = (const unsigned short*)(ws + OFF_KCH);
    const unsigned short* kcl = (const unsigned short*)(ws + OFF_KCL);
    unsigned short* ph = (unsigned short*)(ws + OFF_PH);
    unsigned short* pl = (unsigned short*)(ws + OFF_PL);
    int mb = blk >> 2, rq = blk & 3;
    int r0 = rq * 32;
    size_t gbase = (size_t)mb * 128 * 1024;
    int lane = t & 63, wc = t >> 6;
    int q = lane >> 4, r = lane & 15;
    int at = t & 127;                      // A-stage slot (32 rows x 4 chunks)
    size_t arow = gbase + (size_t)(r0 + (at >> 2)) * 1024 + (at & 3) * 8;
    int srow = t >> 2, skoff = (t & 3) * 8;
    size_t brow1 = gbase + (size_t)srow * 1024 + skoff;
    size_t brow2 = gbase + (size_t)(64 + srow) * 1024 + skoff;

    floatx4 acc[2][2];
#pragma unroll
    for (int i = 0; i < 2; ++i)
#pragma unroll
      for (int j = 0; j < 2; ++j) acc[i][j] = (floatx4){0.f, 0.f, 0.f, 0.f};

    for (int k0 = 0; k0 < 1024; k0 += 32) {
      // waves 0,1 stage A-hi; waves 2,3 stage A-lo (uniform branch per wave)
      if (t < 128) gll16(qch + arow + k0, (char*)Ah + at * 16);
      else         gll16(qcl + arow + k0, (char*)Al + at * 16);
      gll16(kch + brow1 + k0, (char*)Bh + t * 16);
      gll16(kch + brow2 + k0, (char*)Bh + 4096 + t * 16);
      gll16(kcl + brow1 + k0, (char*)Bl + t * 16);
      gll16(kcl + brow2 + k0, (char*)Bl + 4096 + t * 16);
      __syncthreads();
      s8v ah[2], al[2], bh[2], bl[2];
#pragma unroll
      for (int i = 0; i < 2; ++i) {
        int ro = (i * 16 + r) * 32 + q * 8;
        ah[i] = *(const s8v*)((const short*)Ah + ro);
        al[i] = *(const s8v*)((const short*)Al + ro);
      }
#pragma unroll
      for (int j = 0; j < 2; ++j) {
        int ro = (wc * 32 + j * 16 + r) * 32 + q * 8;
        bh[j] = *(const s8v*)((const short*)Bh + ro);
        bl[j] = *(const s8v*)((const short*)Bl + ro);
      }
#pragma unroll
      for (int i = 0; i < 2; ++i)
#pragma unroll
        for (int j = 0; j < 2; ++j) {
          acc[i][j] = __builtin_amdgcn_mfma_f32_16x16x32_bf16(ah[i], bh[j], acc[i][j], 0, 0, 0);
          acc[i][j] = __builtin_amdgcn_mfma_f32_16x16x32_bf16(ah[i], bl[j], acc[i][j], 0, 0, 0);
          acc[i][j] = __builtin_amdgcn_mfma_f32_16x16x32_bf16(al[i], bh[j], acc[i][j], 0, 0, 0);
        }
      __syncthreads();
    }
#pragma unroll
    for (int i = 0; i < 2; ++i)
#pragma unroll
      for (int j = 0; j < 2; ++j)
#pragma unroll
        for (int reg = 0; reg < 4; ++reg) acc[i][j][reg] *= SCALE;
#pragma unroll
    for (int i = 0; i < 2; ++i)
#pragma unroll
      for (int reg = 0; reg < 4; ++reg) {
        float mx = fmaxf(acc[i][0][reg], acc[i][1][reg]);
        for (int o = 1; o < 16; o <<= 1) mx = fmaxf(mx, __shfl_xor(mx, o));
        if (r == 0) rmax[i * 16 + q * 4 + reg][wc] = mx;
      }
    __syncthreads();
#pragma unroll
    for (int i = 0; i < 2; ++i)
#pragma unroll
      for (int reg = 0; reg < 4; ++reg) {
        int row = i * 16 + q * 4 + reg;
        float gmx = fmaxf(fmaxf(rmax[row][0], rmax[row][1]),
                          fmaxf(rmax[row][2], rmax[row][3]));
        float sm = 0.f;
#pragma unroll
        for (int j = 0; j < 2; ++j) {
          float e = __expf(acc[i][j][reg] - gmx);
          acc[i][j][reg] = e;
          sm += e;
        }
        for (int o = 1; o < 16; o <<= 1) sm += __shfl_xor(sm, o);
        if (r == 0) rsum[row][wc] = sm;
      }
    __syncthreads();
#pragma unroll
    for (int i = 0; i < 2; ++i)
#pragma unroll
      for (int reg = 0; reg < 4; ++reg) {
        int row = i * 16 + q * 4 + reg;
        float inv = 1.f / (rsum[row][0] + rsum[row][1] + rsum[row][2] + rsum[row][3]);
        size_t rb = (size_t)(mb * 128 + r0 + row) * 128;
#pragma unroll
        for (int j = 0; j < 2; ++j) {
          float p = acc[i][j][reg] * inv;
          unsigned short h = f2bf(p);
          size_t idx = rb + wc * 32 + j * 16 + r;
          ph[idx] = h;
          pl[idx] = f2bf(p - bf2f(h));
        }
      }
    return;
  }

  // ---- V GEMM path (R13-proven body, w6 in {4,5}) ----
  const unsigned short* xh = (const unsigned short*)(ws + OFF_XH);
  const unsigned short* xl = (const unsigned short*)(ws + OFF_XL);
  const unsigned short* wh = (const unsigned short*)(ws + OFF_WH);
  const unsigned short* wl = (const unsigned short*)(ws + OFF_WL);
  int vblk = blk - 128;
  int plane = vblk >> 5, m = plane >> 1, w6 = 4 + (plane & 1);
  int bx = (vblk & 31) >> 3, by = vblk & 7;
  int p1 = m * 6 + 4 + (w6 & 1);
  int p2 = m * 6 + 4 + ((w6 & 1) ^ 1);
  bool neg2 = ((w6 & 1) == 0);
  const unsigned short* PH1 = wh + (size_t)p1 * 262144;
  const unsigned short* PL1 = wl + (size_t)p1 * 262144;
  const unsigned short* PH2 = wh + (size_t)p2 * 262144;
  const unsigned short* PL2 = wl + (size_t)p2 * 262144;

  int row0 = bx * 128;     // W cols (Vt rows)
  int col0 = by * 128;     // X rows (Vt cols)
  int lane = t & 63, w = t >> 6;
  int wr = w >> 1, wc = w & 1;
  int q = lane >> 4, r = lane & 15;
  int srow = t >> 2;
  int skoff = (t & 3) * 8;
  size_t wrow1 = (size_t)(row0 + srow) * 512 + skoff;
  size_t wrow2 = (size_t)(row0 + 64 + srow) * 512 + skoff;
  size_t xrow1 = (size_t)(col0 + srow) * 1024 + skoff;
  size_t xrow2 = (size_t)(col0 + 64 + srow) * 1024 + skoff;
  const s8v sgn = {(short)0x8000, (short)0x8000, (short)0x8000, (short)0x8000,
                   (short)0x8000, (short)0x8000, (short)0x8000, (short)0x8000};

  floatx4 acc[4][4];
#pragma unroll
  for (int i = 0; i < 4; ++i)
#pragma unroll
    for (int j = 0; j < 4; ++j) acc[i][j] = (floatx4){0.f, 0.f, 0.f, 0.f};

  for (int k0 = 0; k0 < 1024; k0 += 32) {
    const unsigned short *WgH, *WgL;
    int kk = k0;
    bool xon = false;
    if (k0 < 512) { WgH = PH1; WgL = PL1; }
    else          { WgH = PH2; WgL = PL2; kk = k0 - 512; xon = neg2; }
    gll16(WgH + wrow1 + kk, (char*)Ah + t * 16);
    gll16(WgH + wrow2 + kk, (char*)Ah + 4096 + t * 16);
    gll16(WgL + wrow1 + kk, (char*)Al + t * 16);
    gll16(WgL + wrow2 + kk, (char*)Al + 4096 + t * 16);
    gll16(xh + xrow1 + k0, (char*)Bh + t * 16);
    gll16(xh + xrow2 + k0, (char*)Bh + 4096 + t * 16);
    gll16(xl + xrow1 + k0, (char*)Bl + t * 16);
    gll16(xl + xrow2 + k0, (char*)Bl + 4096 + t * 16);
    __syncthreads();
    s8v ah[4], al[4], bh[4], bl[4];
#pragma unroll
    for (int i = 0; i < 4; ++i) {
      int ro = (wr * 64 + i * 16 + r) * 32 + q * 8;
      ah[i] = *(const s8v*)((const short*)Ah + ro);
      al[i] = *(const s8v*)((const short*)Al + ro);
    }
#pragma unroll
    for (int j = 0; j < 4; ++j) {
      int ro = (wc * 64 + j * 16 + r) * 32 + q * 8;
      bh[j] = *(const s8v*)((const short*)Bh + ro);
      bl[j] = *(const s8v*)((const short*)Bl + ro);
    }
    if (xon) {                                 // sign-flip weight-side fragments (A side)
#pragma unroll
      for (int i = 0; i < 4; ++i) { ah[i] = ah[i] ^ sgn; al[i] = al[i] ^ sgn; }
    }
#pragma unroll
    for (int i = 0; i < 4; ++i)
#pragma unroll
      for (int j = 0; j < 4; ++j) {
        acc[i][j] = __builtin_amdgcn_mfma_f32_16x16x32_bf16(ah[i], bh[j], acc[i][j], 0, 0, 0);
        acc[i][j] = __builtin_amdgcn_mfma_f32_16x16x32_bf16(ah[i], bl[j], acc[i][j], 0, 0, 0);
        acc[i][j] = __builtin_amdgcn_mfma_f32_16x16x32_bf16(al[i], bh[j], acc[i][j], 0, 0, 0);
      }
    __syncthreads();
  }
  unsigned short* dh = (unsigned short*)(ws + OFF_VTH);
  unsigned short* dl = (unsigned short*)(ws + OFF_VTL);
  size_t base = (size_t)((w6 & 1) * 4 + m) * 512 * 1024;
#pragma unroll
  for (int i = 0; i < 4; ++i)
#pragma unroll
    for (int j = 0; j < 4; ++j) {
      int rowb = row0 + wr * 64 + i * 16 + q * 4;
      int colb = col0 + wc * 64 + j * 16 + r;
#pragma unroll
      for (int reg = 0; reg < 4; ++reg) {
        float v = acc[i][j][reg];
        unsigned short h = f2bf(v);
        size_t idx = base + (size_t)(rowb + reg) * 1024 + colb;
        dh[idx] = h;
        dl[idx] = f2bf(v - bf2f(h));
      }
    }
}

// ---------------- PV: O = P @ Vt^T (bf16x3 MFMA), fp32 out (R13 single-buffer) ----------------
__global__ __launch_bounds__(256) void k_pv(float* __restrict__ ws) {
  __shared__ __align__(16) unsigned short Ph_[128 * 32], Pl_[128 * 32];
  __shared__ __align__(16) unsigned short VrH[128 * 32], VrL[128 * 32];
  __shared__ __align__(16) unsigned short ViH[128 * 32], ViL[128 * 32];
  const unsigned short* ph = (const unsigned short*)(ws + OFF_PH);
  const unsigned short* pl = (const unsigned short*)(ws + OFF_PL);
  const unsigned short* vth = (const unsigned short*)(ws + OFF_VTH);
  const unsigned short* vtl = (const unsigned short*)(ws + OFF_VTL);
  int mb = blockIdx.y, m = mb >> 3, b = mb & 7;
  int col0 = blockIdx.x * 128;
  int t = threadIdx.x, lane = t & 63, w = t >> 6;
  int wr = w >> 1, wc = w & 1;
  int q = lane >> 4, r = lane & 15;
  int srow = t >> 2;
  int skoff = (t & 3) * 8;
  size_t prow1 = (size_t)(mb * 128 + srow) * 128 + skoff;
  size_t prow2 = (size_t)(mb * 128 + 64 + srow) * 128 + skoff;
  size_t vbr1 = ((size_t)(m * 512) + col0 + srow) * 1024 + b * 128 + skoff;
  size_t vbr2 = ((size_t)(m * 512) + col0 + 64 + srow) * 1024 + b * 128 + skoff;
  size_t vplane_i = (size_t)4 * 512 * 1024;

  floatx4 accR[4][4], accI[4][4];
#pragma unroll
  for (int i = 0; i < 4; ++i)
#pragma unroll
    for (int j = 0; j < 4; ++j) {
      accR[i][j] = (floatx4){0.f, 0.f, 0.f, 0.f};
      accI[i][j] = (floatx4){0.f, 0.f, 0.f, 0.f};
    }

  for (int k0 = 0; k0 < 128; k0 += 32) {
    gll16(ph + prow1 + k0, (char*)Ph_ + t * 16);
    gll16(ph + prow2 + k0, (char*)Ph_ + 4096 + t * 16);
    gll16(pl + prow1 + k0, (char*)Pl_ + t * 16);
    gll16(pl + prow2 + k0, (char*)Pl_ + 4096 + t * 16);
    gll16(vth + vbr1 + k0, (char*)VrH + t * 16);
    gll16(vth + vbr2 + k0, (char*)VrH + 4096 + t * 16);
    gll16(vtl + vbr1 + k0, (char*)VrL + t * 16);
    gll16(vtl + vbr2 + k0, (char*)VrL + 4096 + t * 16);
    gll16(vth + vplane_i + vbr1 + k0, (char*)ViH + t * 16);
    gll16(vth + vplane_i + vbr2 + k0, (char*)ViH + 4096 + t * 16);
    gll16(vtl + vplane_i + vbr1 + k0, (char*)ViL + t * 16);
    gll16(vtl + vplane_i + vbr2 + k0, (char*)ViL + 4096 + t * 16);
    __syncthreads();
    s8v ah[4], al[4];
#pragma unroll
    for (int i = 0; i < 4; ++i) {
      int ro = (wr * 64 + i * 16 + r) * 32 + q * 8;
      ah[i] = *(const s8v*)((const short*)Ph_ + ro);
      al[i] = *(const s8v*)((const short*)Pl_ + ro);
    }
#pragma unroll
    for (int j = 0; j < 4; ++j) {
      int ro = (wc * 64 + j * 16 + r) * 32 + q * 8;
      s8v vrh = *(const s8v*)((const short*)VrH + ro);
      s8v vrl = *(const s8v*)((const short*)VrL + ro);
      s8v vih = *(const s8v*)((const short*)ViH + ro);
      s8v vil = *(const s8v*)((const short*)ViL + ro);
#pragma unroll
      for (int i = 0; i < 4; ++i) {
        accR[i][j] = __builtin_amdgcn_mfma_f32_16x16x32_bf16(ah[i], vrh, accR[i][j], 0, 0, 0);
        accR[i][j] = __builtin_amdgcn_mfma_f32_16x16x32_bf16(ah[i], vrl, accR[i][j], 0, 0, 0);
        accR[i][j] = __builtin_amdgcn_mfma_f32_16x16x32_bf16(al[i], vrh, accR[i][j], 0, 0, 0);
        accI[i][j] = __builtin_amdgcn_mfma_f32_16x16x32_bf16(ah[i], vih, accI[i][j], 0, 0, 0);
        accI[i][j] = __builtin_amdgcn_mfma_f32_16x16x32_bf16(ah[i], vil, accI[i][j], 0, 0, 0);
        accI[i][j] = __builtin_amdgcn_mfma_f32_16x16x32_bf16(al[i], vih, accI[i][j], 0, 0, 0);
      }
    }
    __syncthreads();
  }
  float* orp = ws + OFF_OR + (size_t)mb * 128 * 512;
  float* oip = ws + OFF_OI + (size_t)mb * 128 * 512;
#pragma unroll
  for (int i = 0; i < 4; ++i)
#pragma unroll
    for (int j = 0; j < 4; ++j) {
      int rowb = wr * 64 + i * 16 + q * 4;
      int colb = col0 + wc * 64 + j * 16 + r;
#pragma unroll
      for (int reg = 0; reg < 4; ++reg) {
        orp[(size_t)(rowb + reg) * 512 + colb] = accR[i][j][reg];
        oip[(size_t)(rowb + reg) * 512 + colb] = accI[i][j][reg];
      }
    }
}

// ---------------- ModReLU + ComplexLayerNorm + feat partials (fused, R9/R11) ----------------
__global__ __launch_bounds__(256) void k_modlnfeat(float* __restrict__ ws,
                                                   const float* __restrict__ mod_bias,
                                                   const float* __restrict__ ln_scale,
                                                   const float* __restrict__ ln_shift) {
  int blk = blockIdx.x;
  int mb = blk >> 2, grp = blk & 3;
  int m = mb >> 3;
  int t = threadIdx.x, w = t >> 6, l = t & 63;
  int e0 = l * 8;
  float mb_[8], lsc[8], lsh[8];
  *(float4*)&mb_[0] = *(const float4*)(mod_bias + m * 512 + e0);
  *(float4*)&mb_[4] = *(const float4*)(mod_bias + m * 512 + e0 + 4);
  *(float4*)&lsc[0] = *(const float4*)(ln_scale + m * 512 + e0);
  *(float4*)&lsc[4] = *(const float4*)(ln_scale + m * 512 + e0 + 4);
  *(float4*)&lsh[0] = *(const float4*)(ln_shift + m * 512 + e0);
  *(float4*)&lsh[4] = *(const float4*)(ln_shift + m * 512 + e0 + 4);
  float featR[8] = {}, featI[8] = {};
  for (int it = 0; it < 8; ++it) {
    int s = grp * 32 + it * 4 + w;
    float* orp = ws + OFF_OR + ((size_t)mb * 128 + s) * 512 + e0;
    float* oip = ws + OFF_OI + ((size_t)mb * 128 + s) * 512 + e0;
    float orv[8], oiv[8], magv[8];
    *(float4*)&orv[0] = *(const float4*)orp;
    *(float4*)&orv[4] = *(const float4*)(orp + 4);
    *(float4*)&oiv[0] = *(const float4*)oip;
    *(float4*)&oiv[4] = *(const float4*)(oip + 4);
    float sum = 0.f, sumsq = 0.f;
#pragma unroll
    for (int j = 0; j < 8; ++j) {
      float o_r = orv[j], o_i = oiv[j];
      float mag = sqrtf(o_r * o_r + o_i * o_i) + EPS;
      float g = fmaxf(mag + mb_[j], 0.f) / mag;
      o_r *= g; o_i *= g;
      orv[j] = o_r; oiv[j] = o_i;
      float mag2 = sqrtf(o_r * o_r + o_i * o_i) + EPS;
      magv[j] = mag2;
      sum += mag2;
      sumsq += mag2 * mag2;
    }
    for (int o = 1; o < 64; o <<= 1) {
      sum += __shfl_xor(sum, o);
      sumsq += __shfl_xor(sumsq, o);
    }
    float mu = sum * (1.f / D);
    float var = (sumsq - (float)D * mu * mu) * (1.f / (D - 1));
    float inv = 1.f / sqrtf(var + EPS);
#pragma unroll
    for (int j = 0; j < 8; ++j) {
      float nm = (magv[j] - mu) * inv * lsc[j] + lsh[j];
      float hyp = magv[j] - EPS;
      float cp, sp;
      if (hyp > 0.f) { cp = orv[j] / hyp; sp = oiv[j] / hyp; }
      else           { cp = 1.f;          sp = 0.f; }
      orv[j] = nm * cp;
      oiv[j] = nm * sp;
      featR[j] += orv[j];
      featI[j] += oiv[j];
    }
    *(float4*)orp = *(float4*)&orv[0];
    *(float4*)(orp + 4) = *(float4*)&orv[4];
    *(float4*)oip = *(float4*)&oiv[0];
    *(float4*)(oip + 4) = *(float4*)&oiv[4];
  }
  float* fb = ws + OFF_FEAT + (size_t)mb * 1024;
#pragma unroll
  for (int j = 0; j < 8; ++j) {
    atomicAdd(fb + e0 + j, featR[j] * (1.0f / S));
    atomicAdd(fb + 512 + e0 + j, featI[j] * (1.0f / S));
  }
}

// ---------------- wsel (R1) + zero FEAT/GWP for next step (R9) ----------------
__global__ __launch_bounds__(256) void k_wsel(float* __restrict__ ws,
                                              const float* __restrict__ hnew,
                                              const float* __restrict__ bias_W,
                                              const float* __restrict__ bias_b,
                                              const float* __restrict__ w_sal) {
  __shared__ float mb_s[B][M];
  __shared__ float sal_s[M][B];
  int t = threadIdx.x;
  int p = t >> 3, l = t & 7;
  {
    int b = p >> 2, m = p & 3;
    float s = 0.f;
    for (int d2 = l; d2 < D; d2 += 8) s += hnew[b * D + d2] * bias_W[d2 * M + m];
    for (int o = 1; o < 8; o <<= 1) s += __shfl_xor(s, o);
    if (l == 0) mb_s[b][m] = s + bias_b[m];
  }
  {
    int m = p >> 3, b = p & 7;
    float s = 0.f;
    for (int f = l; f < 2 * D; f += 8) s += ws[OFF_FEAT + (m * B + b) * 2 * D + f] * w_sal[m * 2 * D + f];
    for (int o = 1; o < 8; o <<= 1) s += __shfl_xor(s, o);
    if (l == 0) sal_s[m][b] = s;
  }
  __syncthreads();
  if (t < B) {
    int b = t;
    float lg[M], mx = -1e30f;
#pragma unroll
    for (int m = 0; m < M; ++m) { lg[m] = sal_s[m][b] + mb_s[b][m]; mx = fmaxf(mx, lg[m]); }
    float sm = 0.f;
#pragma unroll
    for (int m = 0; m < M; ++m) { lg[m] = expf(lg[m] - mx); sm += lg[m]; }
    float inv = 1.f / sm;
#pragma unroll
    for (int m = 0; m < M; ++m) ws[OFF_W + m * B + b] = lg[m] * inv;
  }
  float4 z4 = {0.f, 0.f, 0.f, 0.f};
  for (int i = t; i < 16384; i += 256) ((float4*)(ws + OFF_FEAT))[i] = z4;
  for (int i = t; i < 2048; i += 256) ((float4*)(ws + OFF_GWP))[i] = z4;
}

// ---------------- bcast (fp32 Z + bf16 Xcat) + gwp partial accumulation (R9) ----------------
__global__ __launch_bounds__(256) void k_bcast(float* __restrict__ ws) {
  __shared__ float pr[1024];
  unsigned short* xh = (unsigned short*)(ws + OFF_XH);
  unsigned short* xl = (unsigned short*)(ws + OFF_XL);
  int t = threadIdx.x;
  int i4 = blockIdx.x * 256 + t;
  int b = i4 >> 14;
  int l = t & 127;
  float w0 = ws[OFF_W + 0 * B + b], w1 = ws[OFF_W + 1 * B + b];
  float w2 = ws[OFF_W + 2 * B + b], w3 = ws[OFF_W + 3 * B + b];
  const float4* mr = (const float4*)(ws + OFF_OR);
  const float4* mi = (const float4*)(ws + OFF_OI);
  const int MS = BSD / 4;
  int row = i4 >> 7;
  int d4 = (i4 & 127) * 4;
  float4 r0 = mr[i4], r1 = mr[i4 + MS], r2 = mr[i4 + 2 * MS], r3 = mr[i4 + 3 * MS];
  float gvR[4];
  gvR[0] = w0 * r0.x + w1 * r1.x + w2 * r2.x + w3 * r3.x;
  gvR[1] = w0 * r0.y + w1 * r1.y + w2 * r2.y + w3 * r3.y;
  gvR[2] = w0 * r0.z + w1 * r1.z + w2 * r2.z + w3 * r3.z;
  gvR[3] = w0 * r0.w + w1 * r1.w + w2 * r2.w + w3 * r3.w;
  ((float4*)(ws + OFF_ZR))[i4] = (float4){gvR[0], gvR[1], gvR[2], gvR[3]};
  us4 hh, hl;
#pragma unroll
  for (int j = 0; j < 4; ++j) {
    unsigned short h = f2bf(gvR[j]); hh[j] = h; hl[j] = f2bf(gvR[j] - bf2f(h));
  }
  *(us4*)(xh + (size_t)row * 1024 + d4) = hh;
  *(us4*)(xl + (size_t)row * 1024 + d4) = hl;
  float4 s0 = mi[i4], s1 = mi[i4 + MS], s2 = mi[i4 + 2 * MS], s3 = mi[i4 + 3 * MS];
  float gvI[4];
  gvI[0] = w0 * s0.x + w1 * s1.x + w2 * s2.x + w3 * s3.x;
  gvI[1] = w0 * s0.y + w1 * s1.y + w2 * s2.y + w3 * s3.y;
  gvI[2] = w0 * s0.z + w1 * s1.z + w2 * s2.z + w3 * s3.z;
  gvI[3] = w0 * s0.w + w1 * s1.w + w2 * s2.w + w3 * s3.w;
  ((float4*)(ws + OFF_ZI))[i4] = (float4){gvI[0], gvI[1], gvI[2], gvI[3]};
#pragma unroll
  for (int j = 0; j < 4; ++j) {
    unsigned short h = f2bf(gvI[j]); hh[j] = h; hl[j] = f2bf(gvI[j] - bf2f(h));
  }
  *(us4*)(xh + (size_t)row * 1024 + 512 + d4) = hh;
  *(us4*)(xl + (size_t)row * 1024 + 512 + d4) = hl;
  if (t < 128) {
#pragma unroll
    for (int j = 0; j < 4; ++j) { pr[l * 4 + j] = gvR[j]; pr[512 + l * 4 + j] = gvI[j]; }
  }
  __syncthreads();
  if (t >= 128) {
#pragma unroll
    for (int j = 0; j < 4; ++j) { pr[l * 4 + j] += gvR[j]; pr[512 + l * 4 + j] += gvI[j]; }
  }
  __syncthreads();
  for (int pp = t; pp < 1024; pp += 256)
    atomicAdd(ws + OFF_GWP + b * 1024 + pp, pr[pp] * (1.0f / S));
}

// ---------------- halt + ACT accumulate (fused; cum double-buffered) (R9) ----------------
__global__ __launch_bounds__(256) void k_acchalt(float* __restrict__ ws,
                                                 const float* __restrict__ w_halt,
                                                 const float* __restrict__ b_halt,
                                                 const float* __restrict__ cumr,
                                                 float* __restrict__ cumw) {
  __shared__ float sred[4];
  int t = threadIdx.x;
  int i4 = blockIdx.x * 256 + t;
  int b = i4 >> 14;
  float4 g = *(const float4*)(ws + OFF_GWP + b * 1024 + t * 4);
  float4 wv = *(const float4*)(w_halt + t * 4);
  float s = g.x * wv.x + g.y * wv.y + g.z * wv.z + g.w * wv.w;
  for (int o = 1; o < 64; o <<= 1) s += __shfl_xor(s, o);
  if ((t & 63) == 0) sred[t >> 6] = s;
  __syncthreads();
  float tot = sred[0] + sred[1] + sred[2] + sred[3];
  float p = 1.f / (1.f + expf(-(tot + b_halt[0])));
  float cum = cumr[b];
  float still = (cum < THRESH) ? 1.f : 0.f;
  bool nh = ((cum + p) >= THRESH) && (cum < THRESH);
  float wt = (nh ? (1.f - cum) : p) * still;
  if (((blockIdx.x & 63) == 0) && t == 0) cumw[b] = cum + wt;
  float4 z = ((const float4*)(ws + OFF_ZR))[i4];
  float4 a = ((float4*)(ws + OFF_AR))[i4];
  a.x += wt * z.x; a.y += wt * z.y; a.z += wt * z.z; a.w += wt * z.w;
  ((float4*)(ws + OFF_AR))[i4] = a;
  z = ((const float4*)(ws + OFF_ZI))[i4];
  a = ((float4*)(ws + OFF_AI))[i4];
  a.x += wt * z.x; a.y += wt * z.y; a.z += wt * z.z; a.w += wt * z.w;
  ((float4*)(ws + OFF_AI))[i4] = a;
}

// ---------------- output (R1) ----------------
__global__ __launch_bounds__(256) void k_out(const float* __restrict__ ws,
                                             float* __restrict__ out) {
  int i4 = blockIdx.x * 256 + threadIdx.x;
  ((float4*)out)[i4] = ((const float4*)(ws + OFF_AR))[i4];
  ((float4*)out)[i4 + BSD / 4] = ((const float4*)(ws + OFF_AI))[i4];
}

extern "C" void kernel_launch(void* const* d_in, const int* in_sizes, int n_in,
                              void* d_out, int out_size, void* d_ws, size_t ws_size,
                              hipStream_t stream) {
  (void)in_sizes; (void)n_in; (void)out_size; (void)ws_size;
  const float* x_real  = (const float*)d_in[0];
  const float* x_imag  = (const float*)d_in[1];
  const float* Wq_r    = (const float*)d_in[2];
  const float* Wq_i    = (const float*)d_in[3];
  const float* Wk_r    = (const float*)d_in[4];
  const float* Wk_i    = (const float*)d_in[5];
  const float* Wv_r    = (const float*)d_in[6];
  const float* Wv_i    = (const float*)d_in[7];
  const float* mod_bias = (const float*)d_in[8];
  const float* ln_scale = (const float*)d_in[9];
  const float* ln_shift = (const float*)d_in[10];
  const float* w_sal   = (const float*)d_in[11];
  const float* gru_Wih = (const float*)d_in[12];
  const float* gru_Whh = (const float*)d_in[13];
  const float* gru_bih = (const float*)d_in[14];
  const float* gru_bhh = (const float*)d_in[15];
  const float* bias_W  = (const float*)d_in[16];
  const float* bias_b  = (const float*)d_in[17];
  const float* w_halt  = (const float*)d_in[18];
  const float* b_halt  = (const float*)d_in[19];
  float* ws = (float*)d_ws;
  float* out = (float*)d_out;

  k_wprep<<<dim3(8, 8, 24), 256, 0, stream>>>(Wq_r, Wq_i, Wk_r, Wk_i, Wv_r, Wv_i, ws);
  k_init<<<512, 256, 0, stream>>>(x_real, x_imag, ws);
  k_gwp<<<32, 256, 0, stream>>>(ws + OFF_ZR, ws + OFF_ZI, ws + OFF_GWP);
  for (int step = 0; step < DEPTH; ++step) {
    const float* hold = ws + ((step & 1) ? OFF_H1 : OFF_H0);
    float* hnew = ws + ((step & 1) ? OFF_H0 : OFF_H1);
    const float* cumr = ws + ((step & 1) ? OFF_CUM2 : OFF_CUM);
    float* cumw = ws + ((step & 1) ? OFF_CUM : OFF_CUM2);
    k_qk<<<dim3(4, 8, 16), 256, 0, stream>>>(ws);
    k_vattn<<<448, 256, 0, stream>>>(ws, ws + OFF_GWP, hold, hnew,
                                     gru_Wih, gru_Whh, gru_bih, gru_bhh);
    k_pv<<<dim3(4, 32), 256, 0, stream>>>(ws);
    k_modlnfeat<<<128, 256, 0, stream>>>(ws, mod_bias, ln_scale, ln_shift);
    k_wsel<<<1, 256, 0, stream>>>(ws, hnew, bias_W, bias_b, w_sal);
    k_bcast<<<512, 256, 0, stream>>>(ws);
    k_acchalt<<<512, 256, 0, stream>>>(ws, w_halt, b_halt, cumr, cumw);
  }
  k_out<<<512, 256, 0, stream>>>(ws, out);
}

// Round 8
// 3406.016 us; speedup vs baseline: 1.2448x; 1.0949x over previous
//
#include <hip/hip_runtime.h>
#include <math.h>

#define B 8
#define S 128
#define D 512
#define M 4
#define BS 1024
#define BSD 524288          // B*S*D
#define DEPTH 16
#define THRESH 0.9999f
#define EPS 1e-6f
#define SCALE 0.04419417382415922f   // D^-0.5

typedef float floatx4 __attribute__((ext_vector_type(4)));
typedef short s8v __attribute__((ext_vector_type(8)));
typedef unsigned short us4 __attribute__((ext_vector_type(4)));

__device__ __forceinline__ unsigned short f2bf(float f) {
  unsigned int u = __float_as_uint(f);
  u += 0x7FFFu + ((u >> 16) & 1u);          // round-to-nearest-even
  return (unsigned short)(u >> 16);
}
__device__ __forceinline__ float bf2f(unsigned short h) {
  return __uint_as_float((unsigned int)h << 16);
}

// async global->LDS, 16B per lane, linear LDS dest (wave-uniform base + lane*16)
__device__ __forceinline__ void gll16(const void* g, void* l) {
  __builtin_amdgcn_global_load_lds(
      (const __attribute__((address_space(1))) unsigned int*)g,
      (__attribute__((address_space(3))) unsigned int*)l, 16, 0, 0);
}

// ---------------- workspace layout (float-slot offsets) ----------------
#define OFF_ZR   0
#define OFF_ZI   (1*BSD)
#define OFF_AR   (2*BSD)
#define OFF_AI   (3*BSD)
#define OFF_OR   (4*BSD)            // [M][B][S][D] fp32 = 4*BSD
#define OFF_OI   (8*BSD)
#define OFF_FEAT (12*BSD)           // 65536
#define OFF_GWP  (12*BSD + 65536)   // 8192
#define OFF_H0   (12*BSD + 73728)
#define OFF_H1   (12*BSD + 77824)
#define OFF_CUM  (12*BSD + 81920)   // 8
#define OFF_W    (12*BSD + 81928)   // 32
#define OFF_WT   (12*BSD + 81960)   // 8
#define OFF_CUM2 (12*BSD + 81968)   // 8
// R19: GRU partial-sum scratch PART[B][512][4] = 16384 floats, OVERLAYS OFF_ZR.
//   ZR is dead between k_acchalt (prev step, last reader) and k_bcast (this step,
//   writer). Window used: k_qk zeroes -> k_vattn atomicAdds -> k_modlnfeat reads.
#define OFF_PART OFF_ZR
// bf16 annex (slots)
#define OFF_XH   (12*BSD + 90112)           // xcat hi [1024][1024] = 1 BSD
#define OFF_XL   (OFF_XH + 1*BSD)
#define OFF_WH   (OFF_XH + 2*BSD)           // 24 planes [512][512] hi = 6 BSD
#define OFF_WL   (OFF_XH + 8*BSD)
#define OFF_QCH  (OFF_XH + 14*BSD)          // Qcat hi [M][1024][1024] = 4 BSD
#define OFF_QCL  (OFF_XH + 18*BSD)
#define OFF_KCH  (OFF_XH + 22*BSD)
#define OFF_KCL  (OFF_XH + 26*BSD)
#define OFF_VTH  (OFF_XH + 30*BSD)          // Vt hi [2ri][M][512][1024] = 4 BSD
#define OFF_VTL  (OFF_XH + 34*BSD)
#define OFF_PH   (OFF_XH + 38*BSD)          // P hi [32][128][128] = 262144 slots
#define OFF_PL   (OFF_PH + 262144)
// end ~= 107.3 MB (R6/R8 proven)

// ---------------- init: fp32 carry + bf16 hi/lo Xcat + zero FEAT/GWP/CUMs ----------------
__global__ __launch_bounds__(256) void k_init(const float* __restrict__ xr,
                                              const float* __restrict__ xi,
                                              float* __restrict__ ws) {
  unsigned short* xh = (unsigned short*)(ws + OFF_XH);
  unsigned short* xl = (unsigned short*)(ws + OFF_XL);
  int i4 = blockIdx.x * 256 + threadIdx.x;      // BSD/4
  float4 a = ((const float4*)xr)[i4];
  float4 b = ((const float4*)xi)[i4];
  ((float4*)(ws + OFF_ZR))[i4] = a;
  ((float4*)(ws + OFF_ZI))[i4] = b;
  float4 z = {0.f, 0.f, 0.f, 0.f};
  ((float4*)(ws + OFF_AR))[i4] = z;
  ((float4*)(ws + OFF_AI))[i4] = z;
  int row = i4 >> 7;
  int d4 = (i4 & 127) * 4;
  float av[4] = {a.x, a.y, a.z, a.w}, bv[4] = {b.x, b.y, b.z, b.w};
  us4 hh, hl;
#pragma unroll
  for (int j = 0; j < 4; ++j) {
    unsigned short h = f2bf(av[j]); hh[j] = h; hl[j] = f2bf(av[j] - bf2f(h));
  }
  *(us4*)(xh + (size_t)row * 1024 + d4) = hh;
  *(us4*)(xl + (size_t)row * 1024 + d4) = hl;
#pragma unroll
  for (int j = 0; j < 4; ++j) {
    unsigned short h = f2bf(bv[j]); hh[j] = h; hl[j] = f2bf(bv[j] - bf2f(h));
  }
  *(us4*)(xh + (size_t)row * 1024 + 512 + d4) = hh;
  *(us4*)(xl + (size_t)row * 1024 + 512 + d4) = hl;
  if (i4 < (B * D) / 4) {
    ((float4*)(ws + OFF_H0))[i4] = z;
    ((float4*)(ws + OFF_H1))[i4] = z;
  }
  if (i4 < 16384) ((float4*)(ws + OFF_FEAT))[i4] = z;
  if (i4 < 2048)  ((float4*)(ws + OFF_GWP))[i4] = z;
  if (i4 < B) { ws[OFF_CUM + i4] = 0.f; ws[OFF_CUM2 + i4] = 0.f; }
}

// ---------------- weight prep (R6, proven) ----------------
__global__ __launch_bounds__(256) void k_wprep(const float* __restrict__ Wqr,
                                               const float* __restrict__ Wqi,
                                               const float* __restrict__ Wkr,
                                               const float* __restrict__ Wki,
                                               const float* __restrict__ Wvr,
                                               const float* __restrict__ Wvi,
                                               float* __restrict__ ws) {
  __shared__ float lt[64][65];
  unsigned short* wh = (unsigned short*)(ws + OFF_WH);
  unsigned short* wl = (unsigned short*)(ws + OFF_WL);
  int z = blockIdx.z, m = z / 6, idx = z % 6;
  const float* Wsrc;
  switch (idx) {
    case 0:  Wsrc = Wqr; break;
    case 1:  Wsrc = Wqi; break;
    case 2:  Wsrc = Wkr; break;
    case 3:  Wsrc = Wki; break;
    case 4:  Wsrc = Wvr; break;
    default: Wsrc = Wvi; break;
  }
  Wsrc += (size_t)m * D * D;
  int k0 = blockIdx.x * 64, n0 = blockIdx.y * 64;
  int tx = threadIdx.x & 63, ty = threadIdx.x >> 6;
#pragma unroll
  for (int i = 0; i < 16; ++i) {
    int kl = ty + i * 4;
    lt[kl][tx] = Wsrc[(size_t)(k0 + kl) * D + n0 + tx];
  }
  __syncthreads();
  unsigned short* whp = wh + (size_t)z * 262144;
  unsigned short* wlp = wl + (size_t)z * 262144;
#pragma unroll
  for (int i = 0; i < 16; ++i) {
    int nl = ty + i * 4;
    float v = lt[tx][nl];
    unsigned short h = f2bf(v);
    whp[(size_t)(n0 + nl) * 512 + k0 + tx] = h;
    wlp[(size_t)(n0 + nl) * 512 + k0 + tx] = f2bf(v - bf2f(h));
  }
}

// ---------------- gwp (pre-loop only) ----------------
__global__ __launch_bounds__(256) void k_gwp(const float* __restrict__ zr,
                                             const float* __restrict__ zi,
                                             float* __restrict__ gwp) {
  int idx = blockIdx.x * 256 + threadIdx.x;
  int b = idx >> 10;
  int f = idx & 1023;
  const float* src = (f < D) ? (zr + b * S * D + f) : (zi + b * S * D + (f - D));
  float s = 0.f;
#pragma unroll 8
  for (int ss = 0; ss < S; ++ss) s += src[ss * D];
  gwp[idx] = s * (1.0f / S);
}

// ---------------- k_qk: Q/K GEMMs only (R16-proven; 512 blocks = 2 CU-rounds) ----------------
// R19: block (0,0,0) additionally zeroes PART before its GEMM (kernel-boundary
// ordering guarantees visibility to k_vattn's atomics).
__global__ __launch_bounds__(256) void k_qk(float* __restrict__ ws) {
  __shared__ __align__(16) unsigned short Ah[128 * 32], Al[128 * 32];
  __shared__ __align__(16) unsigned short Bh[128 * 32], Bl[128 * 32];
  int t = threadIdx.x;
  if (blockIdx.x == 0 && blockIdx.y == 0 && blockIdx.z == 0) {
    float4 z4 = {0.f, 0.f, 0.f, 0.f};
    for (int i = t; i < 4096; i += 256) ((float4*)(ws + OFF_PART))[i] = z4;
  }
  const unsigned short* xh = (const unsigned short*)(ws + OFF_XH);
  const unsigned short* xl = (const unsigned short*)(ws + OFF_XL);
  const unsigned short* wh = (const unsigned short*)(ws + OFF_WH);
  const unsigned short* wl = (const unsigned short*)(ws + OFF_WL);
  int z = blockIdx.z, m = z >> 2, w6 = z & 3;
  int pair = (w6 >> 1) * 2;
  int p1 = m * 6 + pair + (w6 & 1);
  int p2 = m * 6 + pair + ((w6 & 1) ^ 1);
  bool neg2 = ((w6 & 1) == 0);               // real-output GEMMs negate second K-half
  const unsigned short* PH1 = wh + (size_t)p1 * 262144;
  const unsigned short* PL1 = wl + (size_t)p1 * 262144;
  const unsigned short* PH2 = wh + (size_t)p2 * 262144;
  const unsigned short* PL2 = wl + (size_t)p2 * 262144;

  int row0 = blockIdx.y * 128;    // X rows
  int col0 = blockIdx.x * 128;    // W cols
  int lane = t & 63, w = t >> 6;
  int wr = w >> 1, wc = w & 1;
  int q = lane >> 4, r = lane & 15;
  int srow = t >> 2;
  int skoff = (t & 3) * 8;
  size_t wrow1 = (size_t)(col0 + srow) * 512 + skoff;
  size_t wrow2 = (size_t)(col0 + 64 + srow) * 512 + skoff;
  size_t xrow1 = (size_t)(row0 + srow) * 1024 + skoff;
  size_t xrow2 = (size_t)(row0 + 64 + srow) * 1024 + skoff;
  const s8v sgn = {(short)0x8000, (short)0x8000, (short)0x8000, (short)0x8000,
                   (short)0x8000, (short)0x8000, (short)0x8000, (short)0x8000};

  floatx4 acc[4][4];
#pragma unroll
  for (int i = 0; i < 4; ++i)
#pragma unroll
    for (int j = 0; j < 4; ++j) acc[i][j] = (floatx4){0.f, 0.f, 0.f, 0.f};

  for (int k0 = 0; k0 < 1024; k0 += 32) {
    const unsigned short *WgH, *WgL;
    int kk = k0;
    bool xon = false;
    if (k0 < 512) { WgH = PH1; WgL = PL1; }
    else          { WgH = PH2; WgL = PL2; kk = k0 - 512; xon = neg2; }
    gll16(xh + xrow1 + k0, (char*)Ah + t * 16);
    gll16(xh + xrow2 + k0, (char*)Ah + 4096 + t * 16);
    gll16(xl + xrow1 + k0, (char*)Al + t * 16);
    gll16(xl + xrow2 + k0, (char*)Al + 4096 + t * 16);
    gll16(WgH + wrow1 + kk, (char*)Bh + t * 16);
    gll16(WgH + wrow2 + kk, (char*)Bh + 4096 + t * 16);
    gll16(WgL + wrow1 + kk, (char*)Bl + t * 16);
    gll16(WgL + wrow2 + kk, (char*)Bl + 4096 + t * 16);
    __syncthreads();
    s8v ah[4], al[4], bh[4], bl[4];
#pragma unroll
    for (int i = 0; i < 4; ++i) {
      int ro = (wr * 64 + i * 16 + r) * 32 + q * 8;
      ah[i] = *(const s8v*)((const short*)Ah + ro);
      al[i] = *(const s8v*)((const short*)Al + ro);
    }
#pragma unroll
    for (int j = 0; j < 4; ++j) {
      int ro = (wc * 64 + j * 16 + r) * 32 + q * 8;
      bh[j] = *(const s8v*)((const short*)Bh + ro);
      bl[j] = *(const s8v*)((const short*)Bl + ro);
    }
    if (xon) {
#pragma unroll
      for (int j = 0; j < 4; ++j) { bh[j] = bh[j] ^ sgn; bl[j] = bl[j] ^ sgn; }
    }
#pragma unroll
    for (int i = 0; i < 4; ++i)
#pragma unroll
      for (int j = 0; j < 4; ++j) {
        acc[i][j] = __builtin_amdgcn_mfma_f32_16x16x32_bf16(ah[i], bh[j], acc[i][j], 0, 0, 0);
        acc[i][j] = __builtin_amdgcn_mfma_f32_16x16x32_bf16(ah[i], bl[j], acc[i][j], 0, 0, 0);
        acc[i][j] = __builtin_amdgcn_mfma_f32_16x16x32_bf16(al[i], bh[j], acc[i][j], 0, 0, 0);
      }
    __syncthreads();
  }
  unsigned short *dh, *dl;
  if (w6 < 2) { dh = (unsigned short*)(ws + OFF_QCH); dl = (unsigned short*)(ws + OFF_QCL); }
  else        { dh = (unsigned short*)(ws + OFF_KCH); dl = (unsigned short*)(ws + OFF_KCL); }
  int half = (w6 & 1) * 512;
  size_t base = (size_t)m * 1024 * 1024;
#pragma unroll
  for (int i = 0; i < 4; ++i)
#pragma unroll
    for (int j = 0; j < 4; ++j) {
      int rowb = row0 + wr * 64 + i * 16 + q * 4;
      int colb = col0 + wc * 64 + j * 16 + r;
#pragma unroll
      for (int reg = 0; reg < 4; ++reg) {
        float v = acc[i][j][reg];
        unsigned short h = f2bf(v);
        size_t idx = base + (size_t)(rowb + reg) * 1024 + half + colb;
        dh[idx] = h;
        dl[idx] = f2bf(v - bf2f(h));
      }
    }
}

// ---------------- k_vattn: V GEMM (blk<256) + attn (256..319) + GRU-partials (320..575) ----------------
// R19: GRU chain shortened 4x — 256 partial blocks (b8 x cchunk8 x kq4), per-wave
// 96 iters (was 384); partial gate sums via device atomicAdd into PART (OFF_ZR
// overlay). Finish (nonlinearity) moved to k_modlnfeat extra blocks.
__global__ __launch_bounds__(256) void k_vattn(float* __restrict__ ws,
                                               const float* __restrict__ gwp,
                                               const float* __restrict__ hold,
                                               const float* __restrict__ Wih,
                                               const float* __restrict__ Whh) {
  __shared__ __align__(16) unsigned short Ah[128 * 32], Al[128 * 32];
  __shared__ __align__(16) unsigned short Bh[128 * 32], Bl[128 * 32];
  __shared__ float rmax[64][4];
  __shared__ float rsum[64][4];
  int t = threadIdx.x;
  int blk = blockIdx.x;

  if (blk >= 320) {
    // ---- GRU partial path ----
    float* xbuf = (float*)Ah;                 // 1024 floats
    float* hbuf = (float*)Al;                 // 512 floats
    float (*red)[64][4] = (float (*)[64][4])Bh;
    int idx = blk - 320;                      // 0..255
    int b = idx >> 5;                         // 8
    int cc = (idx >> 2) & 7;                  // 8
    int kq = idx & 3;                         // 4
    int c0 = cc * 64;
    int td = t & 63, ks = t >> 6;
    for (int f = t; f < 1024; f += 256) xbuf[f] = gwp[b * 1024 + f];
    for (int d2 = t; d2 < 512; d2 += 256) hbuf[d2] = hold[b * 512 + d2];
    __syncthreads();
    float aR = 0.f, aZ = 0.f, aXn = 0.f, aHn = 0.f;
    int kbeg = kq * 384 + ks * 96, kend = kbeg + 96;
#pragma unroll 8
    for (int kk = kbeg; kk < kend; ++kk) {
      bool ih = kk < 1024;
      float x = ih ? xbuf[kk] : hbuf[kk - 1024];
      const float* base = ih ? (Wih + (size_t)kk * 1536) : (Whh + (size_t)(kk - 1024) * 1536);
      float wr = base[c0 + td];
      float wz = base[512 + c0 + td];
      float wn = base[1024 + c0 + td];
      aR += x * wr;
      aZ += x * wz;
      if (ih) aXn += x * wn; else aHn += x * wn;
    }
    red[ks][td][0] = aR;
    red[ks][td][1] = aZ;
    red[ks][td][2] = aXn;
    red[ks][td][3] = aHn;
    __syncthreads();
    if (t < 64) {
      float r_ = 0.f, z_ = 0.f, xn = 0.f, hn = 0.f;
#pragma unroll
      for (int s = 0; s < 4; ++s) {
        r_ += red[s][t][0]; z_ += red[s][t][1]; xn += red[s][t][2]; hn += red[s][t][3];
      }
      float* part = ws + OFF_PART + ((size_t)b * 512 + c0 + t) * 4;
      atomicAdd(part + 0, r_);
      atomicAdd(part + 1, z_);
      atomicAdd(part + 2, xn);
      atomicAdd(part + 3, hn);
    }
    return;
  }

  if (blk >= 256) {
    // ---- attn path (R16-proven body; 64 Q-rows x 128 K-cols) ----
    const unsigned short* qch = (const unsigned short*)(ws + OFF_QCH);
    const unsigned short* qcl = (const unsigned short*)(ws + OFF_QCL);
    const unsigned short* kch = (const unsigned short*)(ws + OFF_KCH);
    const unsigned short* kcl = (const unsigned short*)(ws + OFF_KCL);
    unsigned short* ph = (unsigned short*)(ws + OFF_PH);
    unsigned short* pl = (unsigned short*)(ws + OFF_PL);
    int ablk = blk - 256, mb = ablk >> 1, half = ablk & 1;
    size_t gbase = (size_t)mb * 128 * 1024;
    int lane = t & 63, wc = t >> 6;
    int q = lane >> 4, r = lane & 15;
    int srow = t >> 2;
    int skoff = (t & 3) * 8;
    size_t arow = gbase + (size_t)(half * 64 + srow) * 1024 + skoff;
    size_t brow1 = gbase + (size_t)srow * 1024 + skoff;
    size_t brow2 = gbase + (size_t)(64 + srow) * 1024 + skoff;

    floatx4 acc[4][2];
#pragma unroll
    for (int i = 0; i < 4; ++i)
#pragma unroll
      for (int j = 0; j < 2; ++j) acc[i][j] = (floatx4){0.f, 0.f, 0.f, 0.f};

    for (int k0 = 0; k0 < 1024; k0 += 32) {
      gll16(qch + arow + k0, (char*)Ah + t * 16);
      gll16(qcl + arow + k0, (char*)Al + t * 16);
      gll16(kch + brow1 + k0, (char*)Bh + t * 16);
      gll16(kch + brow2 + k0, (char*)Bh + 4096 + t * 16);
      gll16(kcl + brow1 + k0, (char*)Bl + t * 16);
      gll16(kcl + brow2 + k0, (char*)Bl + 4096 + t * 16);
      __syncthreads();
      s8v ah[4], al[4], bh[2], bl[2];
#pragma unroll
      for (int i = 0; i < 4; ++i) {
        int ro = (i * 16 + r) * 32 + q * 8;
        ah[i] = *(const s8v*)((const short*)Ah + ro);
        al[i] = *(const s8v*)((const short*)Al + ro);
      }
#pragma unroll
      for (int j = 0; j < 2; ++j) {
        int ro = (wc * 32 + j * 16 + r) * 32 + q * 8;
        bh[j] = *(const s8v*)((const short*)Bh + ro);
        bl[j] = *(const s8v*)((const short*)Bl + ro);
      }
#pragma unroll
      for (int i = 0; i < 4; ++i)
#pragma unroll
        for (int j = 0; j < 2; ++j) {
          acc[i][j] = __builtin_amdgcn_mfma_f32_16x16x32_bf16(ah[i], bh[j], acc[i][j], 0, 0, 0);
          acc[i][j] = __builtin_amdgcn_mfma_f32_16x16x32_bf16(ah[i], bl[j], acc[i][j], 0, 0, 0);
          acc[i][j] = __builtin_amdgcn_mfma_f32_16x16x32_bf16(al[i], bh[j], acc[i][j], 0, 0, 0);
        }
      __syncthreads();
    }
#pragma unroll
    for (int i = 0; i < 4; ++i)
#pragma unroll
      for (int j = 0; j < 2; ++j)
#pragma unroll
        for (int reg = 0; reg < 4; ++reg) acc[i][j][reg] *= SCALE;
#pragma unroll
    for (int i = 0; i < 4; ++i)
#pragma unroll
      for (int reg = 0; reg < 4; ++reg) {
        float mx = fmaxf(acc[i][0][reg], acc[i][1][reg]);
        for (int o = 1; o < 16; o <<= 1) mx = fmaxf(mx, __shfl_xor(mx, o));
        if (r == 0) rmax[i * 16 + q * 4 + reg][wc] = mx;
      }
    __syncthreads();
#pragma unroll
    for (int i = 0; i < 4; ++i)
#pragma unroll
      for (int reg = 0; reg < 4; ++reg) {
        int row = i * 16 + q * 4 + reg;
        float gmx = fmaxf(fmaxf(rmax[row][0], rmax[row][1]),
                          fmaxf(rmax[row][2], rmax[row][3]));
        float sm = 0.f;
#pragma unroll
        for (int j = 0; j < 2; ++j) {
          float e = __expf(acc[i][j][reg] - gmx);
          acc[i][j][reg] = e;
          sm += e;
        }
        for (int o = 1; o < 16; o <<= 1) sm += __shfl_xor(sm, o);
        if (r == 0) rsum[row][wc] = sm;
      }
    __syncthreads();
#pragma unroll
    for (int i = 0; i < 4; ++i)
#pragma unroll
      for (int reg = 0; reg < 4; ++reg) {
        int row = i * 16 + q * 4 + reg;
        float inv = 1.f / (rsum[row][0] + rsum[row][1] + rsum[row][2] + rsum[row][3]);
        size_t rb = (size_t)(mb * 128 + half * 64 + row) * 128;
#pragma unroll
        for (int j = 0; j < 2; ++j) {
          float p = acc[i][j][reg] * inv;
          unsigned short h = f2bf(p);
          size_t idx = rb + wc * 32 + j * 16 + r;
          ph[idx] = h;
          pl[idx] = f2bf(p - bf2f(h));
        }
      }
    return;
  }

  // ---- V GEMM path (R13-proven body, w6 in {4,5}) ----
  const unsigned short* xh = (const unsigned short*)(ws + OFF_XH);
  const unsigned short* xl = (const unsigned short*)(ws + OFF_XL);
  const unsigned short* wh = (const unsigned short*)(ws + OFF_WH);
  const unsigned short* wl = (const unsigned short*)(ws + OFF_WL);
  int plane = blk >> 5, m = plane >> 1, w6 = 4 + (plane & 1);
  int bx = (blk & 31) >> 3, by = blk & 7;
  int p1 = m * 6 + 4 + (w6 & 1);
  int p2 = m * 6 + 4 + ((w6 & 1) ^ 1);
  bool neg2 = ((w6 & 1) == 0);
  const unsigned short* PH1 = wh + (size_t)p1 * 262144;
  const unsigned short* PL1 = wl + (size_t)p1 * 262144;
  const unsigned short* PH2 = wh + (size_t)p2 * 262144;
  const unsigned short* PL2 = wl + (size_t)p2 * 262144;

  int row0 = bx * 128;     // W cols (Vt rows)
  int col0 = by * 128;     // X rows (Vt cols)
  int lane = t & 63, w = t >> 6;
  int wr = w >> 1, wc = w & 1;
  int q = lane >> 4, r = lane & 15;
  int srow = t >> 2;
  int skoff = (t & 3) * 8;
  size_t wrow1 = (size_t)(row0 + srow) * 512 + skoff;
  size_t wrow2 = (size_t)(row0 + 64 + srow) * 512 + skoff;
  size_t xrow1 = (size_t)(col0 + srow) * 1024 + skoff;
  size_t xrow2 = (size_t)(col0 + 64 + srow) * 1024 + skoff;
  const s8v sgn = {(short)0x8000, (short)0x8000, (short)0x8000, (short)0x8000,
                   (short)0x8000, (short)0x8000, (short)0x8000, (short)0x8000};

  floatx4 acc[4][4];
#pragma unroll
  for (int i = 0; i < 4; ++i)
#pragma unroll
    for (int j = 0; j < 4; ++j) acc[i][j] = (floatx4){0.f, 0.f, 0.f, 0.f};

  for (int k0 = 0; k0 < 1024; k0 += 32) {
    const unsigned short *WgH, *WgL;
    int kk = k0;
    bool xon = false;
    if (k0 < 512) { WgH = PH1; WgL = PL1; }
    else          { WgH = PH2; WgL = PL2; kk = k0 - 512; xon = neg2; }
    gll16(WgH + wrow1 + kk, (char*)Ah + t * 16);
    gll16(WgH + wrow2 + kk, (char*)Ah + 4096 + t * 16);
    gll16(WgL + wrow1 + kk, (char*)Al + t * 16);
    gll16(WgL + wrow2 + kk, (char*)Al + 4096 + t * 16);
    gll16(xh + xrow1 + k0, (char*)Bh + t * 16);
    gll16(xh + xrow2 + k0, (char*)Bh + 4096 + t * 16);
    gll16(xl + xrow1 + k0, (char*)Bl + t * 16);
    gll16(xl + xrow2 + k0, (char*)Bl + 4096 + t * 16);
    __syncthreads();
    s8v ah[4], al[4], bh[4], bl[4];
#pragma unroll
    for (int i = 0; i < 4; ++i) {
      int ro = (wr * 64 + i * 16 + r) * 32 + q * 8;
      ah[i] = *(const s8v*)((const short*)Ah + ro);
      al[i] = *(const s8v*)((const short*)Al + ro);
    }
#pragma unroll
    for (int j = 0; j < 4; ++j) {
      int ro = (wc * 64 + j * 16 + r) * 32 + q * 8;
      bh[j] = *(const s8v*)((const short*)Bh + ro);
      bl[j] = *(const s8v*)((const short*)Bl + ro);
    }
    if (xon) {                                 // sign-flip weight-side fragments (A side)
#pragma unroll
      for (int i = 0; i < 4; ++i) { ah[i] = ah[i] ^ sgn; al[i] = al[i] ^ sgn; }
    }
#pragma unroll
    for (int i = 0; i < 4; ++i)
#pragma unroll
      for (int j = 0; j < 4; ++j) {
        acc[i][j] = __builtin_amdgcn_mfma_f32_16x16x32_bf16(ah[i], bh[j], acc[i][j], 0, 0, 0);
        acc[i][j] = __builtin_amdgcn_mfma_f32_16x16x32_bf16(ah[i], bl[j], acc[i][j], 0, 0, 0);
        acc[i][j] = __builtin_amdgcn_mfma_f32_16x16x32_bf16(al[i], bh[j], acc[i][j], 0, 0, 0);
      }
    __syncthreads();
  }
  unsigned short* dh = (unsigned short*)(ws + OFF_VTH);
  unsigned short* dl = (unsigned short*)(ws + OFF_VTL);
  size_t base = (size_t)((w6 & 1) * 4 + m) * 512 * 1024;
#pragma unroll
  for (int i = 0; i < 4; ++i)
#pragma unroll
    for (int j = 0; j < 4; ++j) {
      int rowb = row0 + wr * 64 + i * 16 + q * 4;
      int colb = col0 + wc * 64 + j * 16 + r;
#pragma unroll
      for (int reg = 0; reg < 4; ++reg) {
        float v = acc[i][j][reg];
        unsigned short h = f2bf(v);
        size_t idx = base + (size_t)(rowb + reg) * 1024 + colb;
        dh[idx] = h;
        dl[idx] = f2bf(v - bf2f(h));
      }
    }
}

// ---------------- PV: O = P @ Vt^T (bf16x3 MFMA), fp32 out (R13 single-buffer) ----------------
__global__ __launch_bounds__(256) void k_pv(float* __restrict__ ws) {
  __shared__ __align__(16) unsigned short Ph_[128 * 32], Pl_[128 * 32];
  __shared__ __align__(16) unsigned short VrH[128 * 32], VrL[128 * 32];
  __shared__ __align__(16) unsigned short ViH[128 * 32], ViL[128 * 32];
  const unsigned short* ph = (const unsigned short*)(ws + OFF_PH);
  const unsigned short* pl = (const unsigned short*)(ws + OFF_PL);
  const unsigned short* vth = (const unsigned short*)(ws + OFF_VTH);
  const unsigned short* vtl = (const unsigned short*)(ws + OFF_VTL);
  int mb = blockIdx.y, m = mb >> 3, b = mb & 7;
  int col0 = blockIdx.x * 128;
  int t = threadIdx.x, lane = t & 63, w = t >> 6;
  int wr = w >> 1, wc = w & 1;
  int q = lane >> 4, r = lane & 15;
  int srow = t >> 2;
  int skoff = (t & 3) * 8;
  size_t prow1 = (size_t)(mb * 128 + srow) * 128 + skoff;
  size_t prow2 = (size_t)(mb * 128 + 64 + srow) * 128 + skoff;
  size_t vbr1 = ((size_t)(m * 512) + col0 + srow) * 1024 + b * 128 + skoff;
  size_t vbr2 = ((size_t)(m * 512) + col0 + 64 + srow) * 1024 + b * 128 + skoff;
  size_t vplane_i = (size_t)4 * 512 * 1024;

  floatx4 accR[4][4], accI[4][4];
#pragma unroll
  for (int i = 0; i < 4; ++i)
#pragma unroll
    for (int j = 0; j < 4; ++j) {
      accR[i][j] = (floatx4){0.f, 0.f, 0.f, 0.f};
      accI[i][j] = (floatx4){0.f, 0.f, 0.f, 0.f};
    }

  for (int k0 = 0; k0 < 128; k0 += 32) {
    gll16(ph + prow1 + k0, (char*)Ph_ + t * 16);
    gll16(ph + prow2 + k0, (char*)Ph_ + 4096 + t * 16);
    gll16(pl + prow1 + k0, (char*)Pl_ + t * 16);
    gll16(pl + prow2 + k0, (char*)Pl_ + 4096 + t * 16);
    gll16(vth + vbr1 + k0, (char*)VrH + t * 16);
    gll16(vth + vbr2 + k0, (char*)VrH + 4096 + t * 16);
    gll16(vtl + vbr1 + k0, (char*)VrL + t * 16);
    gll16(vtl + vbr2 + k0, (char*)VrL + 4096 + t * 16);
    gll16(vth + vplane_i + vbr1 + k0, (char*)ViH + t * 16);
    gll16(vth + vplane_i + vbr2 + k0, (char*)ViH + 4096 + t * 16);
    gll16(vtl + vplane_i + vbr1 + k0, (char*)ViL + t * 16);
    gll16(vtl + vplane_i + vbr2 + k0, (char*)ViL + 4096 + t * 16);
    __syncthreads();
    s8v ah[4], al[4];
#pragma unroll
    for (int i = 0; i < 4; ++i) {
      int ro = (wr * 64 + i * 16 + r) * 32 + q * 8;
      ah[i] = *(const s8v*)((const short*)Ph_ + ro);
      al[i] = *(const s8v*)((const short*)Pl_ + ro);
    }
#pragma unroll
    for (int j = 0; j < 4; ++j) {
      int ro = (wc * 64 + j * 16 + r) * 32 + q * 8;
      s8v vrh = *(const s8v*)((const short*)VrH + ro);
      s8v vrl = *(const s8v*)((const short*)VrL + ro);
      s8v vih = *(const s8v*)((const short*)ViH + ro);
      s8v vil = *(const s8v*)((const short*)ViL + ro);
#pragma unroll
      for (int i = 0; i < 4; ++i) {
        accR[i][j] = __builtin_amdgcn_mfma_f32_16x16x32_bf16(ah[i], vrh, accR[i][j], 0, 0, 0);
        accR[i][j] = __builtin_amdgcn_mfma_f32_16x16x32_bf16(ah[i], vrl, accR[i][j], 0, 0, 0);
        accR[i][j] = __builtin_amdgcn_mfma_f32_16x16x32_bf16(al[i], vrh, accR[i][j], 0, 0, 0);
        accI[i][j] = __builtin_amdgcn_mfma_f32_16x16x32_bf16(ah[i], vih, accI[i][j], 0, 0, 0);
        accI[i][j] = __builtin_amdgcn_mfma_f32_16x16x32_bf16(ah[i], vil, accI[i][j], 0, 0, 0);
        accI[i][j] = __builtin_amdgcn_mfma_f32_16x16x32_bf16(al[i], vih, accI[i][j], 0, 0, 0);
      }
    }
    __syncthreads();
  }
  float* orp = ws + OFF_OR + (size_t)mb * 128 * 512;
  float* oip = ws + OFF_OI + (size_t)mb * 128 * 512;
#pragma unroll
  for (int i = 0; i < 4; ++i)
#pragma unroll
    for (int j = 0; j < 4; ++j) {
      int rowb = wr * 64 + i * 16 + q * 4;
      int colb = col0 + wc * 64 + j * 16 + r;
#pragma unroll
      for (int reg = 0; reg < 4; ++reg) {
        orp[(size_t)(rowb + reg) * 512 + colb] = accR[i][j][reg];
        oip[(size_t)(rowb + reg) * 512 + colb] = accI[i][j][reg];
      }
    }
}

// ---------------- ModReLU + ComplexLayerNorm + feat partials (fused) + GRU finish ----------------
// R19: grid 136. blk<128: proven R9/R11 body. blk>=128: GRU finish (b = blk-128):
// read PART, add biases, nonlinearity, write hnew. Runs before k_wsel (hnew's only
// consumer); PART written in k_vattn (kernel-boundary ordered).
__global__ __launch_bounds__(256) void k_modlnfeat(float* __restrict__ ws,
                                                   const float* __restrict__ mod_bias,
                                                   const float* __restrict__ ln_scale,
                                                   const float* __restrict__ ln_shift,
                                                   const float* __restrict__ hold,
                                                   float* __restrict__ hnew,
                                                   const float* __restrict__ bih,
                                                   const float* __restrict__ bhh) {
  int blk = blockIdx.x;
  int t = threadIdx.x;
  if (blk >= 128) {
    int b = blk - 128;
    for (int c = t; c < 512; c += 256) {
      const float* part = ws + OFF_PART + ((size_t)b * 512 + c) * 4;
      float r_ = part[0] + bih[c] + bhh[c];
      float z_ = part[1] + bih[512 + c] + bhh[512 + c];
      float xn = part[2] + bih[1024 + c];
      float hn = part[3] + bhh[1024 + c];
      float r = 1.f / (1.f + expf(-r_));
      float z = 1.f / (1.f + expf(-z_));
      float n = tanhf(xn + r * hn);
      hnew[b * 512 + c] = (1.f - z) * n + z * hold[b * 512 + c];
    }
    return;
  }
  int mb = blk >> 2, grp = blk & 3;
  int m = mb >> 3;
  int w = t >> 6, l = t & 63;
  int e0 = l * 8;
  float mb_[8], lsc[8], lsh[8];
  *(float4*)&mb_[0] = *(const float4*)(mod_bias + m * 512 + e0);
  *(float4*)&mb_[4] = *(const float4*)(mod_bias + m * 512 + e0 + 4);
  *(float4*)&lsc[0] = *(const float4*)(ln_scale + m * 512 + e0);
  *(float4*)&lsc[4] = *(const float4*)(ln_scale + m * 512 + e0 + 4);
  *(float4*)&lsh[0] = *(const float4*)(ln_shift + m * 512 + e0);
  *(float4*)&lsh[4] = *(const float4*)(ln_shift + m * 512 + e0 + 4);
  float featR[8] = {}, featI[8] = {};
  for (int it = 0; it < 8; ++it) {
    int s = grp * 32 + it * 4 + w;
    float* orp = ws + OFF_OR + ((size_t)mb * 128 + s) * 512 + e0;
    float* oip = ws + OFF_OI + ((size_t)mb * 128 + s) * 512 + e0;
    float orv[8], oiv[8], magv[8];
    *(float4*)&orv[0] = *(const float4*)orp;
    *(float4*)&orv[4] = *(const float4*)(orp + 4);
    *(float4*)&oiv[0] = *(const float4*)oip;
    *(float4*)&oiv[4] = *(const float4*)(oip + 4);
    float sum = 0.f, sumsq = 0.f;
#pragma unroll
    for (int j = 0; j < 8; ++j) {
      float o_r = orv[j], o_i = oiv[j];
      float mag = sqrtf(o_r * o_r + o_i * o_i) + EPS;
      float g = fmaxf(mag + mb_[j], 0.f) / mag;
      o_r *= g; o_i *= g;
      orv[j] = o_r; oiv[j] = o_i;
      float mag2 = sqrtf(o_r * o_r + o_i * o_i) + EPS;
      magv[j] = mag2;
      sum += mag2;
      sumsq += mag2 * mag2;
    }
    for (int o = 1; o < 64; o <<= 1) {
      sum += __shfl_xor(sum, o);
      sumsq += __shfl_xor(sumsq, o);
    }
    float mu = sum * (1.f / D);
    float var = (sumsq - (float)D * mu * mu) * (1.f / (D - 1));
    float inv = 1.f / sqrtf(var + EPS);
#pragma unroll
    for (int j = 0; j < 8; ++j) {
      float nm = (magv[j] - mu) * inv * lsc[j] + lsh[j];
      float hyp = magv[j] - EPS;
      float cp, sp;
      if (hyp > 0.f) { cp = orv[j] / hyp; sp = oiv[j] / hyp; }
      else           { cp = 1.f;          sp = 0.f; }
      orv[j] = nm * cp;
      oiv[j] = nm * sp;
      featR[j] += orv[j];
      featI[j] += oiv[j];
    }
    *(float4*)orp = *(float4*)&orv[0];
    *(float4*)(orp + 4) = *(float4*)&orv[4];
    *(float4*)oip = *(float4*)&oiv[0];
    *(float4*)(oip + 4) = *(float4*)&oiv[4];
  }
  float* fb = ws + OFF_FEAT + (size_t)mb * 1024;
#pragma unroll
  for (int j = 0; j < 8; ++j) {
    atomicAdd(fb + e0 + j, featR[j] * (1.0f / S));
    atomicAdd(fb + 512 + e0 + j, featI[j] * (1.0f / S));
  }
}

// ---------------- wsel (R1) + zero FEAT/GWP for next step (R9) ----------------
__global__ __launch_bounds__(256) void k_wsel(float* __restrict__ ws,
                                              const float* __restrict__ hnew,
                                              const float* __restrict__ bias_W,
                                              const float* __restrict__ bias_b,
                                              const float* __restrict__ w_sal) {
  __shared__ float mb_s[B][M];
  __shared__ float sal_s[M][B];
  int t = threadIdx.x;
  int p = t >> 3, l = t & 7;
  {
    int b = p >> 2, m = p & 3;
    float s = 0.f;
    for (int d2 = l; d2 < D; d2 += 8) s += hnew[b * D + d2] * bias_W[d2 * M + m];
    for (int o = 1; o < 8; o <<= 1) s += __shfl_xor(s, o);
    if (l == 0) mb_s[b][m] = s + bias_b[m];
  }
  {
    int m = p >> 3, b = p & 7;
    float s = 0.f;
    for (int f = l; f < 2 * D; f += 8) s += ws[OFF_FEAT + (m * B + b) * 2 * D + f] * w_sal[m * 2 * D + f];
    for (int o = 1; o < 8; o <<= 1) s += __shfl_xor(s, o);
    if (l == 0) sal_s[m][b] = s;
  }
  __syncthreads();
  if (t < B) {
    int b = t;
    float lg[M], mx = -1e30f;
#pragma unroll
    for (int m = 0; m < M; ++m) { lg[m] = sal_s[m][b] + mb_s[b][m]; mx = fmaxf(mx, lg[m]); }
    float sm = 0.f;
#pragma unroll
    for (int m = 0; m < M; ++m) { lg[m] = expf(lg[m] - mx); sm += lg[m]; }
    float inv = 1.f / sm;
#pragma unroll
    for (int m = 0; m < M; ++m) ws[OFF_W + m * B + b] = lg[m] * inv;
  }
  float4 z4 = {0.f, 0.f, 0.f, 0.f};
  for (int i = t; i < 16384; i += 256) ((float4*)(ws + OFF_FEAT))[i] = z4;
  for (int i = t; i < 2048; i += 256) ((float4*)(ws + OFF_GWP))[i] = z4;
}

// ---------------- bcast (fp32 Z + bf16 Xcat) + gwp partial accumulation (R9) ----------------
__global__ __launch_bounds__(256) void k_bcast(float* __restrict__ ws) {
  __shared__ float pr[1024];
  unsigned short* xh = (unsigned short*)(ws + OFF_XH);
  unsigned short* xl = (unsigned short*)(ws + OFF_XL);
  int t = threadIdx.x;
  int i4 = blockIdx.x * 256 + t;
  int b = i4 >> 14;
  int l = t & 127;
  float w0 = ws[OFF_W + 0 * B + b], w1 = ws[OFF_W + 1 * B + b];
  float w2 = ws[OFF_W + 2 * B + b], w3 = ws[OFF_W + 3 * B + b];
  const float4* mr = (const float4*)(ws + OFF_OR);
  const float4* mi = (const float4*)(ws + OFF_OI);
  const int MS = BSD / 4;
  int row = i4 >> 7;
  int d4 = (i4 & 127) * 4;
  float4 r0 = mr[i4], r1 = mr[i4 + MS], r2 = mr[i4 + 2 * MS], r3 = mr[i4 + 3 * MS];
  float gvR[4];
  gvR[0] = w0 * r0.x + w1 * r1.x + w2 * r2.x + w3 * r3.x;
  gvR[1] = w0 * r0.y + w1 * r1.y + w2 * r2.y + w3 * r3.y;
  gvR[2] = w0 * r0.z + w1 * r1.z + w2 * r2.z + w3 * r3.z;
  gvR[3] = w0 * r0.w + w1 * r1.w + w2 * r2.w + w3 * r3.w;
  ((float4*)(ws + OFF_ZR))[i4] = (float4){gvR[0], gvR[1], gvR[2], gvR[3]};
  us4 hh, hl;
#pragma unroll
  for (int j = 0; j < 4; ++j) {
    unsigned short h = f2bf(gvR[j]); hh[j] = h; hl[j] = f2bf(gvR[j] - bf2f(h));
  }
  *(us4*)(xh + (size_t)row * 1024 + d4) = hh;
  *(us4*)(xl + (size_t)row * 1024 + d4) = hl;
  float4 s0 = mi[i4], s1 = mi[i4 + MS], s2 = mi[i4 + 2 * MS], s3 = mi[i4 + 3 * MS];
  float gvI[4];
  gvI[0] = w0 * s0.x + w1 * s1.x + w2 * s2.x + w3 * s3.x;
  gvI[1] = w0 * s0.y + w1 * s1.y + w2 * s2.y + w3 * s3.y;
  gvI[2] = w0 * s0.z + w1 * s1.z + w2 * s2.z + w3 * s3.z;
  gvI[3] = w0 * s0.w + w1 * s1.w + w2 * s2.w + w3 * s3.w;
  ((float4*)(ws + OFF_ZI))[i4] = (float4){gvI[0], gvI[1], gvI[2], gvI[3]};
#pragma unroll
  for (int j = 0; j < 4; ++j) {
    unsigned short h = f2bf(gvI[j]); hh[j] = h; hl[j] = f2bf(gvI[j] - bf2f(h));
  }
  *(us4*)(xh + (size_t)row * 1024 + 512 + d4) = hh;
  *(us4*)(xl + (size_t)row * 1024 + 512 + d4) = hl;
  if (t < 128) {
#pragma unroll
    for (int j = 0; j < 4; ++j) { pr[l * 4 + j] = gvR[j]; pr[512 + l * 4 + j] = gvI[j]; }
  }
  __syncthreads();
  if (t >= 128) {
#pragma unroll
    for (int j = 0; j < 4; ++j) { pr[l * 4 + j] += gvR[j]; pr[512 + l * 4 + j] += gvI[j]; }
  }
  __syncthreads();
  for (int pp = t; pp < 1024; pp += 256)
    atomicAdd(ws + OFF_GWP + b * 1024 + pp, pr[pp] * (1.0f / S));
}

// ---------------- halt + ACT accumulate (fused; cum double-buffered) (R9) ----------------
__global__ __launch_bounds__(256) void k_acchalt(float* __restrict__ ws,
                                                 const float* __restrict__ w_halt,
                                                 const float* __restrict__ b_halt,
                                                 const float* __restrict__ cumr,
                                                 float* __restrict__ cumw) {
  __shared__ float sred[4];
  int t = threadIdx.x;
  int i4 = blockIdx.x * 256 + t;
  int b = i4 >> 14;
  float4 g = *(const float4*)(ws + OFF_GWP + b * 1024 + t * 4);
  float4 wv = *(const float4*)(w_halt + t * 4);
  float s = g.x * wv.x + g.y * wv.y + g.z * wv.z + g.w * wv.w;
  for (int o = 1; o < 64; o <<= 1) s += __shfl_xor(s, o);
  if ((t & 63) == 0) sred[t >> 6] = s;
  __syncthreads();
  float tot = sred[0] + sred[1] + sred[2] + sred[3];
  float p = 1.f / (1.f + expf(-(tot + b_halt[0])));
  float cum = cumr[b];
  float still = (cum < THRESH) ? 1.f : 0.f;
  bool nh = ((cum + p) >= THRESH) && (cum < THRESH);
  float wt = (nh ? (1.f - cum) : p) * still;
  if (((blockIdx.x & 63) == 0) && t == 0) cumw[b] = cum + wt;
  float4 z = ((const float4*)(ws + OFF_ZR))[i4];
  float4 a = ((float4*)(ws + OFF_AR))[i4];
  a.x += wt * z.x; a.y += wt * z.y; a.z += wt * z.z; a.w += wt * z.w;
  ((float4*)(ws + OFF_AR))[i4] = a;
  z = ((const float4*)(ws + OFF_ZI))[i4];
  a = ((float4*)(ws + OFF_AI))[i4];
  a.x += wt * z.x; a.y += wt * z.y; a.z += wt * z.z; a.w += wt * z.w;
  ((float4*)(ws + OFF_AI))[i4] = a;
}

// ---------------- output (R1) ----------------
__global__ __launch_bounds__(256) void k_out(const float* __restrict__ ws,
                                             float* __restrict__ out) {
  int i4 = blockIdx.x * 256 + threadIdx.x;
  ((float4*)out)[i4] = ((const float4*)(ws + OFF_AR))[i4];
  ((float4*)out)[i4 + BSD / 4] = ((const float4*)(ws + OFF_AI))[i4];
}

extern "C" void kernel_launch(void* const* d_in, const int* in_sizes, int n_in,
                              void* d_out, int out_size, void* d_ws, size_t ws_size,
                              hipStream_t stream) {
  (void)in_sizes; (void)n_in; (void)out_size; (void)ws_size;
  const float* x_real  = (const float*)d_in[0];
  const float* x_imag  = (const float*)d_in[1];
  const float* Wq_r    = (const float*)d_in[2];
  const float* Wq_i    = (const float*)d_in[3];
  const float* Wk_r    = (const float*)d_in[4];
  const float* Wk_i    = (const float*)d_in[5];
  const float* Wv_r    = (const float*)d_in[6];
  const float* Wv_i    = (const float*)d_in[7];
  const float* mod_bias = (const float*)d_in[8];
  const float* ln_scale = (const float*)d_in[9];
  const float* ln_shift = (const float*)d_in[10];
  const float* w_sal   = (const float*)d_in[11];
  const float* gru_Wih = (const float*)d_in[12];
  const float* gru_Whh = (const float*)d_in[13];
  const float* gru_bih = (const float*)d_in[14];
  const float* gru_bhh = (const float*)d_in[15];
  const float* bias_W  = (const float*)d_in[16];
  const float* bias_b  = (const float*)d_in[17];
  const float* w_halt  = (const float*)d_in[18];
  const float* b_halt  = (const float*)d_in[19];
  float* ws = (float*)d_ws;
  float* out = (float*)d_out;

  k_wprep<<<dim3(8, 8, 24), 256, 0, stream>>>(Wq_r, Wq_i, Wk_r, Wk_i, Wv_r, Wv_i, ws);
  k_init<<<512, 256, 0, stream>>>(x_real, x_imag, ws);
  k_gwp<<<32, 256, 0, stream>>>(ws + OFF_ZR, ws + OFF_ZI, ws + OFF_GWP);
  for (int step = 0; step < DEPTH; ++step) {
    const float* hold = ws + ((step & 1) ? OFF_H1 : OFF_H0);
    float* hnew = ws + ((step & 1) ? OFF_H0 : OFF_H1);
    const float* cumr = ws + ((step & 1) ? OFF_CUM2 : OFF_CUM);
    float* cumw = ws + ((step & 1) ? OFF_CUM : OFF_CUM2);
    k_qk<<<dim3(4, 8, 16), 256, 0, stream>>>(ws);
    k_vattn<<<576, 256, 0, stream>>>(ws, ws + OFF_GWP, hold, gru_Wih, gru_Whh);
    k_pv<<<dim3(4, 32), 256, 0, stream>>>(ws);
    k_modlnfeat<<<136, 256, 0, stream>>>(ws, mod_bias, ln_scale, ln_shift,
                                         hold, hnew, gru_bih, gru_bhh);
    k_wsel<<<1, 256, 0, stream>>>(ws, hnew, bias_W, bias_b, w_sal);
    k_bcast<<<512, 256, 0, stream>>>(ws);
    k_acchalt<<<512, 256, 0, stream>>>(ws, w_halt, b_halt, cumr, cumw);
  }
  k_out<<<512, 256, 0, stream>>>(ws, out);
}

// Round 9
// 3295.966 us; speedup vs baseline: 1.2864x; 1.0334x over previous
//
#include <hip/hip_runtime.h>
#include <math.h>

#define B 8
#define S 128
#define D 512
#define M 4
#define BS 1024
#define BSD 524288          // B*S*D
#define DEPTH 16
#define THRESH 0.9999f
#define EPS 1e-6f
#define SCALE 0.04419417382415922f   // D^-0.5

typedef float floatx4 __attribute__((ext_vector_type(4)));
typedef short s8v __attribute__((ext_vector_type(8)));
typedef unsigned short us4 __attribute__((ext_vector_type(4)));

__device__ __forceinline__ unsigned short f2bf(float f) {
  unsigned int u = __float_as_uint(f);
  u += 0x7FFFu + ((u >> 16) & 1u);          // round-to-nearest-even
  return (unsigned short)(u >> 16);
}
__device__ __forceinline__ float bf2f(unsigned short h) {
  return __uint_as_float((unsigned int)h << 16);
}

// async global->LDS, 16B per lane, linear LDS dest (wave-uniform base + lane*16)
__device__ __forceinline__ void gll16(const void* g, void* l) {
  __builtin_amdgcn_global_load_lds(
      (const __attribute__((address_space(1))) unsigned int*)g,
      (__attribute__((address_space(3))) unsigned int*)l, 16, 0, 0);
}

// ---------------- workspace layout (float-slot offsets) ----------------
#define OFF_ZR   0
#define OFF_ZI   (1*BSD)
#define OFF_AR   (2*BSD)
#define OFF_AI   (3*BSD)
#define OFF_OR   (4*BSD)            // [M][B][S][D] fp32 = 4*BSD
#define OFF_OI   (8*BSD)
#define OFF_FEAT (12*BSD)           // 65536
#define OFF_GWP  (12*BSD + 65536)   // 8192
#define OFF_H0   (12*BSD + 73728)
#define OFF_H1   (12*BSD + 77824)
#define OFF_CUM  (12*BSD + 81920)   // 8
#define OFF_W    (12*BSD + 81928)   // 32
#define OFF_WT   (12*BSD + 81960)   // 8
#define OFF_CUM2 (12*BSD + 81968)   // 8
// R19: GRU partial-sum scratch PART[B][512][4] = 16384 floats, OVERLAYS OFF_ZR.
//   R20: in-loop ZR/ZI fp32 are now fully dead (acchalt fused into bcast), so the
//   overlay is trivially safe: k_qk zeroes -> k_vattn atomicAdds -> k_modlnfeat reads.
#define OFF_PART OFF_ZR
// bf16 annex (slots)
#define OFF_XH   (12*BSD + 90112)           // xcat hi [1024][1024] = 1 BSD
#define OFF_XL   (OFF_XH + 1*BSD)
#define OFF_WH   (OFF_XH + 2*BSD)           // 24 planes [512][512] hi = 6 BSD
#define OFF_WL   (OFF_XH + 8*BSD)
#define OFF_QCH  (OFF_XH + 14*BSD)          // Qcat hi [M][1024][1024] = 4 BSD
#define OFF_QCL  (OFF_XH + 18*BSD)
#define OFF_KCH  (OFF_XH + 22*BSD)
#define OFF_KCL  (OFF_XH + 26*BSD)
#define OFF_VTH  (OFF_XH + 30*BSD)          // Vt hi [2ri][M][512][1024] = 4 BSD
#define OFF_VTL  (OFF_XH + 34*BSD)
#define OFF_PH   (OFF_XH + 38*BSD)          // P hi [32][128][128] = 262144 slots
#define OFF_PL   (OFF_PH + 262144)
// end ~= 107.3 MB (R6/R8 proven)

// ---------------- init: fp32 carry + bf16 hi/lo Xcat + zero FEAT/GWP/CUMs ----------------
__global__ __launch_bounds__(256) void k_init(const float* __restrict__ xr,
                                              const float* __restrict__ xi,
                                              float* __restrict__ ws) {
  unsigned short* xh = (unsigned short*)(ws + OFF_XH);
  unsigned short* xl = (unsigned short*)(ws + OFF_XL);
  int i4 = blockIdx.x * 256 + threadIdx.x;      // BSD/4
  float4 a = ((const float4*)xr)[i4];
  float4 b = ((const float4*)xi)[i4];
  ((float4*)(ws + OFF_ZR))[i4] = a;
  ((float4*)(ws + OFF_ZI))[i4] = b;
  float4 z = {0.f, 0.f, 0.f, 0.f};
  ((float4*)(ws + OFF_AR))[i4] = z;
  ((float4*)(ws + OFF_AI))[i4] = z;
  int row = i4 >> 7;
  int d4 = (i4 & 127) * 4;
  float av[4] = {a.x, a.y, a.z, a.w}, bv[4] = {b.x, b.y, b.z, b.w};
  us4 hh, hl;
#pragma unroll
  for (int j = 0; j < 4; ++j) {
    unsigned short h = f2bf(av[j]); hh[j] = h; hl[j] = f2bf(av[j] - bf2f(h));
  }
  *(us4*)(xh + (size_t)row * 1024 + d4) = hh;
  *(us4*)(xl + (size_t)row * 1024 + d4) = hl;
#pragma unroll
  for (int j = 0; j < 4; ++j) {
    unsigned short h = f2bf(bv[j]); hh[j] = h; hl[j] = f2bf(bv[j] - bf2f(h));
  }
  *(us4*)(xh + (size_t)row * 1024 + 512 + d4) = hh;
  *(us4*)(xl + (size_t)row * 1024 + 512 + d4) = hl;
  if (i4 < (B * D) / 4) {
    ((float4*)(ws + OFF_H0))[i4] = z;
    ((float4*)(ws + OFF_H1))[i4] = z;
  }
  if (i4 < 16384) ((float4*)(ws + OFF_FEAT))[i4] = z;
  if (i4 < 2048)  ((float4*)(ws + OFF_GWP))[i4] = z;
  if (i4 < B) { ws[OFF_CUM + i4] = 0.f; ws[OFF_CUM2 + i4] = 0.f; }
}

// ---------------- weight prep (R6, proven) ----------------
__global__ __launch_bounds__(256) void k_wprep(const float* __restrict__ Wqr,
                                               const float* __restrict__ Wqi,
                                               const float* __restrict__ Wkr,
                                               const float* __restrict__ Wki,
                                               const float* __restrict__ Wvr,
                                               const float* __restrict__ Wvi,
                                               float* __restrict__ ws) {
  __shared__ float lt[64][65];
  unsigned short* wh = (unsigned short*)(ws + OFF_WH);
  unsigned short* wl = (unsigned short*)(ws + OFF_WL);
  int z = blockIdx.z, m = z / 6, idx = z % 6;
  const float* Wsrc;
  switch (idx) {
    case 0:  Wsrc = Wqr; break;
    case 1:  Wsrc = Wqi; break;
    case 2:  Wsrc = Wkr; break;
    case 3:  Wsrc = Wki; break;
    case 4:  Wsrc = Wvr; break;
    default: Wsrc = Wvi; break;
  }
  Wsrc += (size_t)m * D * D;
  int k0 = blockIdx.x * 64, n0 = blockIdx.y * 64;
  int tx = threadIdx.x & 63, ty = threadIdx.x >> 6;
#pragma unroll
  for (int i = 0; i < 16; ++i) {
    int kl = ty + i * 4;
    lt[kl][tx] = Wsrc[(size_t)(k0 + kl) * D + n0 + tx];
  }
  __syncthreads();
  unsigned short* whp = wh + (size_t)z * 262144;
  unsigned short* wlp = wl + (size_t)z * 262144;
#pragma unroll
  for (int i = 0; i < 16; ++i) {
    int nl = ty + i * 4;
    float v = lt[tx][nl];
    unsigned short h = f2bf(v);
    whp[(size_t)(n0 + nl) * 512 + k0 + tx] = h;
    wlp[(size_t)(n0 + nl) * 512 + k0 + tx] = f2bf(v - bf2f(h));
  }
}

// ---------------- gwp (pre-loop only) ----------------
__global__ __launch_bounds__(256) void k_gwp(const float* __restrict__ zr,
                                             const float* __restrict__ zi,
                                             float* __restrict__ gwp) {
  int idx = blockIdx.x * 256 + threadIdx.x;
  int b = idx >> 10;
  int f = idx & 1023;
  const float* src = (f < D) ? (zr + b * S * D + f) : (zi + b * S * D + (f - D));
  float s = 0.f;
#pragma unroll 8
  for (int ss = 0; ss < S; ++ss) s += src[ss * D];
  gwp[idx] = s * (1.0f / S);
}

// ---------------- k_qk: Q/K GEMMs only (R16-proven; 512 blocks = 2 CU-rounds) ----------------
// Block (0,0,0) additionally zeroes PART before its GEMM.
__global__ __launch_bounds__(256) void k_qk(float* __restrict__ ws) {
  __shared__ __align__(16) unsigned short Ah[128 * 32], Al[128 * 32];
  __shared__ __align__(16) unsigned short Bh[128 * 32], Bl[128 * 32];
  int t = threadIdx.x;
  if (blockIdx.x == 0 && blockIdx.y == 0 && blockIdx.z == 0) {
    float4 z4 = {0.f, 0.f, 0.f, 0.f};
    for (int i = t; i < 4096; i += 256) ((float4*)(ws + OFF_PART))[i] = z4;
  }
  const unsigned short* xh = (const unsigned short*)(ws + OFF_XH);
  const unsigned short* xl = (const unsigned short*)(ws + OFF_XL);
  const unsigned short* wh = (const unsigned short*)(ws + OFF_WH);
  const unsigned short* wl = (const unsigned short*)(ws + OFF_WL);
  int z = blockIdx.z, m = z >> 2, w6 = z & 3;
  int pair = (w6 >> 1) * 2;
  int p1 = m * 6 + pair + (w6 & 1);
  int p2 = m * 6 + pair + ((w6 & 1) ^ 1);
  bool neg2 = ((w6 & 1) == 0);               // real-output GEMMs negate second K-half
  const unsigned short* PH1 = wh + (size_t)p1 * 262144;
  const unsigned short* PL1 = wl + (size_t)p1 * 262144;
  const unsigned short* PH2 = wh + (size_t)p2 * 262144;
  const unsigned short* PL2 = wl + (size_t)p2 * 262144;

  int row0 = blockIdx.y * 128;    // X rows
  int col0 = blockIdx.x * 128;    // W cols
  int lane = t & 63, w = t >> 6;
  int wr = w >> 1, wc = w & 1;
  int q = lane >> 4, r = lane & 15;
  int srow = t >> 2;
  int skoff = (t & 3) * 8;
  size_t wrow1 = (size_t)(col0 + srow) * 512 + skoff;
  size_t wrow2 = (size_t)(col0 + 64 + srow) * 512 + skoff;
  size_t xrow1 = (size_t)(row0 + srow) * 1024 + skoff;
  size_t xrow2 = (size_t)(row0 + 64 + srow) * 1024 + skoff;
  const s8v sgn = {(short)0x8000, (short)0x8000, (short)0x8000, (short)0x8000,
                   (short)0x8000, (short)0x8000, (short)0x8000, (short)0x8000};

  floatx4 acc[4][4];
#pragma unroll
  for (int i = 0; i < 4; ++i)
#pragma unroll
    for (int j = 0; j < 4; ++j) acc[i][j] = (floatx4){0.f, 0.f, 0.f, 0.f};

  for (int k0 = 0; k0 < 1024; k0 += 32) {
    const unsigned short *WgH, *WgL;
    int kk = k0;
    bool xon = false;
    if (k0 < 512) { WgH = PH1; WgL = PL1; }
    else          { WgH = PH2; WgL = PL2; kk = k0 - 512; xon = neg2; }
    gll16(xh + xrow1 + k0, (char*)Ah + t * 16);
    gll16(xh + xrow2 + k0, (char*)Ah + 4096 + t * 16);
    gll16(xl + xrow1 + k0, (char*)Al + t * 16);
    gll16(xl + xrow2 + k0, (char*)Al + 4096 + t * 16);
    gll16(WgH + wrow1 + kk, (char*)Bh + t * 16);
    gll16(WgH + wrow2 + kk, (char*)Bh + 4096 + t * 16);
    gll16(WgL + wrow1 + kk, (char*)Bl + t * 16);
    gll16(WgL + wrow2 + kk, (char*)Bl + 4096 + t * 16);
    __syncthreads();
    s8v ah[4], al[4], bh[4], bl[4];
#pragma unroll
    for (int i = 0; i < 4; ++i) {
      int ro = (wr * 64 + i * 16 + r) * 32 + q * 8;
      ah[i] = *(const s8v*)((const short*)Ah + ro);
      al[i] = *(const s8v*)((const short*)Al + ro);
    }
#pragma unroll
    for (int j = 0; j < 4; ++j) {
      int ro = (wc * 64 + j * 16 + r) * 32 + q * 8;
      bh[j] = *(const s8v*)((const short*)Bh + ro);
      bl[j] = *(const s8v*)((const short*)Bl + ro);
    }
    if (xon) {
#pragma unroll
      for (int j = 0; j < 4; ++j) { bh[j] = bh[j] ^ sgn; bl[j] = bl[j] ^ sgn; }
    }
#pragma unroll
    for (int i = 0; i < 4; ++i)
#pragma unroll
      for (int j = 0; j < 4; ++j) {
        acc[i][j] = __builtin_amdgcn_mfma_f32_16x16x32_bf16(ah[i], bh[j], acc[i][j], 0, 0, 0);
        acc[i][j] = __builtin_amdgcn_mfma_f32_16x16x32_bf16(ah[i], bl[j], acc[i][j], 0, 0, 0);
        acc[i][j] = __builtin_amdgcn_mfma_f32_16x16x32_bf16(al[i], bh[j], acc[i][j], 0, 0, 0);
      }
    __syncthreads();
  }
  unsigned short *dh, *dl;
  if (w6 < 2) { dh = (unsigned short*)(ws + OFF_QCH); dl = (unsigned short*)(ws + OFF_QCL); }
  else        { dh = (unsigned short*)(ws + OFF_KCH); dl = (unsigned short*)(ws + OFF_KCL); }
  int half = (w6 & 1) * 512;
  size_t base = (size_t)m * 1024 * 1024;
#pragma unroll
  for (int i = 0; i < 4; ++i)
#pragma unroll
    for (int j = 0; j < 4; ++j) {
      int rowb = row0 + wr * 64 + i * 16 + q * 4;
      int colb = col0 + wc * 64 + j * 16 + r;
#pragma unroll
      for (int reg = 0; reg < 4; ++reg) {
        float v = acc[i][j][reg];
        unsigned short h = f2bf(v);
        size_t idx = base + (size_t)(rowb + reg) * 1024 + half + colb;
        dh[idx] = h;
        dl[idx] = f2bf(v - bf2f(h));
      }
    }
}

// ---------------- k_vattn: V GEMM (blk<256) + attn (256..319) + GRU-partials (320..575) ----------------
// R19-proven structure.
__global__ __launch_bounds__(256) void k_vattn(float* __restrict__ ws,
                                               const float* __restrict__ gwp,
                                               const float* __restrict__ hold,
                                               const float* __restrict__ Wih,
                                               const float* __restrict__ Whh) {
  __shared__ __align__(16) unsigned short Ah[128 * 32], Al[128 * 32];
  __shared__ __align__(16) unsigned short Bh[128 * 32], Bl[128 * 32];
  __shared__ float rmax[64][4];
  __shared__ float rsum[64][4];
  int t = threadIdx.x;
  int blk = blockIdx.x;

  if (blk >= 320) {
    // ---- GRU partial path ----
    float* xbuf = (float*)Ah;                 // 1024 floats
    float* hbuf = (float*)Al;                 // 512 floats
    float (*red)[64][4] = (float (*)[64][4])Bh;
    int idx = blk - 320;                      // 0..255
    int b = idx >> 5;                         // 8
    int cc = (idx >> 2) & 7;                  // 8
    int kq = idx & 3;                         // 4
    int c0 = cc * 64;
    int td = t & 63, ks = t >> 6;
    for (int f = t; f < 1024; f += 256) xbuf[f] = gwp[b * 1024 + f];
    for (int d2 = t; d2 < 512; d2 += 256) hbuf[d2] = hold[b * 512 + d2];
    __syncthreads();
    float aR = 0.f, aZ = 0.f, aXn = 0.f, aHn = 0.f;
    int kbeg = kq * 384 + ks * 96, kend = kbeg + 96;
#pragma unroll 8
    for (int kk = kbeg; kk < kend; ++kk) {
      bool ih = kk < 1024;
      float x = ih ? xbuf[kk] : hbuf[kk - 1024];
      const float* base = ih ? (Wih + (size_t)kk * 1536) : (Whh + (size_t)(kk - 1024) * 1536);
      float wr = base[c0 + td];
      float wz = base[512 + c0 + td];
      float wn = base[1024 + c0 + td];
      aR += x * wr;
      aZ += x * wz;
      if (ih) aXn += x * wn; else aHn += x * wn;
    }
    red[ks][td][0] = aR;
    red[ks][td][1] = aZ;
    red[ks][td][2] = aXn;
    red[ks][td][3] = aHn;
    __syncthreads();
    if (t < 64) {
      float r_ = 0.f, z_ = 0.f, xn = 0.f, hn = 0.f;
#pragma unroll
      for (int s = 0; s < 4; ++s) {
        r_ += red[s][t][0]; z_ += red[s][t][1]; xn += red[s][t][2]; hn += red[s][t][3];
      }
      float* part = ws + OFF_PART + ((size_t)b * 512 + c0 + t) * 4;
      atomicAdd(part + 0, r_);
      atomicAdd(part + 1, z_);
      atomicAdd(part + 2, xn);
      atomicAdd(part + 3, hn);
    }
    return;
  }

  if (blk >= 256) {
    // ---- attn path (R16-proven body; 64 Q-rows x 128 K-cols) ----
    const unsigned short* qch = (const unsigned short*)(ws + OFF_QCH);
    const unsigned short* qcl = (const unsigned short*)(ws + OFF_QCL);
    const unsigned short* kch = (const unsigned short*)(ws + OFF_KCH);
    const unsigned short* kcl = (const unsigned short*)(ws + OFF_KCL);
    unsigned short* ph = (unsigned short*)(ws + OFF_PH);
    unsigned short* pl = (unsigned short*)(ws + OFF_PL);
    int ablk = blk - 256, mb = ablk >> 1, half = ablk & 1;
    size_t gbase = (size_t)mb * 128 * 1024;
    int lane = t & 63, wc = t >> 6;
    int q = lane >> 4, r = lane & 15;
    int srow = t >> 2;
    int skoff = (t & 3) * 8;
    size_t arow = gbase + (size_t)(half * 64 + srow) * 1024 + skoff;
    size_t brow1 = gbase + (size_t)srow * 1024 + skoff;
    size_t brow2 = gbase + (size_t)(64 + srow) * 1024 + skoff;

    floatx4 acc[4][2];
#pragma unroll
    for (int i = 0; i < 4; ++i)
#pragma unroll
      for (int j = 0; j < 2; ++j) acc[i][j] = (floatx4){0.f, 0.f, 0.f, 0.f};

    for (int k0 = 0; k0 < 1024; k0 += 32) {
      gll16(qch + arow + k0, (char*)Ah + t * 16);
      gll16(qcl + arow + k0, (char*)Al + t * 16);
      gll16(kch + brow1 + k0, (char*)Bh + t * 16);
      gll16(kch + brow2 + k0, (char*)Bh + 4096 + t * 16);
      gll16(kcl + brow1 + k0, (char*)Bl + t * 16);
      gll16(kcl + brow2 + k0, (char*)Bl + 4096 + t * 16);
      __syncthreads();
      s8v ah[4], al[4], bh[2], bl[2];
#pragma unroll
      for (int i = 0; i < 4; ++i) {
        int ro = (i * 16 + r) * 32 + q * 8;
        ah[i] = *(const s8v*)((const short*)Ah + ro);
        al[i] = *(const s8v*)((const short*)Al + ro);
      }
#pragma unroll
      for (int j = 0; j < 2; ++j) {
        int ro = (wc * 32 + j * 16 + r) * 32 + q * 8;
        bh[j] = *(const s8v*)((const short*)Bh + ro);
        bl[j] = *(const s8v*)((const short*)Bl + ro);
      }
#pragma unroll
      for (int i = 0; i < 4; ++i)
#pragma unroll
        for (int j = 0; j < 2; ++j) {
          acc[i][j] = __builtin_amdgcn_mfma_f32_16x16x32_bf16(ah[i], bh[j], acc[i][j], 0, 0, 0);
          acc[i][j] = __builtin_amdgcn_mfma_f32_16x16x32_bf16(ah[i], bl[j], acc[i][j], 0, 0, 0);
          acc[i][j] = __builtin_amdgcn_mfma_f32_16x16x32_bf16(al[i], bh[j], acc[i][j], 0, 0, 0);
        }
      __syncthreads();
    }
#pragma unroll
    for (int i = 0; i < 4; ++i)
#pragma unroll
      for (int j = 0; j < 2; ++j)
#pragma unroll
        for (int reg = 0; reg < 4; ++reg) acc[i][j][reg] *= SCALE;
#pragma unroll
    for (int i = 0; i < 4; ++i)
#pragma unroll
      for (int reg = 0; reg < 4; ++reg) {
        float mx = fmaxf(acc[i][0][reg], acc[i][1][reg]);
        for (int o = 1; o < 16; o <<= 1) mx = fmaxf(mx, __shfl_xor(mx, o));
        if (r == 0) rmax[i * 16 + q * 4 + reg][wc] = mx;
      }
    __syncthreads();
#pragma unroll
    for (int i = 0; i < 4; ++i)
#pragma unroll
      for (int reg = 0; reg < 4; ++reg) {
        int row = i * 16 + q * 4 + reg;
        float gmx = fmaxf(fmaxf(rmax[row][0], rmax[row][1]),
                          fmaxf(rmax[row][2], rmax[row][3]));
        float sm = 0.f;
#pragma unroll
        for (int j = 0; j < 2; ++j) {
          float e = __expf(acc[i][j][reg] - gmx);
          acc[i][j][reg] = e;
          sm += e;
        }
        for (int o = 1; o < 16; o <<= 1) sm += __shfl_xor(sm, o);
        if (r == 0) rsum[row][wc] = sm;
      }
    __syncthreads();
#pragma unroll
    for (int i = 0; i < 4; ++i)
#pragma unroll
      for (int reg = 0; reg < 4; ++reg) {
        int row = i * 16 + q * 4 + reg;
        float inv = 1.f / (rsum[row][0] + rsum[row][1] + rsum[row][2] + rsum[row][3]);
        size_t rb = (size_t)(mb * 128 + half * 64 + row) * 128;
#pragma unroll
        for (int j = 0; j < 2; ++j) {
          float p = acc[i][j][reg] * inv;
          unsigned short h = f2bf(p);
          size_t idx = rb + wc * 32 + j * 16 + r;
          ph[idx] = h;
          pl[idx] = f2bf(p - bf2f(h));
        }
      }
    return;
  }

  // ---- V GEMM path (R13-proven body, w6 in {4,5}) ----
  const unsigned short* xh = (const unsigned short*)(ws + OFF_XH);
  const unsigned short* xl = (const unsigned short*)(ws + OFF_XL);
  const unsigned short* wh = (const unsigned short*)(ws + OFF_WH);
  const unsigned short* wl = (const unsigned short*)(ws + OFF_WL);
  int plane = blk >> 5, m = plane >> 1, w6 = 4 + (plane & 1);
  int bx = (blk & 31) >> 3, by = blk & 7;
  int p1 = m * 6 + 4 + (w6 & 1);
  int p2 = m * 6 + 4 + ((w6 & 1) ^ 1);
  bool neg2 = ((w6 & 1) == 0);
  const unsigned short* PH1 = wh + (size_t)p1 * 262144;
  const unsigned short* PL1 = wl + (size_t)p1 * 262144;
  const unsigned short* PH2 = wh + (size_t)p2 * 262144;
  const unsigned short* PL2 = wl + (size_t)p2 * 262144;

  int row0 = bx * 128;     // W cols (Vt rows)
  int col0 = by * 128;     // X rows (Vt cols)
  int lane = t & 63, w = t >> 6;
  int wr = w >> 1, wc = w & 1;
  int q = lane >> 4, r = lane & 15;
  int srow = t >> 2;
  int skoff = (t & 3) * 8;
  size_t wrow1 = (size_t)(row0 + srow) * 512 + skoff;
  size_t wrow2 = (size_t)(row0 + 64 + srow) * 512 + skoff;
  size_t xrow1 = (size_t)(col0 + srow) * 1024 + skoff;
  size_t xrow2 = (size_t)(col0 + 64 + srow) * 1024 + skoff;
  const s8v sgn = {(short)0x8000, (short)0x8000, (short)0x8000, (short)0x8000,
                   (short)0x8000, (short)0x8000, (short)0x8000, (short)0x8000};

  floatx4 acc[4][4];
#pragma unroll
  for (int i = 0; i < 4; ++i)
#pragma unroll
    for (int j = 0; j < 4; ++j) acc[i][j] = (floatx4){0.f, 0.f, 0.f, 0.f};

  for (int k0 = 0; k0 < 1024; k0 += 32) {
    const unsigned short *WgH, *WgL;
    int kk = k0;
    bool xon = false;
    if (k0 < 512) { WgH = PH1; WgL = PL1; }
    else          { WgH = PH2; WgL = PL2; kk = k0 - 512; xon = neg2; }
    gll16(WgH + wrow1 + kk, (char*)Ah + t * 16);
    gll16(WgH + wrow2 + kk, (char*)Ah + 4096 + t * 16);
    gll16(WgL + wrow1 + kk, (char*)Al + t * 16);
    gll16(WgL + wrow2 + kk, (char*)Al + 4096 + t * 16);
    gll16(xh + xrow1 + k0, (char*)Bh + t * 16);
    gll16(xh + xrow2 + k0, (char*)Bh + 4096 + t * 16);
    gll16(xl + xrow1 + k0, (char*)Bl + t * 16);
    gll16(xl + xrow2 + k0, (char*)Bl + 4096 + t * 16);
    __syncthreads();
    s8v ah[4], al[4], bh[4], bl[4];
#pragma unroll
    for (int i = 0; i < 4; ++i) {
      int ro = (wr * 64 + i * 16 + r) * 32 + q * 8;
      ah[i] = *(const s8v*)((const short*)Ah + ro);
      al[i] = *(const s8v*)((const short*)Al + ro);
    }
#pragma unroll
    for (int j = 0; j < 4; ++j) {
      int ro = (wc * 64 + j * 16 + r) * 32 + q * 8;
      bh[j] = *(const s8v*)((const short*)Bh + ro);
      bl[j] = *(const s8v*)((const short*)Bl + ro);
    }
    if (xon) {                                 // sign-flip weight-side fragments (A side)
#pragma unroll
      for (int i = 0; i < 4; ++i) { ah[i] = ah[i] ^ sgn; al[i] = al[i] ^ sgn; }
    }
#pragma unroll
    for (int i = 0; i < 4; ++i)
#pragma unroll
      for (int j = 0; j < 4; ++j) {
        acc[i][j] = __builtin_amdgcn_mfma_f32_16x16x32_bf16(ah[i], bh[j], acc[i][j], 0, 0, 0);
        acc[i][j] = __builtin_amdgcn_mfma_f32_16x16x32_bf16(ah[i], bl[j], acc[i][j], 0, 0, 0);
        acc[i][j] = __builtin_amdgcn_mfma_f32_16x16x32_bf16(al[i], bh[j], acc[i][j], 0, 0, 0);
      }
    __syncthreads();
  }
  unsigned short* dh = (unsigned short*)(ws + OFF_VTH);
  unsigned short* dl = (unsigned short*)(ws + OFF_VTL);
  size_t base = (size_t)((w6 & 1) * 4 + m) * 512 * 1024;
#pragma unroll
  for (int i = 0; i < 4; ++i)
#pragma unroll
    for (int j = 0; j < 4; ++j) {
      int rowb = row0 + wr * 64 + i * 16 + q * 4;
      int colb = col0 + wc * 64 + j * 16 + r;
#pragma unroll
      for (int reg = 0; reg < 4; ++reg) {
        float v = acc[i][j][reg];
        unsigned short h = f2bf(v);
        size_t idx = base + (size_t)(rowb + reg) * 1024 + colb;
        dh[idx] = h;
        dl[idx] = f2bf(v - bf2f(h));
      }
    }
}

// ---------------- PV: O = P @ Vt^T (R20 row-split: 256 blocks, 64 rows x 128 cols) ----------------
__global__ __launch_bounds__(256) void k_pv(float* __restrict__ ws) {
  __shared__ __align__(16) unsigned short Ph_[64 * 32], Pl_[64 * 32];
  __shared__ __align__(16) unsigned short VrH[128 * 32], VrL[128 * 32];
  __shared__ __align__(16) unsigned short ViH[128 * 32], ViL[128 * 32];
  const unsigned short* ph = (const unsigned short*)(ws + OFF_PH);
  const unsigned short* pl = (const unsigned short*)(ws + OFF_PL);
  const unsigned short* vth = (const unsigned short*)(ws + OFF_VTH);
  const unsigned short* vtl = (const unsigned short*)(ws + OFF_VTL);
  int yb = blockIdx.y, mb = yb >> 1, half = yb & 1;
  int m = mb >> 3, b = mb & 7;
  int col0 = blockIdx.x * 128;
  int t = threadIdx.x, lane = t & 63, w = t >> 6;
  int wr = w >> 1, wc = w & 1;              // wr: 32-row group, wc: 64-col group
  int q = lane >> 4, r = lane & 15;
  int srow = t >> 2;
  int skoff = (t & 3) * 8;
  size_t prow = (size_t)(mb * 128 + half * 64 + srow) * 128 + skoff;
  size_t vbr1 = ((size_t)(m * 512) + col0 + srow) * 1024 + b * 128 + skoff;
  size_t vbr2 = ((size_t)(m * 512) + col0 + 64 + srow) * 1024 + b * 128 + skoff;
  size_t vplane_i = (size_t)4 * 512 * 1024;

  floatx4 accR[2][4], accI[2][4];
#pragma unroll
  for (int i = 0; i < 2; ++i)
#pragma unroll
    for (int j = 0; j < 4; ++j) {
      accR[i][j] = (floatx4){0.f, 0.f, 0.f, 0.f};
      accI[i][j] = (floatx4){0.f, 0.f, 0.f, 0.f};
    }

  for (int k0 = 0; k0 < 128; k0 += 32) {
    gll16(ph + prow + k0, (char*)Ph_ + t * 16);
    gll16(pl + prow + k0, (char*)Pl_ + t * 16);
    gll16(vth + vbr1 + k0, (char*)VrH + t * 16);
    gll16(vth + vbr2 + k0, (char*)VrH + 4096 + t * 16);
    gll16(vtl + vbr1 + k0, (char*)VrL + t * 16);
    gll16(vtl + vbr2 + k0, (char*)VrL + 4096 + t * 16);
    gll16(vth + vplane_i + vbr1 + k0, (char*)ViH + t * 16);
    gll16(vth + vplane_i + vbr2 + k0, (char*)ViH + 4096 + t * 16);
    gll16(vtl + vplane_i + vbr1 + k0, (char*)ViL + t * 16);
    gll16(vtl + vplane_i + vbr2 + k0, (char*)ViL + 4096 + t * 16);
    __syncthreads();
    s8v ah[2], al[2];
#pragma unroll
    for (int i = 0; i < 2; ++i) {
      int ro = (wr * 32 + i * 16 + r) * 32 + q * 8;
      ah[i] = *(const s8v*)((const short*)Ph_ + ro);
      al[i] = *(const s8v*)((const short*)Pl_ + ro);
    }
#pragma unroll
    for (int j = 0; j < 4; ++j) {
      int ro = (wc * 64 + j * 16 + r) * 32 + q * 8;
      s8v vrh = *(const s8v*)((const short*)VrH + ro);
      s8v vrl = *(const s8v*)((const short*)VrL + ro);
      s8v vih = *(const s8v*)((const short*)ViH + ro);
      s8v vil = *(const s8v*)((const short*)ViL + ro);
#pragma unroll
      for (int i = 0; i < 2; ++i) {
        accR[i][j] = __builtin_amdgcn_mfma_f32_16x16x32_bf16(ah[i], vrh, accR[i][j], 0, 0, 0);
        accR[i][j] = __builtin_amdgcn_mfma_f32_16x16x32_bf16(ah[i], vrl, accR[i][j], 0, 0, 0);
        accR[i][j] = __builtin_amdgcn_mfma_f32_16x16x32_bf16(al[i], vrh, accR[i][j], 0, 0, 0);
        accI[i][j] = __builtin_amdgcn_mfma_f32_16x16x32_bf16(ah[i], vih, accI[i][j], 0, 0, 0);
        accI[i][j] = __builtin_amdgcn_mfma_f32_16x16x32_bf16(ah[i], vil, accI[i][j], 0, 0, 0);
        accI[i][j] = __builtin_amdgcn_mfma_f32_16x16x32_bf16(al[i], vih, accI[i][j], 0, 0, 0);
      }
    }
    __syncthreads();
  }
  float* orp = ws + OFF_OR + (size_t)mb * 128 * 512;
  float* oip = ws + OFF_OI + (size_t)mb * 128 * 512;
#pragma unroll
  for (int i = 0; i < 2; ++i)
#pragma unroll
    for (int j = 0; j < 4; ++j) {
      int rowb = half * 64 + wr * 32 + i * 16 + q * 4;
      int colb = col0 + wc * 64 + j * 16 + r;
#pragma unroll
      for (int reg = 0; reg < 4; ++reg) {
        orp[(size_t)(rowb + reg) * 512 + colb] = accR[i][j][reg];
        oip[(size_t)(rowb + reg) * 512 + colb] = accI[i][j][reg];
      }
    }
}

// ---------------- ModReLU + ComplexLayerNorm + feat partials (fused) + GRU finish ----------------
__global__ __launch_bounds__(256) void k_modlnfeat(float* __restrict__ ws,
                                                   const float* __restrict__ mod_bias,
                                                   const float* __restrict__ ln_scale,
                                                   const float* __restrict__ ln_shift,
                                                   const float* __restrict__ hold,
                                                   float* __restrict__ hnew,
                                                   const float* __restrict__ bih,
                                                   const float* __restrict__ bhh) {
  int blk = blockIdx.x;
  int t = threadIdx.x;
  if (blk >= 128) {
    int b = blk - 128;
    for (int c = t; c < 512; c += 256) {
      const float* part = ws + OFF_PART + ((size_t)b * 512 + c) * 4;
      float r_ = part[0] + bih[c] + bhh[c];
      float z_ = part[1] + bih[512 + c] + bhh[512 + c];
      float xn = part[2] + bih[1024 + c];
      float hn = part[3] + bhh[1024 + c];
      float r = 1.f / (1.f + expf(-r_));
      float z = 1.f / (1.f + expf(-z_));
      float n = tanhf(xn + r * hn);
      hnew[b * 512 + c] = (1.f - z) * n + z * hold[b * 512 + c];
    }
    return;
  }
  int mb = blk >> 2, grp = blk & 3;
  int m = mb >> 3;
  int w = t >> 6, l = t & 63;
  int e0 = l * 8;
  float mb_[8], lsc[8], lsh[8];
  *(float4*)&mb_[0] = *(const float4*)(mod_bias + m * 512 + e0);
  *(float4*)&mb_[4] = *(const float4*)(mod_bias + m * 512 + e0 + 4);
  *(float4*)&lsc[0] = *(const float4*)(ln_scale + m * 512 + e0);
  *(float4*)&lsc[4] = *(const float4*)(ln_scale + m * 512 + e0 + 4);
  *(float4*)&lsh[0] = *(const float4*)(ln_shift + m * 512 + e0);
  *(float4*)&lsh[4] = *(const float4*)(ln_shift + m * 512 + e0 + 4);
  float featR[8] = {}, featI[8] = {};
  for (int it = 0; it < 8; ++it) {
    int s = grp * 32 + it * 4 + w;
    float* orp = ws + OFF_OR + ((size_t)mb * 128 + s) * 512 + e0;
    float* oip = ws + OFF_OI + ((size_t)mb * 128 + s) * 512 + e0;
    float orv[8], oiv[8], magv[8];
    *(float4*)&orv[0] = *(const float4*)orp;
    *(float4*)&orv[4] = *(const float4*)(orp + 4);
    *(float4*)&oiv[0] = *(const float4*)oip;
    *(float4*)&oiv[4] = *(const float4*)(oip + 4);
    float sum = 0.f, sumsq = 0.f;
#pragma unroll
    for (int j = 0; j < 8; ++j) {
      float o_r = orv[j], o_i = oiv[j];
      float mag = sqrtf(o_r * o_r + o_i * o_i) + EPS;
      float g = fmaxf(mag + mb_[j], 0.f) / mag;
      o_r *= g; o_i *= g;
      orv[j] = o_r; oiv[j] = o_i;
      float mag2 = sqrtf(o_r * o_r + o_i * o_i) + EPS;
      magv[j] = mag2;
      sum += mag2;
      sumsq += mag2 * mag2;
    }
    for (int o = 1; o < 64; o <<= 1) {
      sum += __shfl_xor(sum, o);
      sumsq += __shfl_xor(sumsq, o);
    }
    float mu = sum * (1.f / D);
    float var = (sumsq - (float)D * mu * mu) * (1.f / (D - 1));
    float inv = 1.f / sqrtf(var + EPS);
#pragma unroll
    for (int j = 0; j < 8; ++j) {
      float nm = (magv[j] - mu) * inv * lsc[j] + lsh[j];
      float hyp = magv[j] - EPS;
      float cp, sp;
      if (hyp > 0.f) { cp = orv[j] / hyp; sp = oiv[j] / hyp; }
      else           { cp = 1.f;          sp = 0.f; }
      orv[j] = nm * cp;
      oiv[j] = nm * sp;
      featR[j] += orv[j];
      featI[j] += oiv[j];
    }
    *(float4*)orp = *(float4*)&orv[0];
    *(float4*)(orp + 4) = *(float4*)&orv[4];
    *(float4*)oip = *(float4*)&oiv[0];
    *(float4*)(oip + 4) = *(float4*)&oiv[4];
  }
  float* fb = ws + OFF_FEAT + (size_t)mb * 1024;
#pragma unroll
  for (int j = 0; j < 8; ++j) {
    atomicAdd(fb + e0 + j, featR[j] * (1.0f / S));
    atomicAdd(fb + 512 + e0 + j, featI[j] * (1.0f / S));
  }
}

// ---------------- wsel (R20): w + halt p/wt/cum + gwp (direct) + FEAT zero ----------------
// gwp[b,:] = sum_m w[m,b]*feat[m,b,:]  (mean-over-s commutes with module sum);
// p[b] = sigmoid(sum_m w[m,b]*(feat[m,b,:].w_halt) + b_halt). Replaces k_acchalt's
// halt math; bcast consumes wt for the fused AR/AI accumulate.
__global__ __launch_bounds__(256) void k_wsel(float* __restrict__ ws,
                                              const float* __restrict__ hnew,
                                              const float* __restrict__ bias_W,
                                              const float* __restrict__ bias_b,
                                              const float* __restrict__ w_sal,
                                              const float* __restrict__ w_halt,
                                              const float* __restrict__ b_halt,
                                              const float* __restrict__ cumr,
                                              float* __restrict__ cumw) {
  __shared__ float mb_s[B][M];
  __shared__ float sal_s[M][B];
  __shared__ float hsal_s[M][B];
  __shared__ float wsm[M][B];
  int t = threadIdx.x;
  int p = t >> 3, l = t & 7;
  {
    int b = p >> 2, m = p & 3;
    float s = 0.f;
    for (int d2 = l; d2 < D; d2 += 8) s += hnew[b * D + d2] * bias_W[d2 * M + m];
    for (int o = 1; o < 8; o <<= 1) s += __shfl_xor(s, o);
    if (l == 0) mb_s[b][m] = s + bias_b[m];
  }
  {
    int m = p >> 3, b = p & 7;
    float s = 0.f, s2 = 0.f;
    for (int f = l; f < 2 * D; f += 8) {
      float fv = ws[OFF_FEAT + (m * B + b) * 2 * D + f];
      s += fv * w_sal[m * 2 * D + f];
      s2 += fv * w_halt[f];
    }
    for (int o = 1; o < 8; o <<= 1) { s += __shfl_xor(s, o); s2 += __shfl_xor(s2, o); }
    if (l == 0) { sal_s[m][b] = s; hsal_s[m][b] = s2; }
  }
  __syncthreads();
  if (t < B) {
    int b = t;
    float lg[M], mx = -1e30f;
#pragma unroll
    for (int m = 0; m < M; ++m) { lg[m] = sal_s[m][b] + mb_s[b][m]; mx = fmaxf(mx, lg[m]); }
    float sm = 0.f;
#pragma unroll
    for (int m = 0; m < M; ++m) { lg[m] = expf(lg[m] - mx); sm += lg[m]; }
    float inv = 1.f / sm;
    float hs = 0.f;
#pragma unroll
    for (int m = 0; m < M; ++m) {
      float wv = lg[m] * inv;
      wsm[m][b] = wv;
      ws[OFF_W + m * B + b] = wv;
      hs += wv * hsal_s[m][b];
    }
    float pp = 1.f / (1.f + expf(-(hs + b_halt[0])));
    float cum = cumr[b];
    float still = (cum < THRESH) ? 1.f : 0.f;
    bool nh = ((cum + pp) >= THRESH) && (cum < THRESH);
    float wt = (nh ? (1.f - cum) : pp) * still;
    cumw[b] = cum + wt;
    ws[OFF_WT + b] = wt;
  }
  __syncthreads();
  // gwp for next step's GRU + FEAT zero (read-then-clear per element)
  for (int idx = t; idx < 8192; idx += 256) {
    int b = idx >> 10, f = idx & 1023;
    float g = 0.f;
#pragma unroll
    for (int m = 0; m < M; ++m) {
      size_t fi = OFF_FEAT + (size_t)(m * B + b) * 1024 + f;
      g += wsm[m][b] * ws[fi];
      ws[fi] = 0.f;
    }
    ws[OFF_GWP + idx] = g;
  }
}

// ---------------- bcast (R20): bf16 Xcat + fused ACT accumulate (acchalt absorbed) ----------------
// ZR/ZI fp32 stores removed (dead — only reader was acchalt). GWP atomics removed
// (gwp computed directly in wsel). wt read from ws[OFF_WT].
__global__ __launch_bounds__(256) void k_bcast(float* __restrict__ ws) {
  unsigned short* xh = (unsigned short*)(ws + OFF_XH);
  unsigned short* xl = (unsigned short*)(ws + OFF_XL);
  int t = threadIdx.x;
  int i4 = blockIdx.x * 256 + t;
  int b = i4 >> 14;
  float w0 = ws[OFF_W + 0 * B + b], w1 = ws[OFF_W + 1 * B + b];
  float w2 = ws[OFF_W + 2 * B + b], w3 = ws[OFF_W + 3 * B + b];
  float wt = ws[OFF_WT + b];
  const float4* mr = (const float4*)(ws + OFF_OR);
  const float4* mi = (const float4*)(ws + OFF_OI);
  const int MS = BSD / 4;
  int row = i4 >> 7;
  int d4 = (i4 & 127) * 4;
  float4 r0 = mr[i4], r1 = mr[i4 + MS], r2 = mr[i4 + 2 * MS], r3 = mr[i4 + 3 * MS];
  float gvR[4];
  gvR[0] = w0 * r0.x + w1 * r1.x + w2 * r2.x + w3 * r3.x;
  gvR[1] = w0 * r0.y + w1 * r1.y + w2 * r2.y + w3 * r3.y;
  gvR[2] = w0 * r0.z + w1 * r1.z + w2 * r2.z + w3 * r3.z;
  gvR[3] = w0 * r0.w + w1 * r1.w + w2 * r2.w + w3 * r3.w;
  us4 hh, hl;
#pragma unroll
  for (int j = 0; j < 4; ++j) {
    unsigned short h = f2bf(gvR[j]); hh[j] = h; hl[j] = f2bf(gvR[j] - bf2f(h));
  }
  *(us4*)(xh + (size_t)row * 1024 + d4) = hh;
  *(us4*)(xl + (size_t)row * 1024 + d4) = hl;
  float4 s0 = mi[i4], s1 = mi[i4 + MS], s2 = mi[i4 + 2 * MS], s3 = mi[i4 + 3 * MS];
  float gvI[4];
  gvI[0] = w0 * s0.x + w1 * s1.x + w2 * s2.x + w3 * s3.x;
  gvI[1] = w0 * s0.y + w1 * s1.y + w2 * s2.y + w3 * s3.y;
  gvI[2] = w0 * s0.z + w1 * s1.z + w2 * s2.z + w3 * s3.z;
  gvI[3] = w0 * s0.w + w1 * s1.w + w2 * s2.w + w3 * s3.w;
#pragma unroll
  for (int j = 0; j < 4; ++j) {
    unsigned short h = f2bf(gvI[j]); hh[j] = h; hl[j] = f2bf(gvI[j] - bf2f(h));
  }
  *(us4*)(xh + (size_t)row * 1024 + 512 + d4) = hh;
  *(us4*)(xl + (size_t)row * 1024 + 512 + d4) = hl;
  float4 a = ((float4*)(ws + OFF_AR))[i4];
  a.x += wt * gvR[0]; a.y += wt * gvR[1]; a.z += wt * gvR[2]; a.w += wt * gvR[3];
  ((float4*)(ws + OFF_AR))[i4] = a;
  a = ((float4*)(ws + OFF_AI))[i4];
  a.x += wt * gvI[0]; a.y += wt * gvI[1]; a.z += wt * gvI[2]; a.w += wt * gvI[3];
  ((float4*)(ws + OFF_AI))[i4] = a;
}

// ---------------- output (R1) ----------------
__global__ __launch_bounds__(256) void k_out(const float* __restrict__ ws,
                                             float* __restrict__ out) {
  int i4 = blockIdx.x * 256 + threadIdx.x;
  ((float4*)out)[i4] = ((const float4*)(ws + OFF_AR))[i4];
  ((float4*)out)[i4 + BSD / 4] = ((const float4*)(ws + OFF_AI))[i4];
}

extern "C" void kernel_launch(void* const* d_in, const int* in_sizes, int n_in,
                              void* d_out, int out_size, void* d_ws, size_t ws_size,
                              hipStream_t stream) {
  (void)in_sizes; (void)n_in; (void)out_size; (void)ws_size;
  const float* x_real  = (const float*)d_in[0];
  const float* x_imag  = (const float*)d_in[1];
  const float* Wq_r    = (const float*)d_in[2];
  const float* Wq_i    = (const float*)d_in[3];
  const float* Wk_r    = (const float*)d_in[4];
  const float* Wk_i    = (const float*)d_in[5];
  const float* Wv_r    = (const float*)d_in[6];
  const float* Wv_i    = (const float*)d_in[7];
  const float* mod_bias = (const float*)d_in[8];
  const float* ln_scale = (const float*)d_in[9];
  const float* ln_shift = (const float*)d_in[10];
  const float* w_sal   = (const float*)d_in[11];
  const float* gru_Wih = (const float*)d_in[12];
  const float* gru_Whh = (const float*)d_in[13];
  const float* gru_bih = (const float*)d_in[14];
  const float* gru_bhh = (const float*)d_in[15];
  const float* bias_W  = (const float*)d_in[16];
  const float* bias_b  = (const float*)d_in[17];
  const float* w_halt  = (const float*)d_in[18];
  const float* b_halt  = (const float*)d_in[19];
  float* ws = (float*)d_ws;
  float* out = (float*)d_out;

  k_wprep<<<dim3(8, 8, 24), 256, 0, stream>>>(Wq_r, Wq_i, Wk_r, Wk_i, Wv_r, Wv_i, ws);
  k_init<<<512, 256, 0, stream>>>(x_real, x_imag, ws);
  k_gwp<<<32, 256, 0, stream>>>(ws + OFF_ZR, ws + OFF_ZI, ws + OFF_GWP);
  for (int step = 0; step < DEPTH; ++step) {
    const float* hold = ws + ((step & 1) ? OFF_H1 : OFF_H0);
    float* hnew = ws + ((step & 1) ? OFF_H0 : OFF_H1);
    const float* cumr = ws + ((step & 1) ? OFF_CUM2 : OFF_CUM);
    float* cumw = ws + ((step & 1) ? OFF_CUM : OFF_CUM2);
    k_qk<<<dim3(4, 8, 16), 256, 0, stream>>>(ws);
    k_vattn<<<576, 256, 0, stream>>>(ws, ws + OFF_GWP, hold, gru_Wih, gru_Whh);
    k_pv<<<dim3(4, 64), 256, 0, stream>>>(ws);
    k_modlnfeat<<<136, 256, 0, stream>>>(ws, mod_bias, ln_scale, ln_shift,
                                         hold, hnew, gru_bih, gru_bhh);
    k_wsel<<<1, 256, 0, stream>>>(ws, hnew, bias_W, bias_b, w_sal,
                                  w_halt, b_halt, cumr, cumw);
    k_bcast<<<512, 256, 0, stream>>>(ws);
  }
  k_out<<<512, 256, 0, stream>>>(ws, out);
}

// Round 10
// 2862.839 us; speedup vs baseline: 1.4810x; 1.1513x over previous
//
#include <hip/hip_runtime.h>
#include <math.h>

#define B 8
#define S 128
#define D 512
#define M 4
#define BS 1024
#define BSD 524288          // B*S*D
#define DEPTH 16
#define THRESH 0.9999f
#define EPS 1e-6f
#define SCALE 0.04419417382415922f   // D^-0.5

typedef float floatx4 __attribute__((ext_vector_type(4)));
typedef short s8v __attribute__((ext_vector_type(8)));
typedef unsigned short us4 __attribute__((ext_vector_type(4)));

__device__ __forceinline__ unsigned short f2bf(float f) {
  unsigned int u = __float_as_uint(f);
  u += 0x7FFFu + ((u >> 16) & 1u);          // round-to-nearest-even
  return (unsigned short)(u >> 16);
}
__device__ __forceinline__ float bf2f(unsigned short h) {
  return __uint_as_float((unsigned int)h << 16);
}

// async global->LDS, 16B per lane, linear LDS dest (wave-uniform base + lane*16)
__device__ __forceinline__ void gll16(const void* g, void* l) {
  __builtin_amdgcn_global_load_lds(
      (const __attribute__((address_space(1))) unsigned int*)g,
      (__attribute__((address_space(3))) unsigned int*)l, 16, 0, 0);
}

// ---------------- workspace layout (float-slot offsets) ----------------
#define OFF_ZR   0
#define OFF_ZI   (1*BSD)
#define OFF_AR   (2*BSD)
#define OFF_AI   (3*BSD)
#define OFF_OR   (4*BSD)            // [M][B][S][D] fp32 = 4*BSD
#define OFF_OI   (8*BSD)
#define OFF_FEAT (12*BSD)           // 65536
#define OFF_GWP  (12*BSD + 65536)   // 8192
#define OFF_H0   (12*BSD + 73728)
#define OFF_H1   (12*BSD + 77824)
#define OFF_CUM  (12*BSD + 81920)   // 8
#define OFF_W    (12*BSD + 81928)   // 32
#define OFF_WT   (12*BSD + 81960)   // 8
#define OFF_CUM2 (12*BSD + 81968)   // 8
// GRU partial-sum scratch PART[B][512][4] = 16384 floats, OVERLAYS OFF_ZR
// (in-loop ZR/ZI fp32 fully dead since R20).
#define OFF_PART OFF_ZR
// bf16 annex (slots)
#define OFF_XH   (12*BSD + 90112)           // xcat hi [1024][1024] = 1 BSD
#define OFF_XL   (OFF_XH + 1*BSD)
#define OFF_WH   (OFF_XH + 2*BSD)           // 24 planes [512][512] hi = 6 BSD
#define OFF_WL   (OFF_XH + 8*BSD)
#define OFF_QCH  (OFF_XH + 14*BSD)          // Qcat hi [M][1024][1024] = 4 BSD
#define OFF_QCL  (OFF_XH + 18*BSD)
#define OFF_KCH  (OFF_XH + 22*BSD)
#define OFF_KCL  (OFF_XH + 26*BSD)
#define OFF_VTH  (OFF_XH + 30*BSD)          // Vt hi [2ri][M][512][1024] = 4 BSD
#define OFF_VTL  (OFF_XH + 34*BSD)
#define OFF_PH   (OFF_XH + 38*BSD)          // P hi [32][128][128] = 262144 slots
#define OFF_PL   (OFF_PH + 262144)
// end ~= 107.3 MB (R6/R8 proven)

// ---------------- init: fp32 carry + bf16 hi/lo Xcat + zero FEAT/GWP/CUMs ----------------
__global__ __launch_bounds__(256) void k_init(const float* __restrict__ xr,
                                              const float* __restrict__ xi,
                                              float* __restrict__ ws) {
  unsigned short* xh = (unsigned short*)(ws + OFF_XH);
  unsigned short* xl = (unsigned short*)(ws + OFF_XL);
  int i4 = blockIdx.x * 256 + threadIdx.x;      // BSD/4
  float4 a = ((const float4*)xr)[i4];
  float4 b = ((const float4*)xi)[i4];
  ((float4*)(ws + OFF_ZR))[i4] = a;
  ((float4*)(ws + OFF_ZI))[i4] = b;
  float4 z = {0.f, 0.f, 0.f, 0.f};
  ((float4*)(ws + OFF_AR))[i4] = z;
  ((float4*)(ws + OFF_AI))[i4] = z;
  int row = i4 >> 7;
  int d4 = (i4 & 127) * 4;
  float av[4] = {a.x, a.y, a.z, a.w}, bv[4] = {b.x, b.y, b.z, b.w};
  us4 hh, hl;
#pragma unroll
  for (int j = 0; j < 4; ++j) {
    unsigned short h = f2bf(av[j]); hh[j] = h; hl[j] = f2bf(av[j] - bf2f(h));
  }
  *(us4*)(xh + (size_t)row * 1024 + d4) = hh;
  *(us4*)(xl + (size_t)row * 1024 + d4) = hl;
#pragma unroll
  for (int j = 0; j < 4; ++j) {
    unsigned short h = f2bf(bv[j]); hh[j] = h; hl[j] = f2bf(bv[j] - bf2f(h));
  }
  *(us4*)(xh + (size_t)row * 1024 + 512 + d4) = hh;
  *(us4*)(xl + (size_t)row * 1024 + 512 + d4) = hl;
  if (i4 < (B * D) / 4) {
    ((float4*)(ws + OFF_H0))[i4] = z;
    ((float4*)(ws + OFF_H1))[i4] = z;
  }
  if (i4 < 16384) ((float4*)(ws + OFF_FEAT))[i4] = z;
  if (i4 < 2048)  ((float4*)(ws + OFF_GWP))[i4] = z;
  if (i4 < B) { ws[OFF_CUM + i4] = 0.f; ws[OFF_CUM2 + i4] = 0.f; }
}

// ---------------- weight prep (R6, proven) ----------------
__global__ __launch_bounds__(256) void k_wprep(const float* __restrict__ Wqr,
                                               const float* __restrict__ Wqi,
                                               const float* __restrict__ Wkr,
                                               const float* __restrict__ Wki,
                                               const float* __restrict__ Wvr,
                                               const float* __restrict__ Wvi,
                                               float* __restrict__ ws) {
  __shared__ float lt[64][65];
  unsigned short* wh = (unsigned short*)(ws + OFF_WH);
  unsigned short* wl = (unsigned short*)(ws + OFF_WL);
  int z = blockIdx.z, m = z / 6, idx = z % 6;
  const float* Wsrc;
  switch (idx) {
    case 0:  Wsrc = Wqr; break;
    case 1:  Wsrc = Wqi; break;
    case 2:  Wsrc = Wkr; break;
    case 3:  Wsrc = Wki; break;
    case 4:  Wsrc = Wvr; break;
    default: Wsrc = Wvi; break;
  }
  Wsrc += (size_t)m * D * D;
  int k0 = blockIdx.x * 64, n0 = blockIdx.y * 64;
  int tx = threadIdx.x & 63, ty = threadIdx.x >> 6;
#pragma unroll
  for (int i = 0; i < 16; ++i) {
    int kl = ty + i * 4;
    lt[kl][tx] = Wsrc[(size_t)(k0 + kl) * D + n0 + tx];
  }
  __syncthreads();
  unsigned short* whp = wh + (size_t)z * 262144;
  unsigned short* wlp = wl + (size_t)z * 262144;
#pragma unroll
  for (int i = 0; i < 16; ++i) {
    int nl = ty + i * 4;
    float v = lt[tx][nl];
    unsigned short h = f2bf(v);
    whp[(size_t)(n0 + nl) * 512 + k0 + tx] = h;
    wlp[(size_t)(n0 + nl) * 512 + k0 + tx] = f2bf(v - bf2f(h));
  }
}

// ---------------- gwp (pre-loop only) ----------------
__global__ __launch_bounds__(256) void k_gwp(const float* __restrict__ zr,
                                             const float* __restrict__ zi,
                                             float* __restrict__ gwp) {
  int idx = blockIdx.x * 256 + threadIdx.x;
  int b = idx >> 10;
  int f = idx & 1023;
  const float* src = (f < D) ? (zr + b * S * D + f) : (zi + b * S * D + (f - D));
  float s = 0.f;
#pragma unroll 8
  for (int ss = 0; ss < S; ++ss) s += src[ss * D];
  gwp[idx] = s * (1.0f / S);
}

// ---------------- k_qk: Q/K GEMMs only (R16-proven; 512 blocks = 2 CU-rounds) ----------------
// Block (0,0,0) additionally zeroes PART before its GEMM.
__global__ __launch_bounds__(256) void k_qk(float* __restrict__ ws) {
  __shared__ __align__(16) unsigned short Ah[128 * 32], Al[128 * 32];
  __shared__ __align__(16) unsigned short Bh[128 * 32], Bl[128 * 32];
  int t = threadIdx.x;
  if (blockIdx.x == 0 && blockIdx.y == 0 && blockIdx.z == 0) {
    float4 z4 = {0.f, 0.f, 0.f, 0.f};
    for (int i = t; i < 4096; i += 256) ((float4*)(ws + OFF_PART))[i] = z4;
  }
  const unsigned short* xh = (const unsigned short*)(ws + OFF_XH);
  const unsigned short* xl = (const unsigned short*)(ws + OFF_XL);
  const unsigned short* wh = (const unsigned short*)(ws + OFF_WH);
  const unsigned short* wl = (const unsigned short*)(ws + OFF_WL);
  int z = blockIdx.z, m = z >> 2, w6 = z & 3;
  int pair = (w6 >> 1) * 2;
  int p1 = m * 6 + pair + (w6 & 1);
  int p2 = m * 6 + pair + ((w6 & 1) ^ 1);
  bool neg2 = ((w6 & 1) == 0);               // real-output GEMMs negate second K-half
  const unsigned short* PH1 = wh + (size_t)p1 * 262144;
  const unsigned short* PL1 = wl + (size_t)p1 * 262144;
  const unsigned short* PH2 = wh + (size_t)p2 * 262144;
  const unsigned short* PL2 = wl + (size_t)p2 * 262144;

  int row0 = blockIdx.y * 128;    // X rows
  int col0 = blockIdx.x * 128;    // W cols
  int lane = t & 63, w = t >> 6;
  int wr = w >> 1, wc = w & 1;
  int q = lane >> 4, r = lane & 15;
  int srow = t >> 2;
  int skoff = (t & 3) * 8;
  size_t wrow1 = (size_t)(col0 + srow) * 512 + skoff;
  size_t wrow2 = (size_t)(col0 + 64 + srow) * 512 + skoff;
  size_t xrow1 = (size_t)(row0 + srow) * 1024 + skoff;
  size_t xrow2 = (size_t)(row0 + 64 + srow) * 1024 + skoff;
  const s8v sgn = {(short)0x8000, (short)0x8000, (short)0x8000, (short)0x8000,
                   (short)0x8000, (short)0x8000, (short)0x8000, (short)0x8000};

  floatx4 acc[4][4];
#pragma unroll
  for (int i = 0; i < 4; ++i)
#pragma unroll
    for (int j = 0; j < 4; ++j) acc[i][j] = (floatx4){0.f, 0.f, 0.f, 0.f};

  for (int k0 = 0; k0 < 1024; k0 += 32) {
    const unsigned short *WgH, *WgL;
    int kk = k0;
    bool xon = false;
    if (k0 < 512) { WgH = PH1; WgL = PL1; }
    else          { WgH = PH2; WgL = PL2; kk = k0 - 512; xon = neg2; }
    gll16(xh + xrow1 + k0, (char*)Ah + t * 16);
    gll16(xh + xrow2 + k0, (char*)Ah + 4096 + t * 16);
    gll16(xl + xrow1 + k0, (char*)Al + t * 16);
    gll16(xl + xrow2 + k0, (char*)Al + 4096 + t * 16);
    gll16(WgH + wrow1 + kk, (char*)Bh + t * 16);
    gll16(WgH + wrow2 + kk, (char*)Bh + 4096 + t * 16);
    gll16(WgL + wrow1 + kk, (char*)Bl + t * 16);
    gll16(WgL + wrow2 + kk, (char*)Bl + 4096 + t * 16);
    __syncthreads();
    s8v ah[4], al[4], bh[4], bl[4];
#pragma unroll
    for (int i = 0; i < 4; ++i) {
      int ro = (wr * 64 + i * 16 + r) * 32 + q * 8;
      ah[i] = *(const s8v*)((const short*)Ah + ro);
      al[i] = *(const s8v*)((const short*)Al + ro);
    }
#pragma unroll
    for (int j = 0; j < 4; ++j) {
      int ro = (wc * 64 + j * 16 + r) * 32 + q * 8;
      bh[j] = *(const s8v*)((const short*)Bh + ro);
      bl[j] = *(const s8v*)((const short*)Bl + ro);
    }
    if (xon) {
#pragma unroll
      for (int j = 0; j < 4; ++j) { bh[j] = bh[j] ^ sgn; bl[j] = bl[j] ^ sgn; }
    }
#pragma unroll
    for (int i = 0; i < 4; ++i)
#pragma unroll
      for (int j = 0; j < 4; ++j) {
        acc[i][j] = __builtin_amdgcn_mfma_f32_16x16x32_bf16(ah[i], bh[j], acc[i][j], 0, 0, 0);
        acc[i][j] = __builtin_amdgcn_mfma_f32_16x16x32_bf16(ah[i], bl[j], acc[i][j], 0, 0, 0);
        acc[i][j] = __builtin_amdgcn_mfma_f32_16x16x32_bf16(al[i], bh[j], acc[i][j], 0, 0, 0);
      }
    __syncthreads();
  }
  unsigned short *dh, *dl;
  if (w6 < 2) { dh = (unsigned short*)(ws + OFF_QCH); dl = (unsigned short*)(ws + OFF_QCL); }
  else        { dh = (unsigned short*)(ws + OFF_KCH); dl = (unsigned short*)(ws + OFF_KCL); }
  int half = (w6 & 1) * 512;
  size_t base = (size_t)m * 1024 * 1024;
#pragma unroll
  for (int i = 0; i < 4; ++i)
#pragma unroll
    for (int j = 0; j < 4; ++j) {
      int rowb = row0 + wr * 64 + i * 16 + q * 4;
      int colb = col0 + wc * 64 + j * 16 + r;
#pragma unroll
      for (int reg = 0; reg < 4; ++reg) {
        float v = acc[i][j][reg];
        unsigned short h = f2bf(v);
        size_t idx = base + (size_t)(rowb + reg) * 1024 + half + colb;
        dh[idx] = h;
        dl[idx] = f2bf(v - bf2f(h));
      }
    }
}

// ---------------- k_vattn: V GEMM (blk<256) + attn (256..319) + GRU-partials (320..575) ----------------
// R19-proven structure.
__global__ __launch_bounds__(256) void k_vattn(float* __restrict__ ws,
                                               const float* __restrict__ gwp,
                                               const float* __restrict__ hold,
                                               const float* __restrict__ Wih,
                                               const float* __restrict__ Whh) {
  __shared__ __align__(16) unsigned short Ah[128 * 32], Al[128 * 32];
  __shared__ __align__(16) unsigned short Bh[128 * 32], Bl[128 * 32];
  __shared__ float rmax[64][4];
  __shared__ float rsum[64][4];
  int t = threadIdx.x;
  int blk = blockIdx.x;

  if (blk >= 320) {
    // ---- GRU partial path ----
    float* xbuf = (float*)Ah;                 // 1024 floats
    float* hbuf = (float*)Al;                 // 512 floats
    float (*red)[64][4] = (float (*)[64][4])Bh;
    int idx = blk - 320;                      // 0..255
    int b = idx >> 5;                         // 8
    int cc = (idx >> 2) & 7;                  // 8
    int kq = idx & 3;                         // 4
    int c0 = cc * 64;
    int td = t & 63, ks = t >> 6;
    for (int f = t; f < 1024; f += 256) xbuf[f] = gwp[b * 1024 + f];
    for (int d2 = t; d2 < 512; d2 += 256) hbuf[d2] = hold[b * 512 + d2];
    __syncthreads();
    float aR = 0.f, aZ = 0.f, aXn = 0.f, aHn = 0.f;
    int kbeg = kq * 384 + ks * 96, kend = kbeg + 96;
#pragma unroll 8
    for (int kk = kbeg; kk < kend; ++kk) {
      bool ih = kk < 1024;
      float x = ih ? xbuf[kk] : hbuf[kk - 1024];
      const float* base = ih ? (Wih + (size_t)kk * 1536) : (Whh + (size_t)(kk - 1024) * 1536);
      float wr = base[c0 + td];
      float wz = base[512 + c0 + td];
      float wn = base[1024 + c0 + td];
      aR += x * wr;
      aZ += x * wz;
      if (ih) aXn += x * wn; else aHn += x * wn;
    }
    red[ks][td][0] = aR;
    red[ks][td][1] = aZ;
    red[ks][td][2] = aXn;
    red[ks][td][3] = aHn;
    __syncthreads();
    if (t < 64) {
      float r_ = 0.f, z_ = 0.f, xn = 0.f, hn = 0.f;
#pragma unroll
      for (int s = 0; s < 4; ++s) {
        r_ += red[s][t][0]; z_ += red[s][t][1]; xn += red[s][t][2]; hn += red[s][t][3];
      }
      float* part = ws + OFF_PART + ((size_t)b * 512 + c0 + t) * 4;
      atomicAdd(part + 0, r_);
      atomicAdd(part + 1, z_);
      atomicAdd(part + 2, xn);
      atomicAdd(part + 3, hn);
    }
    return;
  }

  if (blk >= 256) {
    // ---- attn path (R16-proven body; 64 Q-rows x 128 K-cols) ----
    const unsigned short* qch = (const unsigned short*)(ws + OFF_QCH);
    const unsigned short* qcl = (const unsigned short*)(ws + OFF_QCL);
    const unsigned short* kch = (const unsigned short*)(ws + OFF_KCH);
    const unsigned short* kcl = (const unsigned short*)(ws + OFF_KCL);
    unsigned short* ph = (unsigned short*)(ws + OFF_PH);
    unsigned short* pl = (unsigned short*)(ws + OFF_PL);
    int ablk = blk - 256, mb = ablk >> 1, half = ablk & 1;
    size_t gbase = (size_t)mb * 128 * 1024;
    int lane = t & 63, wc = t >> 6;
    int q = lane >> 4, r = lane & 15;
    int srow = t >> 2;
    int skoff = (t & 3) * 8;
    size_t arow = gbase + (size_t)(half * 64 + srow) * 1024 + skoff;
    size_t brow1 = gbase + (size_t)srow * 1024 + skoff;
    size_t brow2 = gbase + (size_t)(64 + srow) * 1024 + skoff;

    floatx4 acc[4][2];
#pragma unroll
    for (int i = 0; i < 4; ++i)
#pragma unroll
      for (int j = 0; j < 2; ++j) acc[i][j] = (floatx4){0.f, 0.f, 0.f, 0.f};

    for (int k0 = 0; k0 < 1024; k0 += 32) {
      gll16(qch + arow + k0, (char*)Ah + t * 16);
      gll16(qcl + arow + k0, (char*)Al + t * 16);
      gll16(kch + brow1 + k0, (char*)Bh + t * 16);
      gll16(kch + brow2 + k0, (char*)Bh + 4096 + t * 16);
      gll16(kcl + brow1 + k0, (char*)Bl + t * 16);
      gll16(kcl + brow2 + k0, (char*)Bl + 4096 + t * 16);
      __syncthreads();
      s8v ah[4], al[4], bh[2], bl[2];
#pragma unroll
      for (int i = 0; i < 4; ++i) {
        int ro = (i * 16 + r) * 32 + q * 8;
        ah[i] = *(const s8v*)((const short*)Ah + ro);
        al[i] = *(const s8v*)((const short*)Al + ro);
      }
#pragma unroll
      for (int j = 0; j < 2; ++j) {
        int ro = (wc * 32 + j * 16 + r) * 32 + q * 8;
        bh[j] = *(const s8v*)((const short*)Bh + ro);
        bl[j] = *(const s8v*)((const short*)Bl + ro);
      }
#pragma unroll
      for (int i = 0; i < 4; ++i)
#pragma unroll
        for (int j = 0; j < 2; ++j) {
          acc[i][j] = __builtin_amdgcn_mfma_f32_16x16x32_bf16(ah[i], bh[j], acc[i][j], 0, 0, 0);
          acc[i][j] = __builtin_amdgcn_mfma_f32_16x16x32_bf16(ah[i], bl[j], acc[i][j], 0, 0, 0);
          acc[i][j] = __builtin_amdgcn_mfma_f32_16x16x32_bf16(al[i], bh[j], acc[i][j], 0, 0, 0);
        }
      __syncthreads();
    }
#pragma unroll
    for (int i = 0; i < 4; ++i)
#pragma unroll
      for (int j = 0; j < 2; ++j)
#pragma unroll
        for (int reg = 0; reg < 4; ++reg) acc[i][j][reg] *= SCALE;
#pragma unroll
    for (int i = 0; i < 4; ++i)
#pragma unroll
      for (int reg = 0; reg < 4; ++reg) {
        float mx = fmaxf(acc[i][0][reg], acc[i][1][reg]);
        for (int o = 1; o < 16; o <<= 1) mx = fmaxf(mx, __shfl_xor(mx, o));
        if (r == 0) rmax[i * 16 + q * 4 + reg][wc] = mx;
      }
    __syncthreads();
#pragma unroll
    for (int i = 0; i < 4; ++i)
#pragma unroll
      for (int reg = 0; reg < 4; ++reg) {
        int row = i * 16 + q * 4 + reg;
        float gmx = fmaxf(fmaxf(rmax[row][0], rmax[row][1]),
                          fmaxf(rmax[row][2], rmax[row][3]));
        float sm = 0.f;
#pragma unroll
        for (int j = 0; j < 2; ++j) {
          float e = __expf(acc[i][j][reg] - gmx);
          acc[i][j][reg] = e;
          sm += e;
        }
        for (int o = 1; o < 16; o <<= 1) sm += __shfl_xor(sm, o);
        if (r == 0) rsum[row][wc] = sm;
      }
    __syncthreads();
#pragma unroll
    for (int i = 0; i < 4; ++i)
#pragma unroll
      for (int reg = 0; reg < 4; ++reg) {
        int row = i * 16 + q * 4 + reg;
        float inv = 1.f / (rsum[row][0] + rsum[row][1] + rsum[row][2] + rsum[row][3]);
        size_t rb = (size_t)(mb * 128 + half * 64 + row) * 128;
#pragma unroll
        for (int j = 0; j < 2; ++j) {
          float p = acc[i][j][reg] * inv;
          unsigned short h = f2bf(p);
          size_t idx = rb + wc * 32 + j * 16 + r;
          ph[idx] = h;
          pl[idx] = f2bf(p - bf2f(h));
        }
      }
    return;
  }

  // ---- V GEMM path (R13-proven body, w6 in {4,5}) ----
  const unsigned short* xh = (const unsigned short*)(ws + OFF_XH);
  const unsigned short* xl = (const unsigned short*)(ws + OFF_XL);
  const unsigned short* wh = (const unsigned short*)(ws + OFF_WH);
  const unsigned short* wl = (const unsigned short*)(ws + OFF_WL);
  int plane = blk >> 5, m = plane >> 1, w6 = 4 + (plane & 1);
  int bx = (blk & 31) >> 3, by = blk & 7;
  int p1 = m * 6 + 4 + (w6 & 1);
  int p2 = m * 6 + 4 + ((w6 & 1) ^ 1);
  bool neg2 = ((w6 & 1) == 0);
  const unsigned short* PH1 = wh + (size_t)p1 * 262144;
  const unsigned short* PL1 = wl + (size_t)p1 * 262144;
  const unsigned short* PH2 = wh + (size_t)p2 * 262144;
  const unsigned short* PL2 = wl + (size_t)p2 * 262144;

  int row0 = bx * 128;     // W cols (Vt rows)
  int col0 = by * 128;     // X rows (Vt cols)
  int lane = t & 63, w = t >> 6;
  int wr = w >> 1, wc = w & 1;
  int q = lane >> 4, r = lane & 15;
  int srow = t >> 2;
  int skoff = (t & 3) * 8;
  size_t wrow1 = (size_t)(row0 + srow) * 512 + skoff;
  size_t wrow2 = (size_t)(row0 + 64 + srow) * 512 + skoff;
  size_t xrow1 = (size_t)(col0 + srow) * 1024 + skoff;
  size_t xrow2 = (size_t)(col0 + 64 + srow) * 1024 + skoff;
  const s8v sgn = {(short)0x8000, (short)0x8000, (short)0x8000, (short)0x8000,
                   (short)0x8000, (short)0x8000, (short)0x8000, (short)0x8000};

  floatx4 acc[4][4];
#pragma unroll
  for (int i = 0; i < 4; ++i)
#pragma unroll
    for (int j = 0; j < 4; ++j) acc[i][j] = (floatx4){0.f, 0.f, 0.f, 0.f};

  for (int k0 = 0; k0 < 1024; k0 += 32) {
    const unsigned short *WgH, *WgL;
    int kk = k0;
    bool xon = false;
    if (k0 < 512) { WgH = PH1; WgL = PL1; }
    else          { WgH = PH2; WgL = PL2; kk = k0 - 512; xon = neg2; }
    gll16(WgH + wrow1 + kk, (char*)Ah + t * 16);
    gll16(WgH + wrow2 + kk, (char*)Ah + 4096 + t * 16);
    gll16(WgL + wrow1 + kk, (char*)Al + t * 16);
    gll16(WgL + wrow2 + kk, (char*)Al + 4096 + t * 16);
    gll16(xh + xrow1 + k0, (char*)Bh + t * 16);
    gll16(xh + xrow2 + k0, (char*)Bh + 4096 + t * 16);
    gll16(xl + xrow1 + k0, (char*)Bl + t * 16);
    gll16(xl + xrow2 + k0, (char*)Bl + 4096 + t * 16);
    __syncthreads();
    s8v ah[4], al[4], bh[4], bl[4];
#pragma unroll
    for (int i = 0; i < 4; ++i) {
      int ro = (wr * 64 + i * 16 + r) * 32 + q * 8;
      ah[i] = *(const s8v*)((const short*)Ah + ro);
      al[i] = *(const s8v*)((const short*)Al + ro);
    }
#pragma unroll
    for (int j = 0; j < 4; ++j) {
      int ro = (wc * 64 + j * 16 + r) * 32 + q * 8;
      bh[j] = *(const s8v*)((const short*)Bh + ro);
      bl[j] = *(const s8v*)((const short*)Bl + ro);
    }
    if (xon) {                                 // sign-flip weight-side fragments (A side)
#pragma unroll
      for (int i = 0; i < 4; ++i) { ah[i] = ah[i] ^ sgn; al[i] = al[i] ^ sgn; }
    }
#pragma unroll
    for (int i = 0; i < 4; ++i)
#pragma unroll
      for (int j = 0; j < 4; ++j) {
        acc[i][j] = __builtin_amdgcn_mfma_f32_16x16x32_bf16(ah[i], bh[j], acc[i][j], 0, 0, 0);
        acc[i][j] = __builtin_amdgcn_mfma_f32_16x16x32_bf16(ah[i], bl[j], acc[i][j], 0, 0, 0);
        acc[i][j] = __builtin_amdgcn_mfma_f32_16x16x32_bf16(al[i], bh[j], acc[i][j], 0, 0, 0);
      }
    __syncthreads();
  }
  unsigned short* dh = (unsigned short*)(ws + OFF_VTH);
  unsigned short* dl = (unsigned short*)(ws + OFF_VTL);
  size_t base = (size_t)((w6 & 1) * 4 + m) * 512 * 1024;
#pragma unroll
  for (int i = 0; i < 4; ++i)
#pragma unroll
    for (int j = 0; j < 4; ++j) {
      int rowb = row0 + wr * 64 + i * 16 + q * 4;
      int colb = col0 + wc * 64 + j * 16 + r;
#pragma unroll
      for (int reg = 0; reg < 4; ++reg) {
        float v = acc[i][j][reg];
        unsigned short h = f2bf(v);
        size_t idx = base + (size_t)(rowb + reg) * 1024 + colb;
        dh[idx] = h;
        dl[idx] = f2bf(v - bf2f(h));
      }
    }
}

// ---------------- PV: O = P @ Vt^T (R20 row-split: 256 blocks, 64 rows x 128 cols) ----------------
__global__ __launch_bounds__(256) void k_pv(float* __restrict__ ws) {
  __shared__ __align__(16) unsigned short Ph_[64 * 32], Pl_[64 * 32];
  __shared__ __align__(16) unsigned short VrH[128 * 32], VrL[128 * 32];
  __shared__ __align__(16) unsigned short ViH[128 * 32], ViL[128 * 32];
  const unsigned short* ph = (const unsigned short*)(ws + OFF_PH);
  const unsigned short* pl = (const unsigned short*)(ws + OFF_PL);
  const unsigned short* vth = (const unsigned short*)(ws + OFF_VTH);
  const unsigned short* vtl = (const unsigned short*)(ws + OFF_VTL);
  int yb = blockIdx.y, mb = yb >> 1, half = yb & 1;
  int m = mb >> 3, b = mb & 7;
  int col0 = blockIdx.x * 128;
  int t = threadIdx.x, lane = t & 63, w = t >> 6;
  int wr = w >> 1, wc = w & 1;              // wr: 32-row group, wc: 64-col group
  int q = lane >> 4, r = lane & 15;
  int srow = t >> 2;
  int skoff = (t & 3) * 8;
  size_t prow = (size_t)(mb * 128 + half * 64 + srow) * 128 + skoff;
  size_t vbr1 = ((size_t)(m * 512) + col0 + srow) * 1024 + b * 128 + skoff;
  size_t vbr2 = ((size_t)(m * 512) + col0 + 64 + srow) * 1024 + b * 128 + skoff;
  size_t vplane_i = (size_t)4 * 512 * 1024;

  floatx4 accR[2][4], accI[2][4];
#pragma unroll
  for (int i = 0; i < 2; ++i)
#pragma unroll
    for (int j = 0; j < 4; ++j) {
      accR[i][j] = (floatx4){0.f, 0.f, 0.f, 0.f};
      accI[i][j] = (floatx4){0.f, 0.f, 0.f, 0.f};
    }

  for (int k0 = 0; k0 < 128; k0 += 32) {
    gll16(ph + prow + k0, (char*)Ph_ + t * 16);
    gll16(pl + prow + k0, (char*)Pl_ + t * 16);
    gll16(vth + vbr1 + k0, (char*)VrH + t * 16);
    gll16(vth + vbr2 + k0, (char*)VrH + 4096 + t * 16);
    gll16(vtl + vbr1 + k0, (char*)VrL + t * 16);
    gll16(vtl + vbr2 + k0, (char*)VrL + 4096 + t * 16);
    gll16(vth + vplane_i + vbr1 + k0, (char*)ViH + t * 16);
    gll16(vth + vplane_i + vbr2 + k0, (char*)ViH + 4096 + t * 16);
    gll16(vtl + vplane_i + vbr1 + k0, (char*)ViL + t * 16);
    gll16(vtl + vplane_i + vbr2 + k0, (char*)ViL + 4096 + t * 16);
    __syncthreads();
    s8v ah[2], al[2];
#pragma unroll
    for (int i = 0; i < 2; ++i) {
      int ro = (wr * 32 + i * 16 + r) * 32 + q * 8;
      ah[i] = *(const s8v*)((const short*)Ph_ + ro);
      al[i] = *(const s8v*)((const short*)Pl_ + ro);
    }
#pragma unroll
    for (int j = 0; j < 4; ++j) {
      int ro = (wc * 64 + j * 16 + r) * 32 + q * 8;
      s8v vrh = *(const s8v*)((const short*)VrH + ro);
      s8v vrl = *(const s8v*)((const short*)VrL + ro);
      s8v vih = *(const s8v*)((const short*)ViH + ro);
      s8v vil = *(const s8v*)((const short*)ViL + ro);
#pragma unroll
      for (int i = 0; i < 2; ++i) {
        accR[i][j] = __builtin_amdgcn_mfma_f32_16x16x32_bf16(ah[i], vrh, accR[i][j], 0, 0, 0);
        accR[i][j] = __builtin_amdgcn_mfma_f32_16x16x32_bf16(ah[i], vrl, accR[i][j], 0, 0, 0);
        accR[i][j] = __builtin_amdgcn_mfma_f32_16x16x32_bf16(al[i], vrh, accR[i][j], 0, 0, 0);
        accI[i][j] = __builtin_amdgcn_mfma_f32_16x16x32_bf16(ah[i], vih, accI[i][j], 0, 0, 0);
        accI[i][j] = __builtin_amdgcn_mfma_f32_16x16x32_bf16(ah[i], vil, accI[i][j], 0, 0, 0);
        accI[i][j] = __builtin_amdgcn_mfma_f32_16x16x32_bf16(al[i], vih, accI[i][j], 0, 0, 0);
      }
    }
    __syncthreads();
  }
  float* orp = ws + OFF_OR + (size_t)mb * 128 * 512;
  float* oip = ws + OFF_OI + (size_t)mb * 128 * 512;
#pragma unroll
  for (int i = 0; i < 2; ++i)
#pragma unroll
    for (int j = 0; j < 4; ++j) {
      int rowb = half * 64 + wr * 32 + i * 16 + q * 4;
      int colb = col0 + wc * 64 + j * 16 + r;
#pragma unroll
      for (int reg = 0; reg < 4; ++reg) {
        orp[(size_t)(rowb + reg) * 512 + colb] = accR[i][j][reg];
        oip[(size_t)(rowb + reg) * 512 + colb] = accI[i][j][reg];
      }
    }
}

// ---------------- ModReLU + ComplexLayerNorm + feat partials (fused) + GRU finish ----------------
__global__ __launch_bounds__(256) void k_modlnfeat(float* __restrict__ ws,
                                                   const float* __restrict__ mod_bias,
                                                   const float* __restrict__ ln_scale,
                                                   const float* __restrict__ ln_shift,
                                                   const float* __restrict__ hold,
                                                   float* __restrict__ hnew,
                                                   const float* __restrict__ bih,
                                                   const float* __restrict__ bhh) {
  int blk = blockIdx.x;
  int t = threadIdx.x;
  if (blk >= 128) {
    int b = blk - 128;
    for (int c = t; c < 512; c += 256) {
      const float* part = ws + OFF_PART + ((size_t)b * 512 + c) * 4;
      float r_ = part[0] + bih[c] + bhh[c];
      float z_ = part[1] + bih[512 + c] + bhh[512 + c];
      float xn = part[2] + bih[1024 + c];
      float hn = part[3] + bhh[1024 + c];
      float r = 1.f / (1.f + expf(-r_));
      float z = 1.f / (1.f + expf(-z_));
      float n = tanhf(xn + r * hn);
      hnew[b * 512 + c] = (1.f - z) * n + z * hold[b * 512 + c];
    }
    return;
  }
  int mb = blk >> 2, grp = blk & 3;
  int m = mb >> 3;
  int w = t >> 6, l = t & 63;
  int e0 = l * 8;
  float mb_[8], lsc[8], lsh[8];
  *(float4*)&mb_[0] = *(const float4*)(mod_bias + m * 512 + e0);
  *(float4*)&mb_[4] = *(const float4*)(mod_bias + m * 512 + e0 + 4);
  *(float4*)&lsc[0] = *(const float4*)(ln_scale + m * 512 + e0);
  *(float4*)&lsc[4] = *(const float4*)(ln_scale + m * 512 + e0 + 4);
  *(float4*)&lsh[0] = *(const float4*)(ln_shift + m * 512 + e0);
  *(float4*)&lsh[4] = *(const float4*)(ln_shift + m * 512 + e0 + 4);
  float featR[8] = {}, featI[8] = {};
  for (int it = 0; it < 8; ++it) {
    int s = grp * 32 + it * 4 + w;
    float* orp = ws + OFF_OR + ((size_t)mb * 128 + s) * 512 + e0;
    float* oip = ws + OFF_OI + ((size_t)mb * 128 + s) * 512 + e0;
    float orv[8], oiv[8], magv[8];
    *(float4*)&orv[0] = *(const float4*)orp;
    *(float4*)&orv[4] = *(const float4*)(orp + 4);
    *(float4*)&oiv[0] = *(const float4*)oip;
    *(float4*)&oiv[4] = *(const float4*)(oip + 4);
    float sum = 0.f, sumsq = 0.f;
#pragma unroll
    for (int j = 0; j < 8; ++j) {
      float o_r = orv[j], o_i = oiv[j];
      float mag = sqrtf(o_r * o_r + o_i * o_i) + EPS;
      float g = fmaxf(mag + mb_[j], 0.f) / mag;
      o_r *= g; o_i *= g;
      orv[j] = o_r; oiv[j] = o_i;
      float mag2 = sqrtf(o_r * o_r + o_i * o_i) + EPS;
      magv[j] = mag2;
      sum += mag2;
      sumsq += mag2 * mag2;
    }
    for (int o = 1; o < 64; o <<= 1) {
      sum += __shfl_xor(sum, o);
      sumsq += __shfl_xor(sumsq, o);
    }
    float mu = sum * (1.f / D);
    float var = (sumsq - (float)D * mu * mu) * (1.f / (D - 1));
    float inv = 1.f / sqrtf(var + EPS);
#pragma unroll
    for (int j = 0; j < 8; ++j) {
      float nm = (magv[j] - mu) * inv * lsc[j] + lsh[j];
      float hyp = magv[j] - EPS;
      float cp, sp;
      if (hyp > 0.f) { cp = orv[j] / hyp; sp = oiv[j] / hyp; }
      else           { cp = 1.f;          sp = 0.f; }
      orv[j] = nm * cp;
      oiv[j] = nm * sp;
      featR[j] += orv[j];
      featI[j] += oiv[j];
    }
    *(float4*)orp = *(float4*)&orv[0];
    *(float4*)(orp + 4) = *(float4*)&orv[4];
    *(float4*)oip = *(float4*)&oiv[0];
    *(float4*)(oip + 4) = *(float4*)&oiv[4];
  }
  float* fb = ws + OFF_FEAT + (size_t)mb * 1024;
#pragma unroll
  for (int j = 0; j < 8; ++j) {
    atomicAdd(fb + e0 + j, featR[j] * (1.0f / S));
    atomicAdd(fb + 512 + e0 + j, featI[j] * (1.0f / S));
  }
}

// ---------------- wsel (R21): 1024 thr, 32 lanes/(m,b) pair, float4 loads ----------------
// Computes w, halt p/wt/cum. gwp + FEAT-zero moved to k_bcast tail blocks.
__global__ __launch_bounds__(1024) void k_wsel(float* __restrict__ ws,
                                               const float* __restrict__ hnew,
                                               const float* __restrict__ bias_W,
                                               const float* __restrict__ bias_b,
                                               const float* __restrict__ w_sal,
                                               const float* __restrict__ w_halt,
                                               const float* __restrict__ b_halt,
                                               const float* __restrict__ cumr,
                                               float* __restrict__ cumw) {
  __shared__ float mb_s[B][M];
  __shared__ float sal_s[M][B];
  __shared__ float hsal_s[M][B];
  int t = threadIdx.x;
  int pair = t >> 5, l32 = t & 31;          // 32 pairs x 32 lanes
  {
    // bias dot: mb_s[b][m] = hnew[b,:] . bias_W[:,m]
    int b = pair >> 2, m = pair & 3;
    float s = 0.f;
    for (int d2 = l32; d2 < D; d2 += 32) s += hnew[b * D + d2] * bias_W[d2 * M + m];
    for (int o = 1; o < 32; o <<= 1) s += __shfl_xor(s, o);
    if (l32 == 0) mb_s[b][m] = s + bias_b[m];
  }
  {
    // salience + halt dots over feat rows (float4)
    int m = pair >> 3, b = pair & 7;
    const float4* fv4 = (const float4*)(ws + OFF_FEAT + (size_t)(m * B + b) * 1024);
    const float4* sv4 = (const float4*)(w_sal + m * 1024);
    const float4* hv4 = (const float4*)w_halt;
    float s = 0.f, s2 = 0.f;
#pragma unroll
    for (int k = 0; k < 8; ++k) {
      int i = l32 + k * 32;                 // 256 float4s per row
      float4 fv = fv4[i], sv = sv4[i], hv = hv4[i];
      s  += fv.x * sv.x + fv.y * sv.y + fv.z * sv.z + fv.w * sv.w;
      s2 += fv.x * hv.x + fv.y * hv.y + fv.z * hv.z + fv.w * hv.w;
    }
    for (int o = 1; o < 32; o <<= 1) { s += __shfl_xor(s, o); s2 += __shfl_xor(s2, o); }
    if (l32 == 0) { sal_s[m][b] = s; hsal_s[m][b] = s2; }
  }
  __syncthreads();
  if (t < B) {
    int b = t;
    float lg[M], mx = -1e30f;
#pragma unroll
    for (int m = 0; m < M; ++m) { lg[m] = sal_s[m][b] + mb_s[b][m]; mx = fmaxf(mx, lg[m]); }
    float sm = 0.f;
#pragma unroll
    for (int m = 0; m < M; ++m) { lg[m] = expf(lg[m] - mx); sm += lg[m]; }
    float inv = 1.f / sm;
    float hs = 0.f;
#pragma unroll
    for (int m = 0; m < M; ++m) {
      float wv = lg[m] * inv;
      ws[OFF_W + m * B + b] = wv;
      hs += wv * hsal_s[m][b];
    }
    float pp = 1.f / (1.f + expf(-(hs + b_halt[0])));
    float cum = cumr[b];
    float still = (cum < THRESH) ? 1.f : 0.f;
    bool nh = ((cum + pp) >= THRESH) && (cum < THRESH);
    float wt = (nh ? (1.f - cum) : pp) * still;
    cumw[b] = cum + wt;
    ws[OFF_WT + b] = wt;
  }
}

// ---------------- bcast (R21): bf16 Xcat + fused ACT accumulate + gwp/FEAT tail ----------------
// grid 520. blk<512: R20 body. blk>=512 (b = blk-512): gwp[b,:] = sum_m w[m,b]*feat[m,b,:]
// + FEAT zeroing (read-then-clear). GWP consumed next step; FEAT next touched by
// next step's modln atomics — kernel-boundary ordered.
__global__ __launch_bounds__(256) void k_bcast(float* __restrict__ ws) {
  int t = threadIdx.x;
  int blk = blockIdx.x;
  if (blk >= 512) {
    int b = blk - 512;
    float w0 = ws[OFF_W + 0 * B + b], w1 = ws[OFF_W + 1 * B + b];
    float w2 = ws[OFF_W + 2 * B + b], w3 = ws[OFF_W + 3 * B + b];
    float4* f0 = (float4*)(ws + OFF_FEAT + (size_t)(0 * B + b) * 1024);
    float4* f1 = (float4*)(ws + OFF_FEAT + (size_t)(1 * B + b) * 1024);
    float4* f2 = (float4*)(ws + OFF_FEAT + (size_t)(2 * B + b) * 1024);
    float4* f3 = (float4*)(ws + OFF_FEAT + (size_t)(3 * B + b) * 1024);
    float4* gp = (float4*)(ws + OFF_GWP + (size_t)b * 1024);
    float4 z4 = {0.f, 0.f, 0.f, 0.f};
    // 256 float4s per row, 256 threads -> 1 each
    float4 a = f0[t], c = f1[t], d = f2[t], e = f3[t];
    float4 g;
    g.x = w0 * a.x + w1 * c.x + w2 * d.x + w3 * e.x;
    g.y = w0 * a.y + w1 * c.y + w2 * d.y + w3 * e.y;
    g.z = w0 * a.z + w1 * c.z + w2 * d.z + w3 * e.z;
    g.w = w0 * a.w + w1 * c.w + w2 * d.w + w3 * e.w;
    gp[t] = g;
    f0[t] = z4; f1[t] = z4; f2[t] = z4; f3[t] = z4;
    return;
  }
  unsigned short* xh = (unsigned short*)(ws + OFF_XH);
  unsigned short* xl = (unsigned short*)(ws + OFF_XL);
  int i4 = blk * 256 + t;
  int b = i4 >> 14;
  float w0 = ws[OFF_W + 0 * B + b], w1 = ws[OFF_W + 1 * B + b];
  float w2 = ws[OFF_W + 2 * B + b], w3 = ws[OFF_W + 3 * B + b];
  float wt = ws[OFF_WT + b];
  const float4* mr = (const float4*)(ws + OFF_OR);
  const float4* mi = (const float4*)(ws + OFF_OI);
  const int MS = BSD / 4;
  int row = i4 >> 7;
  int d4 = (i4 & 127) * 4;
  float4 r0 = mr[i4], r1 = mr[i4 + MS], r2 = mr[i4 + 2 * MS], r3 = mr[i4 + 3 * MS];
  float gvR[4];
  gvR[0] = w0 * r0.x + w1 * r1.x + w2 * r2.x + w3 * r3.x;
  gvR[1] = w0 * r0.y + w1 * r1.y + w2 * r2.y + w3 * r3.y;
  gvR[2] = w0 * r0.z + w1 * r1.z + w2 * r2.z + w3 * r3.z;
  gvR[3] = w0 * r0.w + w1 * r1.w + w2 * r2.w + w3 * r3.w;
  us4 hh, hl;
#pragma unroll
  for (int j = 0; j < 4; ++j) {
    unsigned short h = f2bf(gvR[j]); hh[j] = h; hl[j] = f2bf(gvR[j] - bf2f(h));
  }
  *(us4*)(xh + (size_t)row * 1024 + d4) = hh;
  *(us4*)(xl + (size_t)row * 1024 + d4) = hl;
  float4 s0 = mi[i4], s1 = mi[i4 + MS], s2 = mi[i4 + 2 * MS], s3 = mi[i4 + 3 * MS];
  float gvI[4];
  gvI[0] = w0 * s0.x + w1 * s1.x + w2 * s2.x + w3 * s3.x;
  gvI[1] = w0 * s0.y + w1 * s1.y + w2 * s2.y + w3 * s3.y;
  gvI[2] = w0 * s0.z + w1 * s1.z + w2 * s2.z + w3 * s3.z;
  gvI[3] = w0 * s0.w + w1 * s1.w + w2 * s2.w + w3 * s3.w;
#pragma unroll
  for (int j = 0; j < 4; ++j) {
    unsigned short h = f2bf(gvI[j]); hh[j] = h; hl[j] = f2bf(gvI[j] - bf2f(h));
  }
  *(us4*)(xh + (size_t)row * 1024 + 512 + d4) = hh;
  *(us4*)(xl + (size_t)row * 1024 + 512 + d4) = hl;
  float4 a = ((float4*)(ws + OFF_AR))[i4];
  a.x += wt * gvR[0]; a.y += wt * gvR[1]; a.z += wt * gvR[2]; a.w += wt * gvR[3];
  ((float4*)(ws + OFF_AR))[i4] = a;
  a = ((float4*)(ws + OFF_AI))[i4];
  a.x += wt * gvI[0]; a.y += wt * gvI[1]; a.z += wt * gvI[2]; a.w += wt * gvI[3];
  ((float4*)(ws + OFF_AI))[i4] = a;
}

// ---------------- output (R1) ----------------
__global__ __launch_bounds__(256) void k_out(const float* __restrict__ ws,
                                             float* __restrict__ out) {
  int i4 = blockIdx.x * 256 + threadIdx.x;
  ((float4*)out)[i4] = ((const float4*)(ws + OFF_AR))[i4];
  ((float4*)out)[i4 + BSD / 4] = ((const float4*)(ws + OFF_AI))[i4];
}

extern "C" void kernel_launch(void* const* d_in, const int* in_sizes, int n_in,
                              void* d_out, int out_size, void* d_ws, size_t ws_size,
                              hipStream_t stream) {
  (void)in_sizes; (void)n_in; (void)out_size; (void)ws_size;
  const float* x_real  = (const float*)d_in[0];
  const float* x_imag  = (const float*)d_in[1];
  const float* Wq_r    = (const float*)d_in[2];
  const float* Wq_i    = (const float*)d_in[3];
  const float* Wk_r    = (const float*)d_in[4];
  const float* Wk_i    = (const float*)d_in[5];
  const float* Wv_r    = (const float*)d_in[6];
  const float* Wv_i    = (const float*)d_in[7];
  const float* mod_bias = (const float*)d_in[8];
  const float* ln_scale = (const float*)d_in[9];
  const float* ln_shift = (const float*)d_in[10];
  const float* w_sal   = (const float*)d_in[11];
  const float* gru_Wih = (const float*)d_in[12];
  const float* gru_Whh = (const float*)d_in[13];
  const float* gru_bih = (const float*)d_in[14];
  const float* gru_bhh = (const float*)d_in[15];
  const float* bias_W  = (const float*)d_in[16];
  const float* bias_b  = (const float*)d_in[17];
  const float* w_halt  = (const float*)d_in[18];
  const float* b_halt  = (const float*)d_in[19];
  float* ws = (float*)d_ws;
  float* out = (float*)d_out;

  k_wprep<<<dim3(8, 8, 24), 256, 0, stream>>>(Wq_r, Wq_i, Wk_r, Wk_i, Wv_r, Wv_i, ws);
  k_init<<<512, 256, 0, stream>>>(x_real, x_imag, ws);
  k_gwp<<<32, 256, 0, stream>>>(ws + OFF_ZR, ws + OFF_ZI, ws + OFF_GWP);
  for (int step = 0; step < DEPTH; ++step) {
    const float* hold = ws + ((step & 1) ? OFF_H1 : OFF_H0);
    float* hnew = ws + ((step & 1) ? OFF_H0 : OFF_H1);
    const float* cumr = ws + ((step & 1) ? OFF_CUM2 : OFF_CUM);
    float* cumw = ws + ((step & 1) ? OFF_CUM : OFF_CUM2);
    k_qk<<<dim3(4, 8, 16), 256, 0, stream>>>(ws);
    k_vattn<<<576, 256, 0, stream>>>(ws, ws + OFF_GWP, hold, gru_Wih, gru_Whh);
    k_pv<<<dim3(4, 64), 256, 0, stream>>>(ws);
    k_modlnfeat<<<136, 256, 0, stream>>>(ws, mod_bias, ln_scale, ln_shift,
                                         hold, hnew, gru_bih, gru_bhh);
    k_wsel<<<1, 1024, 0, stream>>>(ws, hnew, bias_W, bias_b, w_sal,
                                   w_halt, b_halt, cumr, cumw);
    k_bcast<<<520, 256, 0, stream>>>(ws);
  }
  k_out<<<512, 256, 0, stream>>>(ws, out);
}